// Round 1
// baseline (4850.842 us; speedup 1.0000x reference)
//
#include <hip/hip_runtime.h>
#include <hip/hip_bf16.h>
#include <cstdint>

#define B_    2
#define S_    1024
#define H_    2048
#define NH_   32
#define NKV_  8
#define HD_   64
#define T_    (B_*S_)
#define E_    16
#define ED_   1024
#define TOPK_ 4
#define WIN_  128
#define LIMIT_ 7.0f
#define ALPHA_ 1.702f
#define EPS_   1e-6f
#define SCALE_ 0.125f  /* HD^-0.5 */

#define TM 64
#define TN 64
#define TK 16

// ---------------- RMSNorm ----------------
__global__ __launch_bounds__(256) void k_rmsnorm(const float* __restrict__ x,
                                                 const float* __restrict__ w,
                                                 float* __restrict__ y) {
    int t = blockIdx.x;
    const float* row = x + (size_t)t * H_;
    float ss = 0.f;
    for (int i = threadIdx.x; i < H_ / 4; i += 256) {
        float4 v = ((const float4*)row)[i];
        ss += v.x * v.x + v.y * v.y + v.z * v.z + v.w * v.w;
    }
    for (int o = 32; o >= 1; o >>= 1) ss += __shfl_xor(ss, o);
    __shared__ float wsum[4];
    if ((threadIdx.x & 63) == 0) wsum[threadIdx.x >> 6] = ss;
    __syncthreads();
    float tot = wsum[0] + wsum[1] + wsum[2] + wsum[3];
    float r = rsqrtf(tot / (float)H_ + EPS_);
    float* yrow = y + (size_t)t * H_;
    for (int i = threadIdx.x; i < H_ / 4; i += 256) {
        float4 v = ((const float4*)row)[i];
        float4 g = ((const float4*)w)[i];
        float4 o4;
        o4.x = v.x * r * g.x; o4.y = v.y * r * g.y;
        o4.z = v.z * r * g.z; o4.w = v.w * r * g.w;
        ((float4*)yrow)[i] = o4;
    }
}

// ---------------- GEMM: C = A(M,K) @ B(N,K)^T (+bias)(+res) ----------------
__global__ __launch_bounds__(256) void k_gemm_bt(const float* __restrict__ A,
                                                 const float* __restrict__ Bw,
                                                 const float* __restrict__ bias,
                                                 const float* __restrict__ res,
                                                 float* __restrict__ C,
                                                 int N, int K) {
    __shared__ float As[TK][TM + 4];
    __shared__ float Bs[TK][TN + 4];
    int row0 = blockIdx.x * TM, col0 = blockIdx.y * TN;
    int tid = threadIdx.x;
    int ty = tid >> 4, tx = tid & 15;
    int lrow = tid >> 2, lk = (tid & 3) * 4;
    const float* Aload = A + (size_t)(row0 + lrow) * K + lk;
    const float* Bload = Bw + (size_t)(col0 + lrow) * K + lk;
    float acc[4][4] = {};
    for (int k0 = 0; k0 < K; k0 += TK) {
        float4 a4 = *(const float4*)(Aload + k0);
        float4 b4 = *(const float4*)(Bload + k0);
        __syncthreads();
        As[lk + 0][lrow] = a4.x; As[lk + 1][lrow] = a4.y;
        As[lk + 2][lrow] = a4.z; As[lk + 3][lrow] = a4.w;
        Bs[lk + 0][lrow] = b4.x; Bs[lk + 1][lrow] = b4.y;
        Bs[lk + 2][lrow] = b4.z; Bs[lk + 3][lrow] = b4.w;
        __syncthreads();
#pragma unroll
        for (int kk = 0; kk < TK; ++kk) {
            float4 av = *(const float4*)&As[kk][ty << 2];
            float4 bv = *(const float4*)&Bs[kk][tx << 2];
            float ar[4] = {av.x, av.y, av.z, av.w};
            float br[4] = {bv.x, bv.y, bv.z, bv.w};
#pragma unroll
            for (int i2 = 0; i2 < 4; ++i2)
#pragma unroll
                for (int j = 0; j < 4; ++j)
                    acc[i2][j] += ar[i2] * br[j];
        }
    }
#pragma unroll
    for (int i2 = 0; i2 < 4; ++i2) {
        int r = row0 + (ty << 2) + i2;
#pragma unroll
        for (int j = 0; j < 4; ++j) {
            int c = col0 + (tx << 2) + j;
            float v = acc[i2][j];
            if (bias) v += bias[c];
            if (res)  v += res[(size_t)r * N + c];
            C[(size_t)r * N + c] = v;
        }
    }
}

// ---------------- RoPE (in-place on q and k) ----------------
__global__ __launch_bounds__(256) void k_rope(float* __restrict__ q, float* __restrict__ k,
                                              const float* __restrict__ cs,
                                              const float* __restrict__ sn) {
    int t = blockIdx.x;
    size_t cb = (size_t)t * HD_;
    for (int p = threadIdx.x; p < (NH_ + NKV_) * 32; p += 256) {
        int head = p >> 5, d = p & 31;
        float c1 = cs[cb + d],      s1v = sn[cb + d];
        float c2 = cs[cb + d + 32], s2v = sn[cb + d + 32];
        float* arr; size_t idx;
        if (head < NH_) { arr = q; idx = (size_t)t * (NH_ * HD_) + head * HD_ + d; }
        else            { arr = k; idx = (size_t)t * (NKV_ * HD_) + (head - NH_) * HD_ + d; }
        float x1 = arr[idx], x2 = arr[idx + 32];
        arr[idx]      = x1 * c1 - x2 * s1v;
        arr[idx + 32] = x2 * c2 + x1 * s2v;
    }
}

// ---------------- Attention: one wave per (token, head) ----------------
__global__ __launch_bounds__(64) void k_attn(const float* __restrict__ q,
                                             const float* __restrict__ k,
                                             const float* __restrict__ v,
                                             const float* __restrict__ sinks,
                                             float* __restrict__ out) {
    int gid = blockIdx.x;
    int h = gid & (NH_ - 1);
    int ti = gid >> 5;            // b*S + i
    int i = ti & (S_ - 1);
    int kvh = h >> 2;
    int lane = threadIdx.x;
    int j0 = max(0, i - (WIN_ - 1));
    __shared__ float qs[HD_];
    __shared__ float ps[2 * 64];
    qs[lane] = q[(size_t)ti * (NH_ * HD_) + h * HD_ + lane];
    __syncthreads();
    int tb = ti - i;              // b*S
    const float* kb2 = k + (size_t)tb * (NKV_ * HD_) + kvh * HD_;
    int j1 = j0 + lane, j2 = j0 + lane + 64;
    float s1 = -3.0e38f, s2 = -3.0e38f;
    if (j1 <= i) {
        const float* kr = kb2 + (size_t)j1 * (NKV_ * HD_);
        float a = 0.f;
#pragma unroll
        for (int d4 = 0; d4 < HD_; d4 += 4) {
            float4 kv4 = *(const float4*)(kr + d4);
            a += qs[d4] * kv4.x + qs[d4 + 1] * kv4.y + qs[d4 + 2] * kv4.z + qs[d4 + 3] * kv4.w;
        }
        s1 = a * SCALE_;
    }
    if (j2 <= i) {
        const float* kr = kb2 + (size_t)j2 * (NKV_ * HD_);
        float a = 0.f;
#pragma unroll
        for (int d4 = 0; d4 < HD_; d4 += 4) {
            float4 kv4 = *(const float4*)(kr + d4);
            a += qs[d4] * kv4.x + qs[d4 + 1] * kv4.y + qs[d4 + 2] * kv4.z + qs[d4 + 3] * kv4.w;
        }
        s2 = a * SCALE_;
    }
    float sink = sinks[h];
    float lm = fmaxf(s1, s2);
    for (int o = 32; o >= 1; o >>= 1) lm = fmaxf(lm, __shfl_xor(lm, o));
    float m = fmaxf(lm, sink);
    float p1 = (j1 <= i) ? __expf(s1 - m) : 0.f;
    float p2 = (j2 <= i) ? __expf(s2 - m) : 0.f;
    float lsum = p1 + p2;
    for (int o = 32; o >= 1; o >>= 1) lsum += __shfl_xor(lsum, o);
    float denom = lsum + __expf(sink - m);
    ps[lane] = p1; ps[lane + 64] = p2;
    __syncthreads();
    int cnt = i - j0 + 1;
    const float* vb2 = v + (size_t)(tb + j0) * (NKV_ * HD_) + kvh * HD_ + lane;
    float oa = 0.f;
    for (int j = 0; j < cnt; j++) oa += ps[j] * vb2[(size_t)j * (NKV_ * HD_)];
    out[(size_t)ti * (NH_ * HD_) + h * HD_ + lane] = oa / denom;
}

// ---------------- Router: logits, top-4, softmax ----------------
__global__ __launch_bounds__(256) void k_router(const float* __restrict__ x,
                                                const float* __restrict__ rw,
                                                const float* __restrict__ rb,
                                                int* __restrict__ topi,
                                                float* __restrict__ topw) {
    int t = blockIdx.x;
    int e = threadIdx.x >> 4, g = threadIdx.x & 15;
    const float* row = x + (size_t)t * H_;
    const float* wr = rw + (size_t)e * H_;
    float acc = 0.f;
    int kbeg = g * (H_ / 16);
    for (int kk = 0; kk < H_ / 16; kk += 4) {
        float4 xv = *(const float4*)(row + kbeg + kk);
        float4 wv = *(const float4*)(wr + kbeg + kk);
        acc += xv.x * wv.x + xv.y * wv.y + xv.z * wv.z + xv.w * wv.w;
    }
    __shared__ float part[16][17];
    part[e][g] = acc;
    __syncthreads();
    __shared__ float logits[16];
    if (threadIdx.x < 16) {
        float s2 = rb[threadIdx.x];
        for (int g2 = 0; g2 < 16; g2++) s2 += part[threadIdx.x][g2];
        logits[threadIdx.x] = s2;
    }
    __syncthreads();
    if (threadIdx.x == 0) {
        float tv[4]; int ti4[4];
        unsigned used = 0;
        for (int s3 = 0; s3 < 4; s3++) {
            float best = -3.0e38f; int bi = 0;
            for (int e2 = 0; e2 < 16; e2++)
                if (!((used >> e2) & 1) && logits[e2] > best) { best = logits[e2]; bi = e2; }
            used |= 1u << bi; tv[s3] = best; ti4[s3] = bi;
        }
        float mx = tv[0], pe[4], sum = 0.f;
        for (int s3 = 0; s3 < 4; s3++) { pe[s3] = __expf(tv[s3] - mx); sum += pe[s3]; }
        for (int s3 = 0; s3 < 4; s3++) {
            topw[t * 4 + s3] = pe[s3] / sum;
            topi[t * 4 + s3] = ti4[s3];
        }
    }
}

// ---------------- MoE prep ----------------
__global__ void k_zero(int* counts) { if (threadIdx.x < E_) counts[threadIdx.x] = 0; }

__global__ void k_hist(const int* __restrict__ topi, int* counts) {
    int g = blockIdx.x * 256 + threadIdx.x;
    if (g < T_ * TOPK_) atomicAdd(&counts[topi[g]], 1);
}

__global__ void k_scan(const int* __restrict__ counts, int* offs, int* cursor) {
    if (threadIdx.x == 0 && blockIdx.x == 0) {
        int run = 0;
        for (int e = 0; e < E_; e++) { offs[e] = run; cursor[e] = run; run += counts[e]; }
    }
}

__global__ void k_scatter(const int* __restrict__ topi, const float* __restrict__ topw,
                          int* cursor, int* __restrict__ perm, float* __restrict__ pw) {
    int g = blockIdx.x * 256 + threadIdx.x;
    if (g >= T_ * TOPK_) return;
    int e = topi[g];
    int pos = atomicAdd(&cursor[e], 1);
    perm[pos] = g >> 2;
    pw[pos] = topw[g];
}

// ---------------- MoE GEMM1: gate_up + fused GLU activation ----------------
__global__ __launch_bounds__(256) void k_moe_gemm1(const float* __restrict__ X,
                                                   const float* __restrict__ W,
                                                   const float* __restrict__ bias,
                                                   const int* __restrict__ perm,
                                                   const int* __restrict__ counts,
                                                   const int* __restrict__ offs,
                                                   float* __restrict__ gated) {
    int e = blockIdx.z;
    int ne = counts[e];
    int m0 = blockIdx.x * TM;
    if (m0 >= ne) return;
    int base = offs[e];
    int col0 = blockIdx.y * TN;
    __shared__ float As[TK][TM + 4];
    __shared__ float Bs[TK][TN + 4];
    int tid = threadIdx.x;
    int ty = tid >> 4, tx = tid & 15;
    int lrow = tid >> 2, lk = (tid & 3) * 4;
    int srow = m0 + lrow;
    int tok = perm[base + min(srow, ne - 1)];
    const float* Aload = X + (size_t)tok * H_ + lk;
    int bkr = tid >> 4, bc4 = (tid & 15) * 4;
    const float* Bload = W + (size_t)e * H_ * 2048 + (size_t)bkr * 2048 + col0 + bc4;
    float acc[4][4] = {};
    for (int k0 = 0; k0 < H_; k0 += TK) {
        float4 a4 = *(const float4*)(Aload + k0);
        float4 b4 = *(const float4*)(Bload + (size_t)k0 * 2048);
        __syncthreads();
        As[lk + 0][lrow] = a4.x; As[lk + 1][lrow] = a4.y;
        As[lk + 2][lrow] = a4.z; As[lk + 3][lrow] = a4.w;
        *(float4*)&Bs[bkr][bc4] = b4;
        __syncthreads();
#pragma unroll
        for (int kk = 0; kk < TK; ++kk) {
            float4 av = *(const float4*)&As[kk][ty << 2];
            float4 bv = *(const float4*)&Bs[kk][tx << 2];
            float ar[4] = {av.x, av.y, av.z, av.w};
            float br[4] = {bv.x, bv.y, bv.z, bv.w};
#pragma unroll
            for (int i2 = 0; i2 < 4; ++i2)
#pragma unroll
                for (int j = 0; j < 4; ++j)
                    acc[i2][j] += ar[i2] * br[j];
        }
    }
#pragma unroll
    for (int i2 = 0; i2 < 4; ++i2) {
        int srow2 = m0 + (ty << 2) + i2;
        if (srow2 >= ne) continue;
        int slot = base + srow2;
#pragma unroll
        for (int jp = 0; jp < 2; ++jp) {
            int ce = col0 + (tx << 2) + jp * 2;
            float gt = acc[i2][jp * 2]     + bias[e * 2048 + ce];
            float up = acc[i2][jp * 2 + 1] + bias[e * 2048 + ce + 1];
            gt = fminf(gt, LIMIT_);
            up = fminf(fmaxf(up, -LIMIT_), LIMIT_);
            float sg = 1.f / (1.f + __expf(-ALPHA_ * gt));
            gated[(size_t)slot * ED_ + (ce >> 1)] = (up + 1.f) * (gt * sg);
        }
    }
}

// ---------------- MoE GEMM2: down proj, scaled, atomic accumulate ----------------
__global__ __launch_bounds__(256) void k_moe_gemm2(const float* __restrict__ G,
                                                   const float* __restrict__ W,
                                                   const float* __restrict__ bias,
                                                   const int* __restrict__ perm,
                                                   const float* __restrict__ pw,
                                                   const int* __restrict__ counts,
                                                   const int* __restrict__ offs,
                                                   float* __restrict__ out) {
    int e = blockIdx.z;
    int ne = counts[e];
    int m0 = blockIdx.x * TM;
    if (m0 >= ne) return;
    int base = offs[e];
    int col0 = blockIdx.y * TN;
    __shared__ float As[TK][TM + 4];
    __shared__ float Bs[TK][TN + 4];
    int tid = threadIdx.x;
    int ty = tid >> 4, tx = tid & 15;
    int lrow = tid >> 2, lk = (tid & 3) * 4;
    int srow = m0 + lrow;
    int slot = base + min(srow, ne - 1);
    const float* Aload = G + (size_t)slot * ED_ + lk;
    int bkr = tid >> 4, bc4 = (tid & 15) * 4;
    const float* Bload = W + (size_t)e * ED_ * H_ + (size_t)bkr * H_ + col0 + bc4;
    float acc[4][4] = {};
    for (int k0 = 0; k0 < ED_; k0 += TK) {
        float4 a4 = *(const float4*)(Aload + k0);
        float4 b4 = *(const float4*)(Bload + (size_t)k0 * H_);
        __syncthreads();
        As[lk + 0][lrow] = a4.x; As[lk + 1][lrow] = a4.y;
        As[lk + 2][lrow] = a4.z; As[lk + 3][lrow] = a4.w;
        *(float4*)&Bs[bkr][bc4] = b4;
        __syncthreads();
#pragma unroll
        for (int kk = 0; kk < TK; ++kk) {
            float4 av = *(const float4*)&As[kk][ty << 2];
            float4 bv = *(const float4*)&Bs[kk][tx << 2];
            float ar[4] = {av.x, av.y, av.z, av.w};
            float br[4] = {bv.x, bv.y, bv.z, bv.w};
#pragma unroll
            for (int i2 = 0; i2 < 4; ++i2)
#pragma unroll
                for (int j = 0; j < 4; ++j)
                    acc[i2][j] += ar[i2] * br[j];
        }
    }
#pragma unroll
    for (int i2 = 0; i2 < 4; ++i2) {
        int srow2 = m0 + (ty << 2) + i2;
        if (srow2 >= ne) continue;
        int slot2 = base + srow2;
        int tok = perm[slot2];
        float wgt = pw[slot2];
#pragma unroll
        for (int j = 0; j < 4; ++j) {
            int c = col0 + (tx << 2) + j;
            float v = wgt * (acc[i2][j] + bias[e * H_ + c]);
            atomicAdd(&out[(size_t)tok * H_ + c], v);
        }
    }
}

// ---------------- launch ----------------
extern "C" void kernel_launch(void* const* d_in, const int* in_sizes, int n_in,
                              void* d_out, int out_size, void* d_ws, size_t ws_size,
                              hipStream_t stream) {
    const float* hidden = (const float*)d_in[0];
    const float* cosp  = (const float*)d_in[1];
    const float* sinp  = (const float*)d_in[2];
    const float* ln1   = (const float*)d_in[3];
    const float* ln2   = (const float*)d_in[4];
    const float* qw    = (const float*)d_in[5];
    const float* qb    = (const float*)d_in[6];
    const float* kw    = (const float*)d_in[7];
    const float* kbia  = (const float*)d_in[8];
    const float* vw    = (const float*)d_in[9];
    const float* vbia  = (const float*)d_in[10];
    const float* ow    = (const float*)d_in[11];
    const float* ob    = (const float*)d_in[12];
    const float* sinks = (const float*)d_in[13];
    const float* rw    = (const float*)d_in[14];
    const float* rb    = (const float*)d_in[15];
    const float* gup   = (const float*)d_in[16];
    const float* gub   = (const float*)d_in[17];
    const float* dwp   = (const float*)d_in[18];
    const float* dwb   = (const float*)d_in[19];
    float* out = (float*)d_out;

    float* f = (float*)d_ws;
    float* xnorm = f; f += (size_t)T_ * H_;
    float* qbuf  = f; f += (size_t)T_ * (NH_ * HD_);
    float* kbuf  = f; f += (size_t)T_ * (NKV_ * HD_);
    float* vbuf  = f; f += (size_t)T_ * (NKV_ * HD_);
    float* attnb = f; f += (size_t)T_ * (NH_ * HD_);
    float* gated = f; f += (size_t)T_ * TOPK_ * ED_;
    float* topw  = f; f += T_ * TOPK_;
    float* pwb   = f; f += T_ * TOPK_;
    int* ip = (int*)f;
    int* topi   = ip; ip += T_ * TOPK_;
    int* perm   = ip; ip += T_ * TOPK_;
    int* counts = ip; ip += E_;
    int* offs   = ip; ip += E_;
    int* cursor = ip; ip += E_;

    k_rmsnorm<<<T_, 256, 0, stream>>>(hidden, ln1, xnorm);
    k_gemm_bt<<<dim3(T_ / TM, 2048 / TN), 256, 0, stream>>>(xnorm, qw, qb, nullptr, qbuf, 2048, H_);
    k_gemm_bt<<<dim3(T_ / TM, 512 / TN), 256, 0, stream>>>(xnorm, kw, kbia, nullptr, kbuf, 512, H_);
    k_gemm_bt<<<dim3(T_ / TM, 512 / TN), 256, 0, stream>>>(xnorm, vw, vbia, nullptr, vbuf, 512, H_);
    k_rope<<<T_, 256, 0, stream>>>(qbuf, kbuf, cosp, sinp);
    k_attn<<<T_ * NH_, 64, 0, stream>>>(qbuf, kbuf, vbuf, sinks, attnb);
    k_gemm_bt<<<dim3(T_ / TM, 2048 / TN), 256, 0, stream>>>(attnb, ow, ob, hidden, out, 2048, H_);
    k_rmsnorm<<<T_, 256, 0, stream>>>(out, ln2, xnorm);
    k_router<<<T_, 256, 0, stream>>>(xnorm, rw, rb, topi, topw);
    k_zero<<<1, 64, 0, stream>>>(counts);
    k_hist<<<(T_ * TOPK_ + 255) / 256, 256, 0, stream>>>(topi, counts);
    k_scan<<<1, 1, 0, stream>>>(counts, offs, cursor);
    k_scatter<<<(T_ * TOPK_ + 255) / 256, 256, 0, stream>>>(topi, topw, cursor, perm, pwb);
    k_moe_gemm1<<<dim3(T_ / TM, 2048 / TN, E_), 256, 0, stream>>>(xnorm, gup, gub, perm, counts, offs, gated);
    k_moe_gemm2<<<dim3(T_ / TM, 2048 / TN, E_), 256, 0, stream>>>(gated, dwp, dwb, perm, pwb, counts, offs, out);
}

// Round 4
// 1640.943 us; speedup vs baseline: 2.9561x; 2.9561x over previous
//
#include <hip/hip_runtime.h>
#include <hip/hip_bf16.h>
#include <cstdint>

#define B_    2
#define S_    1024
#define H_    2048
#define NH_   32
#define NKV_  8
#define HD_   64
#define T_    (B_*S_)
#define E_    16
#define ED_   1024
#define TOPK_ 4
#define WIN_  128
#define LIMIT_ 7.0f
#define ALPHA_ 1.702f
#define EPS_   1e-6f
#define SCALE_ 0.125f  /* HD^-0.5 */
#define SPLIT_ 2048.0f
#define INV_SPLIT_ 4.8828125e-4f

typedef _Float16 half8 __attribute__((ext_vector_type(8)));
typedef _Float16 half4v __attribute__((ext_vector_type(4)));
typedef float floatx4 __attribute__((ext_vector_type(4)));

__device__ __forceinline__ void gload16(const void* g, void* l) {
    __builtin_amdgcn_global_load_lds((const __attribute__((address_space(1))) void*)g,
                                     (__attribute__((address_space(3))) void*)l, 16, 0, 0);
}

// ================= split-fp16 GEMM (fp32-accurate): C = A@B^T + bias (+res) ====
// A,B pre-split: x ~= hi + lo/2048. acc1 = ah*bh; acc2 = ah*bl + al*bh.
// 128x128 tile, BK=32, 4 waves (2x2), 4x4 frags of 16x16x32 f16 MFMA.
__global__ __launch_bounds__(256) void k_gemm_sp(const _Float16* __restrict__ Ah,
                                                 const _Float16* __restrict__ Al,
                                                 const _Float16* __restrict__ Bh,
                                                 const _Float16* __restrict__ Bl,
                                                 const float* __restrict__ bias,
                                                 const float* __restrict__ res,
                                                 float* __restrict__ C, int N, int K) {
    __shared__ _Float16 Ahs[128 * 32];
    __shared__ _Float16 Als[128 * 32];
    __shared__ _Float16 Bhs[128 * 32];
    __shared__ _Float16 Bls[128 * 32];
    const int tid = threadIdx.x;
    const int lane = tid & 63;
    const int wid = tid >> 6;
    const int wr = wid >> 1, wc = wid & 1;
    const int row0 = blockIdx.x * 128, col0 = blockIdx.y * 128;
    floatx4 acc1[4][4], acc2[4][4];
    for (int m = 0; m < 4; ++m)
        for (int n = 0; n < 4; ++n) { acc1[m][n] = (floatx4)0.f; acc2[m][n] = (floatx4)0.f; }
    const int rL = tid >> 2, koff = (tid & 3) * 8;
    const size_t o0 = (size_t)(row0 + rL) * K + koff;
    const size_t o1 = (size_t)(row0 + 64 + rL) * K + koff;
    const size_t p0 = (size_t)(col0 + rL) * K + koff;
    const size_t p1 = (size_t)(col0 + 64 + rL) * K + koff;
    for (int k0 = 0; k0 < K; k0 += 32) {
        __syncthreads();
        gload16(Ah + o0 + k0, Ahs + tid * 8); gload16(Ah + o1 + k0, Ahs + 2048 + tid * 8);
        gload16(Al + o0 + k0, Als + tid * 8); gload16(Al + o1 + k0, Als + 2048 + tid * 8);
        gload16(Bh + p0 + k0, Bhs + tid * 8); gload16(Bh + p1 + k0, Bhs + 2048 + tid * 8);
        gload16(Bl + p0 + k0, Bls + tid * 8); gload16(Bl + p1 + k0, Bls + 2048 + tid * 8);
        __syncthreads();
        const int lk = (lane >> 4) * 8;
        half8 ah[4], al[4], bh[4], bl[4];
#pragma unroll
        for (int m = 0; m < 4; ++m) {
            int ro = (wr * 64 + m * 16 + (lane & 15)) * 32 + lk;
            ah[m] = *(const half8*)&Ahs[ro];
            al[m] = *(const half8*)&Als[ro];
        }
#pragma unroll
        for (int n = 0; n < 4; ++n) {
            int ro = (wc * 64 + n * 16 + (lane & 15)) * 32 + lk;
            bh[n] = *(const half8*)&Bhs[ro];
            bl[n] = *(const half8*)&Bls[ro];
        }
#pragma unroll
        for (int m = 0; m < 4; ++m)
#pragma unroll
            for (int n = 0; n < 4; ++n) {
                acc1[m][n] = __builtin_amdgcn_mfma_f32_16x16x32_f16(ah[m], bh[n], acc1[m][n], 0, 0, 0);
                acc2[m][n] = __builtin_amdgcn_mfma_f32_16x16x32_f16(ah[m], bl[n], acc2[m][n], 0, 0, 0);
                acc2[m][n] = __builtin_amdgcn_mfma_f32_16x16x32_f16(al[m], bh[n], acc2[m][n], 0, 0, 0);
            }
    }
#pragma unroll
    for (int mf = 0; mf < 4; ++mf)
#pragma unroll
        for (int i = 0; i < 4; ++i) {
            int r = row0 + wr * 64 + mf * 16 + ((lane >> 4) << 2) + i;
#pragma unroll
            for (int nf = 0; nf < 4; ++nf) {
                int c = col0 + wc * 64 + nf * 16 + (lane & 15);
                float v = acc1[mf][nf][i] + acc2[mf][nf][i] * INV_SPLIT_ + bias[c];
                if (res) v += res[(size_t)r * N + c];
                C[(size_t)r * N + c] = v;
            }
        }
}

// ================= single-fp16 MFMA core (MoE) =================
#define MFMA_PROLOG() \
    __shared__ _Float16 As[128 * 32]; \
    __shared__ _Float16 Bs[128 * 32]; \
    const int tid = threadIdx.x; \
    const int lane = tid & 63; \
    const int wid = tid >> 6; \
    const int wr = wid >> 1, wc = wid & 1; \
    _Float16* lA0 = As + tid * 8; _Float16* lA1 = As + 2048 + tid * 8; \
    _Float16* lB0 = Bs + tid * 8; _Float16* lB1 = Bs + 2048 + tid * 8; \
    floatx4 acc[4][4]; \
    for (int m = 0; m < 4; ++m) for (int n = 0; n < 4; ++n) acc[m][n] = (floatx4)0.f;

#define MFMA_KLOOP(KD) \
    for (int k0 = 0; k0 < (KD); k0 += 32) { \
        __syncthreads(); \
        gload16(aS0 + k0, lA0); gload16(aS1 + k0, lA1); \
        gload16(bS0 + k0, lB0); gload16(bS1 + k0, lB1); \
        __syncthreads(); \
        const int lk = (lane >> 4) * 8; \
        half8 a[4], b[4]; \
        _Pragma("unroll") for (int m = 0; m < 4; ++m) \
            a[m] = *(const half8*)&As[(wr * 64 + m * 16 + (lane & 15)) * 32 + lk]; \
        _Pragma("unroll") for (int n = 0; n < 4; ++n) \
            b[n] = *(const half8*)&Bs[(wc * 64 + n * 16 + (lane & 15)) * 32 + lk]; \
        _Pragma("unroll") for (int m = 0; m < 4; ++m) \
            _Pragma("unroll") for (int n = 0; n < 4; ++n) \
                acc[m][n] = __builtin_amdgcn_mfma_f32_16x16x32_f16(a[m], b[n], acc[m][n], 0, 0, 0); \
    }

// MoE GEMM1: gathered A rows via perm; fused GLU epilogue -> gated f16 [slot][1024]
__global__ __launch_bounds__(256) void k_moe1(const _Float16* __restrict__ X,
                                              const _Float16* __restrict__ W,
                                              const float* __restrict__ bias,
                                              const int* __restrict__ perm,
                                              const int* __restrict__ counts,
                                              const int* __restrict__ offs,
                                              _Float16* __restrict__ gated) {
    const int e = blockIdx.z;
    const int ne = counts[e];
    const int m0 = blockIdx.x * 128;
    if (m0 >= ne) return;
    const int base = offs[e];
    const int col0 = blockIdx.y * 128;
    MFMA_PROLOG();
    const int rL = tid >> 2, koff = (tid & 3) * 8;
    int t0 = perm[base + min(m0 + rL, ne - 1)];
    int t1 = perm[base + min(m0 + 64 + rL, ne - 1)];
    const _Float16* aS0 = X + (size_t)t0 * H_ + koff;
    const _Float16* aS1 = X + (size_t)t1 * H_ + koff;
    const _Float16* bS0 = W + ((size_t)e * 2048 + col0 + rL) * H_ + koff;
    const _Float16* bS1 = W + ((size_t)e * 2048 + col0 + 64 + rL) * H_ + koff;
    MFMA_KLOOP(H_);
#pragma unroll
    for (int mf = 0; mf < 4; ++mf)
#pragma unroll
        for (int i = 0; i < 4; ++i) {
            int r = m0 + wr * 64 + mf * 16 + ((lane >> 4) << 2) + i;
            bool ok = r < ne;
            int slot = base + r;
#pragma unroll
            for (int nf = 0; nf < 4; ++nf) {
                int c = col0 + wc * 64 + nf * 16 + (lane & 15);
                float v = acc[mf][nf][i] + bias[e * 2048 + c];
                float o = __shfl_xor(v, 1);   // pair even(gate)/odd(up) cols
                if (ok && !(lane & 1)) {
                    float gt = fminf(v, LIMIT_);
                    float up = fminf(fmaxf(o, -LIMIT_), LIMIT_);
                    float sg = 1.f / (1.f + __expf(-ALPHA_ * gt));
                    gated[(size_t)slot * ED_ + (c >> 1)] = (_Float16)((up + 1.f) * (gt * sg));
                }
            }
        }
}

// MoE GEMM2: contiguous slot rows; epilogue scale-by-routing + bias + atomicAdd
__global__ __launch_bounds__(256) void k_moe2(const _Float16* __restrict__ G,
                                              const _Float16* __restrict__ W,
                                              const float* __restrict__ bias,
                                              const int* __restrict__ perm,
                                              const float* __restrict__ pw,
                                              const int* __restrict__ counts,
                                              const int* __restrict__ offs,
                                              float* __restrict__ out) {
    const int e = blockIdx.z;
    const int ne = counts[e];
    const int m0 = blockIdx.x * 128;
    if (m0 >= ne) return;
    const int base = offs[e];
    const int col0 = blockIdx.y * 128;
    MFMA_PROLOG();
    const int rL = tid >> 2, koff = (tid & 3) * 8;
    int s0 = base + min(m0 + rL, ne - 1);
    int s1 = base + min(m0 + 64 + rL, ne - 1);
    const _Float16* aS0 = G + (size_t)s0 * ED_ + koff;
    const _Float16* aS1 = G + (size_t)s1 * ED_ + koff;
    const _Float16* bS0 = W + ((size_t)e * H_ + col0 + rL) * ED_ + koff;
    const _Float16* bS1 = W + ((size_t)e * H_ + col0 + 64 + rL) * ED_ + koff;
    MFMA_KLOOP(ED_);
#pragma unroll
    for (int mf = 0; mf < 4; ++mf)
#pragma unroll
        for (int i = 0; i < 4; ++i) {
            int r = m0 + wr * 64 + mf * 16 + ((lane >> 4) << 2) + i;
            if (r >= ne) continue;
            int slot = base + r;
            int tok = perm[slot];
            float wgt = pw[slot];
#pragma unroll
            for (int nf = 0; nf < 4; ++nf) {
                int c = col0 + wc * 64 + nf * 16 + (lane & 15);
                atomicAdd(&out[(size_t)tok * H_ + c], wgt * (acc[mf][nf][i] + bias[e * H_ + c]));
            }
        }
}

// ================= conversion kernels =================
// split convert: x -> hi(fp16), lo(fp16, residual * 2048)
__global__ __launch_bounds__(256) void k_cvts(const float* __restrict__ s,
                                              _Float16* __restrict__ dh,
                                              _Float16* __restrict__ dl, int n8) {
    int i = blockIdx.x * 256 + threadIdx.x;
    if (i >= n8) return;
    float4 x = ((const float4*)s)[i * 2], y = ((const float4*)s)[i * 2 + 1];
    float xs[8] = {x.x, x.y, x.z, x.w, y.x, y.y, y.z, y.w};
    half8 h, l;
#pragma unroll
    for (int j = 0; j < 8; ++j) {
        _Float16 hv = (_Float16)xs[j];
        h[j] = hv;
        l[j] = (_Float16)((xs[j] - (float)hv) * SPLIT_);
    }
    ((half8*)dh)[i] = h;
    ((half8*)dl)[i] = l;
}

// transpose-convert: src [e][K][N] fp32 -> dst [e][N][K] f16
__global__ __launch_bounds__(256) void k_cvt_t(const float* __restrict__ src,
                                               _Float16* __restrict__ dst, int K, int N) {
    const int e = blockIdx.z;
    const int k0 = blockIdx.x * 32, n0 = blockIdx.y * 32;
    __shared__ float t[32][33];
    const int tid = threadIdx.x;
    {
        int kr = tid >> 3, nc = (tid & 7) * 4;
        float4 v = *(const float4*)(src + ((size_t)e * K + k0 + kr) * N + n0 + nc);
        t[kr][nc] = v.x; t[kr][nc + 1] = v.y; t[kr][nc + 2] = v.z; t[kr][nc + 3] = v.w;
    }
    __syncthreads();
    {
        int nr = tid >> 3, kc = (tid & 7) * 4;
        half4v o;
        o[0] = (_Float16)t[kc + 0][nr];
        o[1] = (_Float16)t[kc + 1][nr];
        o[2] = (_Float16)t[kc + 2][nr];
        o[3] = (_Float16)t[kc + 3][nr];
        *(half4v*)(dst + ((size_t)e * N + n0 + nr) * K + k0 + kc) = o;
    }
}

// ================= RMSNorm (fp32 + split f16 outputs) =================
__global__ __launch_bounds__(256) void k_rmsnorm(const float* __restrict__ x,
                                                 const float* __restrict__ w,
                                                 float* __restrict__ y,
                                                 _Float16* __restrict__ yh,
                                                 _Float16* __restrict__ yl) {
    int t = blockIdx.x;
    const float* row = x + (size_t)t * H_;
    float ss = 0.f;
    for (int i = threadIdx.x; i < H_ / 4; i += 256) {
        float4 v = ((const float4*)row)[i];
        ss += v.x * v.x + v.y * v.y + v.z * v.z + v.w * v.w;
    }
    for (int o = 32; o >= 1; o >>= 1) ss += __shfl_xor(ss, o);
    __shared__ float wsum[4];
    if ((threadIdx.x & 63) == 0) wsum[threadIdx.x >> 6] = ss;
    __syncthreads();
    float tot = wsum[0] + wsum[1] + wsum[2] + wsum[3];
    float r = rsqrtf(tot / (float)H_ + EPS_);
    float* yrow = y + (size_t)t * H_;
    _Float16* hrow = yh + (size_t)t * H_;
    _Float16* lrow = yl + (size_t)t * H_;
    for (int i = threadIdx.x; i < H_ / 4; i += 256) {
        float4 v = ((const float4*)row)[i];
        float4 g = ((const float4*)w)[i];
        float o4[4];
        o4[0] = v.x * r * g.x; o4[1] = v.y * r * g.y;
        o4[2] = v.z * r * g.z; o4[3] = v.w * r * g.w;
        ((float4*)yrow)[i] = *(float4*)o4;
        half4v h4, l4;
#pragma unroll
        for (int j = 0; j < 4; ++j) {
            _Float16 hv = (_Float16)o4[j];
            h4[j] = hv;
            l4[j] = (_Float16)((o4[j] - (float)hv) * SPLIT_);
        }
        ((half4v*)hrow)[i] = h4;
        ((half4v*)lrow)[i] = l4;
    }
}

// ================= RoPE =================
__global__ __launch_bounds__(256) void k_rope(float* __restrict__ q, float* __restrict__ k,
                                              const float* __restrict__ cs,
                                              const float* __restrict__ sn) {
    int t = blockIdx.x;
    size_t cb = (size_t)t * HD_;
    for (int p = threadIdx.x; p < (NH_ + NKV_) * 32; p += 256) {
        int head = p >> 5, d = p & 31;
        float c1 = cs[cb + d],      s1v = sn[cb + d];
        float c2 = cs[cb + d + 32], s2v = sn[cb + d + 32];
        float* arr; size_t idx;
        if (head < NH_) { arr = q; idx = (size_t)t * (NH_ * HD_) + head * HD_ + d; }
        else            { arr = k; idx = (size_t)t * (NKV_ * HD_) + (head - NH_) * HD_ + d; }
        float x1 = arr[idx], x2 = arr[idx + 32];
        arr[idx]      = x1 * c1 - x2 * s1v;
        arr[idx + 32] = x2 * c2 + x1 * s2v;
    }
}

// ================= Attention (fp32 compute, fp32 out) =================
__global__ __launch_bounds__(64) void k_attn(const float* __restrict__ q,
                                             const float* __restrict__ k,
                                             const float* __restrict__ v,
                                             const float* __restrict__ sinks,
                                             float* __restrict__ out) {
    int gid = blockIdx.x;
    int h = gid & (NH_ - 1);
    int ti = gid >> 5;
    int i = ti & (S_ - 1);
    int kvh = h >> 2;
    int lane = threadIdx.x;
    int j0 = max(0, i - (WIN_ - 1));
    __shared__ float qs[HD_];
    __shared__ float ps[2 * 64];
    qs[lane] = q[(size_t)ti * (NH_ * HD_) + h * HD_ + lane];
    __syncthreads();
    int tb = ti - i;
    const float* kb2 = k + (size_t)tb * (NKV_ * HD_) + kvh * HD_;
    int j1 = j0 + lane, j2 = j0 + lane + 64;
    float s1 = -3.0e38f, s2 = -3.0e38f;
    if (j1 <= i) {
        const float* kr = kb2 + (size_t)j1 * (NKV_ * HD_);
        float a = 0.f;
#pragma unroll
        for (int d4 = 0; d4 < HD_; d4 += 4) {
            float4 kv4 = *(const float4*)(kr + d4);
            a += qs[d4] * kv4.x + qs[d4 + 1] * kv4.y + qs[d4 + 2] * kv4.z + qs[d4 + 3] * kv4.w;
        }
        s1 = a * SCALE_;
    }
    if (j2 <= i) {
        const float* kr = kb2 + (size_t)j2 * (NKV_ * HD_);
        float a = 0.f;
#pragma unroll
        for (int d4 = 0; d4 < HD_; d4 += 4) {
            float4 kv4 = *(const float4*)(kr + d4);
            a += qs[d4] * kv4.x + qs[d4 + 1] * kv4.y + qs[d4 + 2] * kv4.z + qs[d4 + 3] * kv4.w;
        }
        s2 = a * SCALE_;
    }
    float sink = sinks[h];
    float lm = fmaxf(s1, s2);
    for (int o = 32; o >= 1; o >>= 1) lm = fmaxf(lm, __shfl_xor(lm, o));
    float m = fmaxf(lm, sink);
    float p1 = (j1 <= i) ? __expf(s1 - m) : 0.f;
    float p2 = (j2 <= i) ? __expf(s2 - m) : 0.f;
    float lsum = p1 + p2;
    for (int o = 32; o >= 1; o >>= 1) lsum += __shfl_xor(lsum, o);
    float denom = lsum + __expf(sink - m);
    ps[lane] = p1; ps[lane + 64] = p2;
    __syncthreads();
    int cnt = i - j0 + 1;
    const float* vb2 = v + (size_t)(tb + j0) * (NKV_ * HD_) + kvh * HD_ + lane;
    float oa = 0.f;
    for (int j = 0; j < cnt; j++) oa += ps[j] * vb2[(size_t)j * (NKV_ * HD_)];
    out[(size_t)ti * (NH_ * HD_) + h * HD_ + lane] = oa / denom;
}

// ================= Router =================
__global__ __launch_bounds__(256) void k_router(const float* __restrict__ x,
                                                const float* __restrict__ rw,
                                                const float* __restrict__ rb,
                                                int* __restrict__ topi,
                                                float* __restrict__ topw) {
    int t = blockIdx.x;
    int e = threadIdx.x >> 4, g = threadIdx.x & 15;
    const float* row = x + (size_t)t * H_;
    const float* wr = rw + (size_t)e * H_;
    float acc = 0.f;
    int kbeg = g * (H_ / 16);
    for (int kk = 0; kk < H_ / 16; kk += 4) {
        float4 xv = *(const float4*)(row + kbeg + kk);
        float4 wv = *(const float4*)(wr + kbeg + kk);
        acc += xv.x * wv.x + xv.y * wv.y + xv.z * wv.z + xv.w * wv.w;
    }
    __shared__ float part[16][17];
    part[e][g] = acc;
    __syncthreads();
    __shared__ float logits[16];
    if (threadIdx.x < 16) {
        float s2 = rb[threadIdx.x];
        for (int g2 = 0; g2 < 16; g2++) s2 += part[threadIdx.x][g2];
        logits[threadIdx.x] = s2;
    }
    __syncthreads();
    if (threadIdx.x == 0) {
        float tv[4]; int ti4[4];
        unsigned used = 0;
        for (int s3 = 0; s3 < 4; s3++) {
            float best = -3.0e38f; int bi = 0;
            for (int e2 = 0; e2 < 16; e2++)
                if (!((used >> e2) & 1) && logits[e2] > best) { best = logits[e2]; bi = e2; }
            used |= 1u << bi; tv[s3] = best; ti4[s3] = bi;
        }
        float mx = tv[0], pe[4], sum = 0.f;
        for (int s3 = 0; s3 < 4; s3++) { pe[s3] = __expf(tv[s3] - mx); sum += pe[s3]; }
        for (int s3 = 0; s3 < 4; s3++) {
            topw[t * 4 + s3] = pe[s3] / sum;
            topi[t * 4 + s3] = ti4[s3];
        }
    }
}

// ================= MoE prep =================
__global__ void k_zero(int* counts) { if (threadIdx.x < E_) counts[threadIdx.x] = 0; }

__global__ void k_hist(const int* __restrict__ topi, int* counts) {
    int g = blockIdx.x * 256 + threadIdx.x;
    if (g < T_ * TOPK_) atomicAdd(&counts[topi[g]], 1);
}

__global__ void k_scan(const int* __restrict__ counts, int* offs, int* cursor) {
    if (threadIdx.x == 0 && blockIdx.x == 0) {
        int run = 0;
        for (int e = 0; e < E_; e++) { offs[e] = run; cursor[e] = run; run += counts[e]; }
    }
}

__global__ void k_scatter(const int* __restrict__ topi, const float* __restrict__ topw,
                          int* cursor, int* __restrict__ perm, float* __restrict__ pw) {
    int g = blockIdx.x * 256 + threadIdx.x;
    if (g >= T_ * TOPK_) return;
    int e = topi[g];
    int pos = atomicAdd(&cursor[e], 1);
    perm[pos] = g >> 2;
    pw[pos] = topw[g];
}

// ================= launch =================
extern "C" void kernel_launch(void* const* d_in, const int* in_sizes, int n_in,
                              void* d_out, int out_size, void* d_ws, size_t ws_size,
                              hipStream_t stream) {
    const float* hidden = (const float*)d_in[0];
    const float* cosp  = (const float*)d_in[1];
    const float* sinp  = (const float*)d_in[2];
    const float* ln1   = (const float*)d_in[3];
    const float* ln2   = (const float*)d_in[4];
    const float* qw    = (const float*)d_in[5];
    const float* qb    = (const float*)d_in[6];
    const float* kw    = (const float*)d_in[7];
    const float* kbia  = (const float*)d_in[8];
    const float* vw    = (const float*)d_in[9];
    const float* vbia  = (const float*)d_in[10];
    const float* ow    = (const float*)d_in[11];
    const float* ob    = (const float*)d_in[12];
    const float* sinks = (const float*)d_in[13];
    const float* rw    = (const float*)d_in[14];
    const float* rb    = (const float*)d_in[15];
    const float* gup   = (const float*)d_in[16];
    const float* gub   = (const float*)d_in[17];
    const float* dwp   = (const float*)d_in[18];
    const float* dwb   = (const float*)d_in[19];
    float* out = (float*)d_out;

    char* p = (char*)d_ws;
    auto alloc = [&](size_t bytes) { char* r = p; p += (bytes + 255) & ~(size_t)255; return r; };
    float*     xnorm  = (float*)alloc((size_t)T_ * H_ * 4);
    _Float16*  xh     = (_Float16*)alloc((size_t)T_ * H_ * 2);
    _Float16*  xl     = (_Float16*)alloc((size_t)T_ * H_ * 2);
    float*     qbuf   = (float*)alloc((size_t)T_ * NH_ * HD_ * 4);
    float*     kbuf   = (float*)alloc((size_t)T_ * NKV_ * HD_ * 4);
    float*     vbuf   = (float*)alloc((size_t)T_ * NKV_ * HD_ * 4);
    float*     attnb  = (float*)alloc((size_t)T_ * NH_ * HD_ * 4);
    _Float16*  ath    = (_Float16*)alloc((size_t)T_ * NH_ * HD_ * 2);
    _Float16*  atl    = (_Float16*)alloc((size_t)T_ * NH_ * HD_ * 2);
    _Float16*  gatedh = (_Float16*)alloc((size_t)T_ * TOPK_ * ED_ * 2);
    _Float16*  qwh    = (_Float16*)alloc((size_t)2048 * H_ * 2);
    _Float16*  qwl    = (_Float16*)alloc((size_t)2048 * H_ * 2);
    _Float16*  kwh    = (_Float16*)alloc((size_t)512 * H_ * 2);
    _Float16*  kwl    = (_Float16*)alloc((size_t)512 * H_ * 2);
    _Float16*  vwh    = (_Float16*)alloc((size_t)512 * H_ * 2);
    _Float16*  vwl    = (_Float16*)alloc((size_t)512 * H_ * 2);
    _Float16*  owh    = (_Float16*)alloc((size_t)H_ * 2048 * 2);
    _Float16*  owl    = (_Float16*)alloc((size_t)H_ * 2048 * 2);
    _Float16*  gupt   = (_Float16*)alloc((size_t)E_ * 2048 * H_ * 2);
    _Float16*  dwnt   = (_Float16*)alloc((size_t)E_ * H_ * ED_ * 2);
    float*     topw   = (float*)alloc(T_ * TOPK_ * 4);
    float*     pwb    = (float*)alloc(T_ * TOPK_ * 4);
    int*       topi   = (int*)alloc(T_ * TOPK_ * 4);
    int*       perm   = (int*)alloc(T_ * TOPK_ * 4);
    int*       counts = (int*)alloc(E_ * 4);
    int*       offs   = (int*)alloc(E_ * 4);
    int*       cursor = (int*)alloc(E_ * 4);

    // weight conversions
    k_cvts<<<2048, 256, 0, stream>>>(qw, qwh, qwl, 2048 * H_ / 8);
    k_cvts<<<512, 256, 0, stream>>>(kw, kwh, kwl, 512 * H_ / 8);
    k_cvts<<<512, 256, 0, stream>>>(vw, vwh, vwl, 512 * H_ / 8);
    k_cvts<<<2048, 256, 0, stream>>>(ow, owh, owl, H_ * 2048 / 8);
    k_cvt_t<<<dim3(H_ / 32, 2048 / 32, E_), 256, 0, stream>>>(gup, gupt, H_, 2048);
    k_cvt_t<<<dim3(ED_ / 32, H_ / 32, E_), 256, 0, stream>>>(dwp, dwnt, ED_, H_);

    k_rmsnorm<<<T_, 256, 0, stream>>>(hidden, ln1, xnorm, xh, xl);
    k_gemm_sp<<<dim3(16, 16), 256, 0, stream>>>(xh, xl, qwh, qwl, qb, nullptr, qbuf, 2048, H_);
    k_gemm_sp<<<dim3(16, 4), 256, 0, stream>>>(xh, xl, kwh, kwl, kbia, nullptr, kbuf, 512, H_);
    k_gemm_sp<<<dim3(16, 4), 256, 0, stream>>>(xh, xl, vwh, vwl, vbia, nullptr, vbuf, 512, H_);
    k_rope<<<T_, 256, 0, stream>>>(qbuf, kbuf, cosp, sinp);
    k_attn<<<T_ * NH_, 64, 0, stream>>>(qbuf, kbuf, vbuf, sinks, attnb);
    k_cvts<<<2048, 256, 0, stream>>>(attnb, ath, atl, T_ * NH_ * HD_ / 8);
    k_gemm_sp<<<dim3(16, 16), 256, 0, stream>>>(ath, atl, owh, owl, ob, hidden, out, 2048, H_);
    k_rmsnorm<<<T_, 256, 0, stream>>>(out, ln2, xnorm, xh, xl);
    k_router<<<T_, 256, 0, stream>>>(xnorm, rw, rb, topi, topw);
    k_zero<<<1, 64, 0, stream>>>(counts);
    k_hist<<<(T_ * TOPK_ + 255) / 256, 256, 0, stream>>>(topi, counts);
    k_scan<<<1, 1, 0, stream>>>(counts, offs, cursor);
    k_scatter<<<(T_ * TOPK_ + 255) / 256, 256, 0, stream>>>(topi, topw, cursor, perm, pwb);
    k_moe1<<<dim3(16, 16, E_), 256, 0, stream>>>(xh, gupt, gub, perm, counts, offs, gatedh);
    k_moe2<<<dim3(16, 16, E_), 256, 0, stream>>>(gatedh, dwnt, dwb, perm, pwb, counts, offs, out);
}

// Round 5
// 1366.608 us; speedup vs baseline: 3.5495x; 1.2007x over previous
//
#include <hip/hip_runtime.h>
#include <hip/hip_bf16.h>
#include <cstdint>

#define B_    2
#define S_    1024
#define H_    2048
#define NH_   32
#define NKV_  8
#define HD_   64
#define T_    (B_*S_)
#define E_    16
#define ED_   1024
#define TOPK_ 4
#define WIN_  128
#define LIMIT_ 7.0f
#define ALPHA_ 1.702f
#define EPS_   1e-6f
#define SCALE_ 0.125f  /* HD^-0.5 */
#define SPLIT_ 2048.0f
#define INV_SPLIT_ 4.8828125e-4f

typedef _Float16 half8 __attribute__((ext_vector_type(8)));
typedef _Float16 half4v __attribute__((ext_vector_type(4)));
typedef float floatx4 __attribute__((ext_vector_type(4)));

__device__ __forceinline__ void gload16(const void* g, void* l) {
    __builtin_amdgcn_global_load_lds((const __attribute__((address_space(1))) void*)g,
                                     (__attribute__((address_space(3))) void*)l, 16, 0, 0);
}

// bijective chunked XCD swizzle (nwg % 8 == 0): consecutive logical tiles -> same XCD
__device__ __forceinline__ int xcd_swz(int bid, int nwg) {
    int cpx = nwg >> 3;
    return (bid & 7) * cpx + (bid >> 3);
}

// ================= split-fp16 GEMM (fp32-accurate): C = A@B^T + bias (+res) ====
// A,B pre-split: x ~= hi + lo/2048. acc1 = ah*bh; acc2 = ah*bl + al*bh.
// 128x128 tile, BK=32, 4 waves (2x2), 4x4 frags of 16x16x32 f16 MFMA.
__global__ __launch_bounds__(256) void k_gemm_sp(const _Float16* __restrict__ Ah,
                                                 const _Float16* __restrict__ Al,
                                                 const _Float16* __restrict__ Bh,
                                                 const _Float16* __restrict__ Bl,
                                                 const float* __restrict__ bias,
                                                 const float* __restrict__ res,
                                                 float* __restrict__ C, int N, int K) {
    __shared__ _Float16 Ahs[128 * 32];
    __shared__ _Float16 Als[128 * 32];
    __shared__ _Float16 Bhs[128 * 32];
    __shared__ _Float16 Bls[128 * 32];
    const int tid = threadIdx.x;
    const int lane = tid & 63;
    const int wid = tid >> 6;
    const int wr = wid >> 1, wc = wid & 1;
    const int wg = xcd_swz(blockIdx.x, gridDim.x);
    const int row0 = (wg & 15) * 128, col0 = (wg >> 4) * 128;   // m fastest: share B panel
    floatx4 acc1[4][4], acc2[4][4];
    for (int m = 0; m < 4; ++m)
        for (int n = 0; n < 4; ++n) { acc1[m][n] = (floatx4)0.f; acc2[m][n] = (floatx4)0.f; }
    const int rL = tid >> 2, koff = (tid & 3) * 8;
    const size_t o0 = (size_t)(row0 + rL) * K + koff;
    const size_t o1 = (size_t)(row0 + 64 + rL) * K + koff;
    const size_t p0 = (size_t)(col0 + rL) * K + koff;
    const size_t p1 = (size_t)(col0 + 64 + rL) * K + koff;
    for (int k0 = 0; k0 < K; k0 += 32) {
        __syncthreads();
        gload16(Ah + o0 + k0, Ahs + tid * 8); gload16(Ah + o1 + k0, Ahs + 2048 + tid * 8);
        gload16(Al + o0 + k0, Als + tid * 8); gload16(Al + o1 + k0, Als + 2048 + tid * 8);
        gload16(Bh + p0 + k0, Bhs + tid * 8); gload16(Bh + p1 + k0, Bhs + 2048 + tid * 8);
        gload16(Bl + p0 + k0, Bls + tid * 8); gload16(Bl + p1 + k0, Bls + 2048 + tid * 8);
        __syncthreads();
        const int lk = (lane >> 4) * 8;
        half8 ah[4], al[4], bh[4], bl[4];
#pragma unroll
        for (int m = 0; m < 4; ++m) {
            int ro = (wr * 64 + m * 16 + (lane & 15)) * 32 + lk;
            ah[m] = *(const half8*)&Ahs[ro];
            al[m] = *(const half8*)&Als[ro];
        }
#pragma unroll
        for (int n = 0; n < 4; ++n) {
            int ro = (wc * 64 + n * 16 + (lane & 15)) * 32 + lk;
            bh[n] = *(const half8*)&Bhs[ro];
            bl[n] = *(const half8*)&Bls[ro];
        }
#pragma unroll
        for (int m = 0; m < 4; ++m)
#pragma unroll
            for (int n = 0; n < 4; ++n) {
                acc1[m][n] = __builtin_amdgcn_mfma_f32_16x16x32_f16(ah[m], bh[n], acc1[m][n], 0, 0, 0);
                acc2[m][n] = __builtin_amdgcn_mfma_f32_16x16x32_f16(ah[m], bl[n], acc2[m][n], 0, 0, 0);
                acc2[m][n] = __builtin_amdgcn_mfma_f32_16x16x32_f16(al[m], bh[n], acc2[m][n], 0, 0, 0);
            }
    }
#pragma unroll
    for (int mf = 0; mf < 4; ++mf)
#pragma unroll
        for (int i = 0; i < 4; ++i) {
            int r = row0 + wr * 64 + mf * 16 + ((lane >> 4) << 2) + i;
#pragma unroll
            for (int nf = 0; nf < 4; ++nf) {
                int c = col0 + wc * 64 + nf * 16 + (lane & 15);
                float v = acc1[mf][nf][i] + acc2[mf][nf][i] * INV_SPLIT_ + bias[c];
                if (res) v += res[(size_t)r * N + c];
                C[(size_t)r * N + c] = v;
            }
        }
}

// ================= MoE MFMA core: BK=64, XOR-swizzled LDS, 128x128 tile ========
// Staging: 8x gload16/step; row contributes 128B/step (2x DRAM granularity vs BK=32).
// LDS [row][64] f16 would be 16-way conflict on ds_read_b128 -> both-sides XOR:
// source chunk (tid&7)^(row&7) loaded into linear LDS; read XORs the same way.
#define MOE_PROLOG() \
    __shared__ _Float16 As[128 * 64]; \
    __shared__ _Float16 Bs[128 * 64]; \
    const int tid = threadIdx.x; \
    const int lane = tid & 63; \
    const int wid = tid >> 6; \
    const int wr = wid >> 1, wc = wid & 1; \
    const int rloc = tid >> 3; \
    const int ksw = ((tid & 7) ^ (rloc & 7)) * 8; \
    floatx4 acc[4][4]; \
    for (int m = 0; m < 4; ++m) for (int n = 0; n < 4; ++n) acc[m][n] = (floatx4)0.f;

#define MOE_KLOOP(KD) \
    for (int k0 = 0; k0 < (KD); k0 += 64) { \
        __syncthreads(); \
        _Pragma("unroll") for (int c = 0; c < 4; ++c) { \
            gload16(asrc[c] + k0, As + c * 2048 + tid * 8); \
            gload16(bsrc[c] + k0, Bs + c * 2048 + tid * 8); \
        } \
        __syncthreads(); \
        _Pragma("unroll") for (int s = 0; s < 2; ++s) { \
            const int gc = ((s * 4 + (lane >> 4)) ^ (lane & 7)) * 8; \
            half8 a[4], b[4]; \
            _Pragma("unroll") for (int m = 0; m < 4; ++m) \
                a[m] = *(const half8*)&As[(wr * 64 + m * 16 + (lane & 15)) * 64 + gc]; \
            _Pragma("unroll") for (int n = 0; n < 4; ++n) \
                b[n] = *(const half8*)&Bs[(wc * 64 + n * 16 + (lane & 15)) * 64 + gc]; \
            _Pragma("unroll") for (int m = 0; m < 4; ++m) \
                _Pragma("unroll") for (int n = 0; n < 4; ++n) \
                    acc[m][n] = __builtin_amdgcn_mfma_f32_16x16x32_f16(a[m], b[n], acc[m][n], 0, 0, 0); \
        } \
    }

// MoE GEMM1: gathered A rows via perm; fused GLU epilogue -> gated f16 [slot][1024]
__global__ __launch_bounds__(256) void k_moe1(const _Float16* __restrict__ X,
                                              const _Float16* __restrict__ W,
                                              const float* __restrict__ bias,
                                              const int* __restrict__ perm,
                                              const int* __restrict__ counts,
                                              const int* __restrict__ offs,
                                              _Float16* __restrict__ gated) {
    const int wg = xcd_swz(blockIdx.x, 4096);
    const int e = wg >> 8;
    const int ne = counts[e];
    const int m0 = (wg & 15) * 128;
    if (m0 >= ne) return;
    const int base = offs[e];
    const int col0 = ((wg >> 4) & 15) * 128;
    MOE_PROLOG();
    const _Float16* asrc[4];
    const _Float16* bsrc[4];
#pragma unroll
    for (int c = 0; c < 4; ++c) {
        int t = perm[base + min(m0 + c * 32 + rloc, ne - 1)];
        asrc[c] = X + (size_t)t * H_ + ksw;
        bsrc[c] = W + ((size_t)e * 2048 + col0 + c * 32 + rloc) * H_ + ksw;
    }
    MOE_KLOOP(H_);
#pragma unroll
    for (int mf = 0; mf < 4; ++mf)
#pragma unroll
        for (int i = 0; i < 4; ++i) {
            int r = m0 + wr * 64 + mf * 16 + ((lane >> 4) << 2) + i;
            bool ok = r < ne;
            int slot = base + r;
#pragma unroll
            for (int nf = 0; nf < 4; ++nf) {
                int c = col0 + wc * 64 + nf * 16 + (lane & 15);
                float v = acc[mf][nf][i] + bias[e * 2048 + c];
                float o = __shfl_xor(v, 1);   // pair even(gate)/odd(up) cols
                if (ok && !(lane & 1)) {
                    float gt = fminf(v, LIMIT_);
                    float up = fminf(fmaxf(o, -LIMIT_), LIMIT_);
                    float sg = 1.f / (1.f + __expf(-ALPHA_ * gt));
                    gated[(size_t)slot * ED_ + (c >> 1)] = (_Float16)((up + 1.f) * (gt * sg));
                }
            }
        }
}

// MoE GEMM2: contiguous slot rows; epilogue scale-by-routing + bias + atomicAdd
__global__ __launch_bounds__(256) void k_moe2(const _Float16* __restrict__ G,
                                              const _Float16* __restrict__ W,
                                              const float* __restrict__ bias,
                                              const int* __restrict__ perm,
                                              const float* __restrict__ pw,
                                              const int* __restrict__ counts,
                                              const int* __restrict__ offs,
                                              float* __restrict__ out) {
    const int wg = xcd_swz(blockIdx.x, 4096);
    const int e = wg >> 8;
    const int ne = counts[e];
    const int m0 = (wg & 15) * 128;
    if (m0 >= ne) return;
    const int base = offs[e];
    const int col0 = ((wg >> 4) & 15) * 128;
    MOE_PROLOG();
    const _Float16* asrc[4];
    const _Float16* bsrc[4];
#pragma unroll
    for (int c = 0; c < 4; ++c) {
        int s = base + min(m0 + c * 32 + rloc, ne - 1);
        asrc[c] = G + (size_t)s * ED_ + ksw;
        bsrc[c] = W + ((size_t)e * H_ + col0 + c * 32 + rloc) * ED_ + ksw;
    }
    MOE_KLOOP(ED_);
#pragma unroll
    for (int mf = 0; mf < 4; ++mf)
#pragma unroll
        for (int i = 0; i < 4; ++i) {
            int r = m0 + wr * 64 + mf * 16 + ((lane >> 4) << 2) + i;
            if (r >= ne) continue;
            int slot = base + r;
            int tok = perm[slot];
            float wgt = pw[slot];
#pragma unroll
            for (int nf = 0; nf < 4; ++nf) {
                int c = col0 + wc * 64 + nf * 16 + (lane & 15);
                atomicAdd(&out[(size_t)tok * H_ + c], wgt * (acc[mf][nf][i] + bias[e * H_ + c]));
            }
        }
}

// ================= conversion kernels =================
// split convert: x -> hi(fp16), lo(fp16, residual * 2048)
__global__ __launch_bounds__(256) void k_cvts(const float* __restrict__ s,
                                              _Float16* __restrict__ dh,
                                              _Float16* __restrict__ dl, int n8) {
    int i = blockIdx.x * 256 + threadIdx.x;
    if (i >= n8) return;
    float4 x = ((const float4*)s)[i * 2], y = ((const float4*)s)[i * 2 + 1];
    float xs[8] = {x.x, x.y, x.z, x.w, y.x, y.y, y.z, y.w};
    half8 h, l;
#pragma unroll
    for (int j = 0; j < 8; ++j) {
        _Float16 hv = (_Float16)xs[j];
        h[j] = hv;
        l[j] = (_Float16)((xs[j] - (float)hv) * SPLIT_);
    }
    ((half8*)dh)[i] = h;
    ((half8*)dl)[i] = l;
}

// transpose-convert: src [e][K][N] fp32 -> dst [e][N][K] f16
__global__ __launch_bounds__(256) void k_cvt_t(const float* __restrict__ src,
                                               _Float16* __restrict__ dst, int K, int N) {
    const int e = blockIdx.z;
    const int k0 = blockIdx.x * 32, n0 = blockIdx.y * 32;
    __shared__ float t[32][33];
    const int tid = threadIdx.x;
    {
        int kr = tid >> 3, nc = (tid & 7) * 4;
        float4 v = *(const float4*)(src + ((size_t)e * K + k0 + kr) * N + n0 + nc);
        t[kr][nc] = v.x; t[kr][nc + 1] = v.y; t[kr][nc + 2] = v.z; t[kr][nc + 3] = v.w;
    }
    __syncthreads();
    {
        int nr = tid >> 3, kc = (tid & 7) * 4;
        half4v o;
        o[0] = (_Float16)t[kc + 0][nr];
        o[1] = (_Float16)t[kc + 1][nr];
        o[2] = (_Float16)t[kc + 2][nr];
        o[3] = (_Float16)t[kc + 3][nr];
        *(half4v*)(dst + ((size_t)e * N + n0 + nr) * K + k0 + kc) = o;
    }
}

// ================= RMSNorm (fp32 + split f16 outputs) =================
__global__ __launch_bounds__(256) void k_rmsnorm(const float* __restrict__ x,
                                                 const float* __restrict__ w,
                                                 float* __restrict__ y,
                                                 _Float16* __restrict__ yh,
                                                 _Float16* __restrict__ yl) {
    int t = blockIdx.x;
    const float* row = x + (size_t)t * H_;
    float ss = 0.f;
    for (int i = threadIdx.x; i < H_ / 4; i += 256) {
        float4 v = ((const float4*)row)[i];
        ss += v.x * v.x + v.y * v.y + v.z * v.z + v.w * v.w;
    }
    for (int o = 32; o >= 1; o >>= 1) ss += __shfl_xor(ss, o);
    __shared__ float wsum[4];
    if ((threadIdx.x & 63) == 0) wsum[threadIdx.x >> 6] = ss;
    __syncthreads();
    float tot = wsum[0] + wsum[1] + wsum[2] + wsum[3];
    float r = rsqrtf(tot / (float)H_ + EPS_);
    float* yrow = y + (size_t)t * H_;
    _Float16* hrow = yh + (size_t)t * H_;
    _Float16* lrow = yl + (size_t)t * H_;
    for (int i = threadIdx.x; i < H_ / 4; i += 256) {
        float4 v = ((const float4*)row)[i];
        float4 g = ((const float4*)w)[i];
        float o4[4];
        o4[0] = v.x * r * g.x; o4[1] = v.y * r * g.y;
        o4[2] = v.z * r * g.z; o4[3] = v.w * r * g.w;
        ((float4*)yrow)[i] = *(float4*)o4;
        half4v h4, l4;
#pragma unroll
        for (int j = 0; j < 4; ++j) {
            _Float16 hv = (_Float16)o4[j];
            h4[j] = hv;
            l4[j] = (_Float16)((o4[j] - (float)hv) * SPLIT_);
        }
        ((half4v*)hrow)[i] = h4;
        ((half4v*)lrow)[i] = l4;
    }
}

// ================= RoPE =================
__global__ __launch_bounds__(256) void k_rope(float* __restrict__ q, float* __restrict__ k,
                                              const float* __restrict__ cs,
                                              const float* __restrict__ sn) {
    int t = blockIdx.x;
    size_t cb = (size_t)t * HD_;
    for (int p = threadIdx.x; p < (NH_ + NKV_) * 32; p += 256) {
        int head = p >> 5, d = p & 31;
        float c1 = cs[cb + d],      s1v = sn[cb + d];
        float c2 = cs[cb + d + 32], s2v = sn[cb + d + 32];
        float* arr; size_t idx;
        if (head < NH_) { arr = q; idx = (size_t)t * (NH_ * HD_) + head * HD_ + d; }
        else            { arr = k; idx = (size_t)t * (NKV_ * HD_) + (head - NH_) * HD_ + d; }
        float x1 = arr[idx], x2 = arr[idx + 32];
        arr[idx]      = x1 * c1 - x2 * s1v;
        arr[idx + 32] = x2 * c2 + x1 * s2v;
    }
}

// ================= Attention (fp32 compute, fp32 out) =================
__global__ __launch_bounds__(64) void k_attn(const float* __restrict__ q,
                                             const float* __restrict__ k,
                                             const float* __restrict__ v,
                                             const float* __restrict__ sinks,
                                             float* __restrict__ out) {
    int gid = blockIdx.x;
    int h = gid & (NH_ - 1);
    int ti = gid >> 5;
    int i = ti & (S_ - 1);
    int kvh = h >> 2;
    int lane = threadIdx.x;
    int j0 = max(0, i - (WIN_ - 1));
    __shared__ float qs[HD_];
    __shared__ float ps[2 * 64];
    qs[lane] = q[(size_t)ti * (NH_ * HD_) + h * HD_ + lane];
    __syncthreads();
    int tb = ti - i;
    const float* kb2 = k + (size_t)tb * (NKV_ * HD_) + kvh * HD_;
    int j1 = j0 + lane, j2 = j0 + lane + 64;
    float s1 = -3.0e38f, s2 = -3.0e38f;
    if (j1 <= i) {
        const float* kr = kb2 + (size_t)j1 * (NKV_ * HD_);
        float a = 0.f;
#pragma unroll
        for (int d4 = 0; d4 < HD_; d4 += 4) {
            float4 kv4 = *(const float4*)(kr + d4);
            a += qs[d4] * kv4.x + qs[d4 + 1] * kv4.y + qs[d4 + 2] * kv4.z + qs[d4 + 3] * kv4.w;
        }
        s1 = a * SCALE_;
    }
    if (j2 <= i) {
        const float* kr = kb2 + (size_t)j2 * (NKV_ * HD_);
        float a = 0.f;
#pragma unroll
        for (int d4 = 0; d4 < HD_; d4 += 4) {
            float4 kv4 = *(const float4*)(kr + d4);
            a += qs[d4] * kv4.x + qs[d4 + 1] * kv4.y + qs[d4 + 2] * kv4.z + qs[d4 + 3] * kv4.w;
        }
        s2 = a * SCALE_;
    }
    float sink = sinks[h];
    float lm = fmaxf(s1, s2);
    for (int o = 32; o >= 1; o >>= 1) lm = fmaxf(lm, __shfl_xor(lm, o));
    float m = fmaxf(lm, sink);
    float p1 = (j1 <= i) ? __expf(s1 - m) : 0.f;
    float p2 = (j2 <= i) ? __expf(s2 - m) : 0.f;
    float lsum = p1 + p2;
    for (int o = 32; o >= 1; o >>= 1) lsum += __shfl_xor(lsum, o);
    float denom = lsum + __expf(sink - m);
    ps[lane] = p1; ps[lane + 64] = p2;
    __syncthreads();
    int cnt = i - j0 + 1;
    const float* vb2 = v + (size_t)(tb + j0) * (NKV_ * HD_) + kvh * HD_ + lane;
    float oa = 0.f;
    for (int j = 0; j < cnt; j++) oa += ps[j] * vb2[(size_t)j * (NKV_ * HD_)];
    out[(size_t)ti * (NH_ * HD_) + h * HD_ + lane] = oa / denom;
}

// ================= Router =================
__global__ __launch_bounds__(256) void k_router(const float* __restrict__ x,
                                                const float* __restrict__ rw,
                                                const float* __restrict__ rb,
                                                int* __restrict__ topi,
                                                float* __restrict__ topw) {
    int t = blockIdx.x;
    int e = threadIdx.x >> 4, g = threadIdx.x & 15;
    const float* row = x + (size_t)t * H_;
    const float* wr = rw + (size_t)e * H_;
    float acc = 0.f;
    int kbeg = g * (H_ / 16);
    for (int kk = 0; kk < H_ / 16; kk += 4) {
        float4 xv = *(const float4*)(row + kbeg + kk);
        float4 wv = *(const float4*)(wr + kbeg + kk);
        acc += xv.x * wv.x + xv.y * wv.y + xv.z * wv.z + xv.w * wv.w;
    }
    __shared__ float part[16][17];
    part[e][g] = acc;
    __syncthreads();
    __shared__ float logits[16];
    if (threadIdx.x < 16) {
        float s2 = rb[threadIdx.x];
        for (int g2 = 0; g2 < 16; g2++) s2 += part[threadIdx.x][g2];
        logits[threadIdx.x] = s2;
    }
    __syncthreads();
    if (threadIdx.x == 0) {
        float tv[4]; int ti4[4];
        unsigned used = 0;
        for (int s3 = 0; s3 < 4; s3++) {
            float best = -3.0e38f; int bi = 0;
            for (int e2 = 0; e2 < 16; e2++)
                if (!((used >> e2) & 1) && logits[e2] > best) { best = logits[e2]; bi = e2; }
            used |= 1u << bi; tv[s3] = best; ti4[s3] = bi;
        }
        float mx = tv[0], pe[4], sum = 0.f;
        for (int s3 = 0; s3 < 4; s3++) { pe[s3] = __expf(tv[s3] - mx); sum += pe[s3]; }
        for (int s3 = 0; s3 < 4; s3++) {
            topw[t * 4 + s3] = pe[s3] / sum;
            topi[t * 4 + s3] = ti4[s3];
        }
    }
}

// ================= MoE prep =================
__global__ void k_zero(int* counts) { if (threadIdx.x < E_) counts[threadIdx.x] = 0; }

__global__ void k_hist(const int* __restrict__ topi, int* counts) {
    int g = blockIdx.x * 256 + threadIdx.x;
    if (g < T_ * TOPK_) atomicAdd(&counts[topi[g]], 1);
}

__global__ void k_scan(const int* __restrict__ counts, int* offs, int* cursor) {
    if (threadIdx.x == 0 && blockIdx.x == 0) {
        int run = 0;
        for (int e = 0; e < E_; e++) { offs[e] = run; cursor[e] = run; run += counts[e]; }
    }
}

__global__ void k_scatter(const int* __restrict__ topi, const float* __restrict__ topw,
                          int* cursor, int* __restrict__ perm, float* __restrict__ pw) {
    int g = blockIdx.x * 256 + threadIdx.x;
    if (g >= T_ * TOPK_) return;
    int e = topi[g];
    int pos = atomicAdd(&cursor[e], 1);
    perm[pos] = g >> 2;
    pw[pos] = topw[g];
}

// ================= launch =================
extern "C" void kernel_launch(void* const* d_in, const int* in_sizes, int n_in,
                              void* d_out, int out_size, void* d_ws, size_t ws_size,
                              hipStream_t stream) {
    const float* hidden = (const float*)d_in[0];
    const float* cosp  = (const float*)d_in[1];
    const float* sinp  = (const float*)d_in[2];
    const float* ln1   = (const float*)d_in[3];
    const float* ln2   = (const float*)d_in[4];
    const float* qw    = (const float*)d_in[5];
    const float* qb    = (const float*)d_in[6];
    const float* kw    = (const float*)d_in[7];
    const float* kbia  = (const float*)d_in[8];
    const float* vw    = (const float*)d_in[9];
    const float* vbia  = (const float*)d_in[10];
    const float* ow    = (const float*)d_in[11];
    const float* ob    = (const float*)d_in[12];
    const float* sinks = (const float*)d_in[13];
    const float* rw    = (const float*)d_in[14];
    const float* rb    = (const float*)d_in[15];
    const float* gup   = (const float*)d_in[16];
    const float* gub   = (const float*)d_in[17];
    const float* dwp   = (const float*)d_in[18];
    const float* dwb   = (const float*)d_in[19];
    float* out = (float*)d_out;

    char* p = (char*)d_ws;
    auto alloc = [&](size_t bytes) { char* r = p; p += (bytes + 255) & ~(size_t)255; return r; };
    float*     xnorm  = (float*)alloc((size_t)T_ * H_ * 4);
    _Float16*  xh     = (_Float16*)alloc((size_t)T_ * H_ * 2);
    _Float16*  xl     = (_Float16*)alloc((size_t)T_ * H_ * 2);
    float*     qbuf   = (float*)alloc((size_t)T_ * NH_ * HD_ * 4);
    float*     kbuf   = (float*)alloc((size_t)T_ * NKV_ * HD_ * 4);
    float*     vbuf   = (float*)alloc((size_t)T_ * NKV_ * HD_ * 4);
    float*     attnb  = (float*)alloc((size_t)T_ * NH_ * HD_ * 4);
    _Float16*  ath    = (_Float16*)alloc((size_t)T_ * NH_ * HD_ * 2);
    _Float16*  atl    = (_Float16*)alloc((size_t)T_ * NH_ * HD_ * 2);
    _Float16*  gatedh = (_Float16*)alloc((size_t)T_ * TOPK_ * ED_ * 2);
    _Float16*  qwh    = (_Float16*)alloc((size_t)2048 * H_ * 2);
    _Float16*  qwl    = (_Float16*)alloc((size_t)2048 * H_ * 2);
    _Float16*  kwh    = (_Float16*)alloc((size_t)512 * H_ * 2);
    _Float16*  kwl    = (_Float16*)alloc((size_t)512 * H_ * 2);
    _Float16*  vwh    = (_Float16*)alloc((size_t)512 * H_ * 2);
    _Float16*  vwl    = (_Float16*)alloc((size_t)512 * H_ * 2);
    _Float16*  owh    = (_Float16*)alloc((size_t)H_ * 2048 * 2);
    _Float16*  owl    = (_Float16*)alloc((size_t)H_ * 2048 * 2);
    _Float16*  gupt   = (_Float16*)alloc((size_t)E_ * 2048 * H_ * 2);
    _Float16*  dwnt   = (_Float16*)alloc((size_t)E_ * H_ * ED_ * 2);
    float*     topw   = (float*)alloc(T_ * TOPK_ * 4);
    float*     pwb    = (float*)alloc(T_ * TOPK_ * 4);
    int*       topi   = (int*)alloc(T_ * TOPK_ * 4);
    int*       perm   = (int*)alloc(T_ * TOPK_ * 4);
    int*       counts = (int*)alloc(E_ * 4);
    int*       offs   = (int*)alloc(E_ * 4);
    int*       cursor = (int*)alloc(E_ * 4);

    // weight conversions
    k_cvts<<<2048, 256, 0, stream>>>(qw, qwh, qwl, 2048 * H_ / 8);
    k_cvts<<<512, 256, 0, stream>>>(kw, kwh, kwl, 512 * H_ / 8);
    k_cvts<<<512, 256, 0, stream>>>(vw, vwh, vwl, 512 * H_ / 8);
    k_cvts<<<2048, 256, 0, stream>>>(ow, owh, owl, H_ * 2048 / 8);
    k_cvt_t<<<dim3(H_ / 32, 2048 / 32, E_), 256, 0, stream>>>(gup, gupt, H_, 2048);
    k_cvt_t<<<dim3(ED_ / 32, H_ / 32, E_), 256, 0, stream>>>(dwp, dwnt, ED_, H_);

    k_rmsnorm<<<T_, 256, 0, stream>>>(hidden, ln1, xnorm, xh, xl);
    k_gemm_sp<<<256, 256, 0, stream>>>(xh, xl, qwh, qwl, qb, nullptr, qbuf, 2048, H_);
    k_gemm_sp<<<64, 256, 0, stream>>>(xh, xl, kwh, kwl, kbia, nullptr, kbuf, 512, H_);
    k_gemm_sp<<<64, 256, 0, stream>>>(xh, xl, vwh, vwl, vbia, nullptr, vbuf, 512, H_);
    k_rope<<<T_, 256, 0, stream>>>(qbuf, kbuf, cosp, sinp);
    k_attn<<<T_ * NH_, 64, 0, stream>>>(qbuf, kbuf, vbuf, sinks, attnb);
    k_cvts<<<2048, 256, 0, stream>>>(attnb, ath, atl, T_ * NH_ * HD_ / 8);
    k_gemm_sp<<<256, 256, 0, stream>>>(ath, atl, owh, owl, ob, hidden, out, 2048, H_);
    k_rmsnorm<<<T_, 256, 0, stream>>>(out, ln2, xnorm, xh, xl);
    k_router<<<T_, 256, 0, stream>>>(xnorm, rw, rb, topi, topw);
    k_zero<<<1, 64, 0, stream>>>(counts);
    k_hist<<<(T_ * TOPK_ + 255) / 256, 256, 0, stream>>>(topi, counts);
    k_scan<<<1, 1, 0, stream>>>(counts, offs, cursor);
    k_scatter<<<(T_ * TOPK_ + 255) / 256, 256, 0, stream>>>(topi, topw, cursor, perm, pwb);
    k_moe1<<<4096, 256, 0, stream>>>(xh, gupt, gub, perm, counts, offs, gatedh);
    k_moe2<<<4096, 256, 0, stream>>>(gatedh, dwnt, dwb, perm, pwb, counts, offs, out);
}

// Round 6
// 1123.840 us; speedup vs baseline: 4.3163x; 1.2160x over previous
//
#include <hip/hip_runtime.h>
#include <hip/hip_bf16.h>
#include <cstdint>

#define B_    2
#define S_    1024
#define H_    2048
#define NH_   32
#define NKV_  8
#define HD_   64
#define T_    (B_*S_)
#define E_    16
#define ED_   1024
#define TOPK_ 4
#define WIN_  128
#define LIMIT_ 7.0f
#define ALPHA_ 1.702f
#define EPS_   1e-6f
#define SCALE_ 0.125f  /* HD^-0.5 */
#define SPLIT_ 2048.0f
#define INV_SPLIT_ 4.8828125e-4f

typedef _Float16 half8 __attribute__((ext_vector_type(8)));
typedef _Float16 half4v __attribute__((ext_vector_type(4)));
typedef float floatx4 __attribute__((ext_vector_type(4)));

#define MF16(a,b,c) __builtin_amdgcn_mfma_f32_16x16x32_f16(a,b,c,0,0,0)

__device__ __forceinline__ void gload16(const void* g, void* l) {
    __builtin_amdgcn_global_load_lds((const __attribute__((address_space(1))) void*)g,
                                     (__attribute__((address_space(3))) void*)l, 16, 0, 0);
}

// bijective chunked XCD swizzle (nwg % 8 == 0)
__device__ __forceinline__ int xcd_swz(int bid, int nwg) {
    int cpx = nwg >> 3;
    return (bid & 7) * cpx + (bid >> 3);
}

// ================= split-fp16 GEMM (fp32-accurate): C = A@B^T + bias (+res) ====
__global__ __launch_bounds__(256) void k_gemm_sp(const _Float16* __restrict__ Ah,
                                                 const _Float16* __restrict__ Al,
                                                 const _Float16* __restrict__ Bh,
                                                 const _Float16* __restrict__ Bl,
                                                 const float* __restrict__ bias,
                                                 const float* __restrict__ res,
                                                 float* __restrict__ C, int N, int K) {
    __shared__ _Float16 Ahs[128 * 32];
    __shared__ _Float16 Als[128 * 32];
    __shared__ _Float16 Bhs[128 * 32];
    __shared__ _Float16 Bls[128 * 32];
    const int tid = threadIdx.x;
    const int lane = tid & 63;
    const int wid = tid >> 6;
    const int wr = wid >> 1, wc = wid & 1;
    const int wg = xcd_swz(blockIdx.x, gridDim.x);
    const int row0 = (wg & 15) * 128, col0 = (wg >> 4) * 128;
    floatx4 acc1[4][4], acc2[4][4];
    for (int m = 0; m < 4; ++m)
        for (int n = 0; n < 4; ++n) { acc1[m][n] = (floatx4)0.f; acc2[m][n] = (floatx4)0.f; }
    const int rL = tid >> 2, koff = (tid & 3) * 8;
    const size_t o0 = (size_t)(row0 + rL) * K + koff;
    const size_t o1 = (size_t)(row0 + 64 + rL) * K + koff;
    const size_t p0 = (size_t)(col0 + rL) * K + koff;
    const size_t p1 = (size_t)(col0 + 64 + rL) * K + koff;
    for (int k0 = 0; k0 < K; k0 += 32) {
        __syncthreads();
        gload16(Ah + o0 + k0, Ahs + tid * 8); gload16(Ah + o1 + k0, Ahs + 2048 + tid * 8);
        gload16(Al + o0 + k0, Als + tid * 8); gload16(Al + o1 + k0, Als + 2048 + tid * 8);
        gload16(Bh + p0 + k0, Bhs + tid * 8); gload16(Bh + p1 + k0, Bhs + 2048 + tid * 8);
        gload16(Bl + p0 + k0, Bls + tid * 8); gload16(Bl + p1 + k0, Bls + 2048 + tid * 8);
        __syncthreads();
        const int lk = (lane >> 4) * 8;
        half8 ah[4], al[4], bh[4], bl[4];
#pragma unroll
        for (int m = 0; m < 4; ++m) {
            int ro = (wr * 64 + m * 16 + (lane & 15)) * 32 + lk;
            ah[m] = *(const half8*)&Ahs[ro];
            al[m] = *(const half8*)&Als[ro];
        }
#pragma unroll
        for (int n = 0; n < 4; ++n) {
            int ro = (wc * 64 + n * 16 + (lane & 15)) * 32 + lk;
            bh[n] = *(const half8*)&Bhs[ro];
            bl[n] = *(const half8*)&Bls[ro];
        }
#pragma unroll
        for (int m = 0; m < 4; ++m)
#pragma unroll
            for (int n = 0; n < 4; ++n) {
                acc1[m][n] = MF16(ah[m], bh[n], acc1[m][n]);
                acc2[m][n] = MF16(ah[m], bl[n], acc2[m][n]);
                acc2[m][n] = MF16(al[m], bh[n], acc2[m][n]);
            }
    }
#pragma unroll
    for (int mf = 0; mf < 4; ++mf)
#pragma unroll
        for (int i = 0; i < 4; ++i) {
            int r = row0 + wr * 64 + mf * 16 + ((lane >> 4) << 2) + i;
#pragma unroll
            for (int nf = 0; nf < 4; ++nf) {
                int c = col0 + wc * 64 + nf * 16 + (lane & 15);
                float v = acc1[mf][nf][i] + acc2[mf][nf][i] * INV_SPLIT_ + bias[c];
                if (res) v += res[(size_t)r * N + c];
                C[(size_t)r * N + c] = v;
            }
        }
}

// ================= MoE MFMA core: BK=64, XOR-swizzled LDS, 128x128 tile ========
#define MOE_PROLOG() \
    __shared__ _Float16 As[128 * 64]; \
    __shared__ _Float16 Bs[128 * 64]; \
    const int tid = threadIdx.x; \
    const int lane = tid & 63; \
    const int wid = tid >> 6; \
    const int wr = wid >> 1, wc = wid & 1; \
    const int rloc = tid >> 3; \
    const int ksw = ((tid & 7) ^ (rloc & 7)) * 8; \
    floatx4 acc[4][4]; \
    for (int m = 0; m < 4; ++m) for (int n = 0; n < 4; ++n) acc[m][n] = (floatx4)0.f;

#define MOE_KLOOP(KD) \
    for (int k0 = 0; k0 < (KD); k0 += 64) { \
        __syncthreads(); \
        _Pragma("unroll") for (int c = 0; c < 4; ++c) { \
            gload16(asrc[c] + k0, As + c * 2048 + tid * 8); \
            gload16(bsrc[c] + k0, Bs + c * 2048 + tid * 8); \
        } \
        __syncthreads(); \
        _Pragma("unroll") for (int s = 0; s < 2; ++s) { \
            const int gc = ((s * 4 + (lane >> 4)) ^ (lane & 7)) * 8; \
            half8 a[4], b[4]; \
            _Pragma("unroll") for (int m = 0; m < 4; ++m) \
                a[m] = *(const half8*)&As[(wr * 64 + m * 16 + (lane & 15)) * 64 + gc]; \
            _Pragma("unroll") for (int n = 0; n < 4; ++n) \
                b[n] = *(const half8*)&Bs[(wc * 64 + n * 16 + (lane & 15)) * 64 + gc]; \
            _Pragma("unroll") for (int m = 0; m < 4; ++m) \
                _Pragma("unroll") for (int n = 0; n < 4; ++n) \
                    acc[m][n] = MF16(a[m], b[n], acc[m][n]); \
        } \
    }

__global__ __launch_bounds__(256) void k_moe1(const _Float16* __restrict__ X,
                                              const _Float16* __restrict__ W,
                                              const float* __restrict__ bias,
                                              const int* __restrict__ perm,
                                              const int* __restrict__ counts,
                                              const int* __restrict__ offs,
                                              _Float16* __restrict__ gated) {
    const int wg = xcd_swz(blockIdx.x, 4096);
    const int e = wg >> 8;
    const int ne = counts[e];
    const int m0 = (wg & 15) * 128;
    if (m0 >= ne) return;
    const int base = offs[e];
    const int col0 = ((wg >> 4) & 15) * 128;
    MOE_PROLOG();
    const _Float16* asrc[4];
    const _Float16* bsrc[4];
#pragma unroll
    for (int c = 0; c < 4; ++c) {
        int t = perm[base + min(m0 + c * 32 + rloc, ne - 1)];
        asrc[c] = X + (size_t)t * H_ + ksw;
        bsrc[c] = W + ((size_t)e * 2048 + col0 + c * 32 + rloc) * H_ + ksw;
    }
    MOE_KLOOP(H_);
#pragma unroll
    for (int mf = 0; mf < 4; ++mf)
#pragma unroll
        for (int i = 0; i < 4; ++i) {
            int r = m0 + wr * 64 + mf * 16 + ((lane >> 4) << 2) + i;
            bool ok = r < ne;
            int slot = base + r;
#pragma unroll
            for (int nf = 0; nf < 4; ++nf) {
                int c = col0 + wc * 64 + nf * 16 + (lane & 15);
                float v = acc[mf][nf][i] + bias[e * 2048 + c];
                float o = __shfl_xor(v, 1);
                if (ok && !(lane & 1)) {
                    float gt = fminf(v, LIMIT_);
                    float up = fminf(fmaxf(o, -LIMIT_), LIMIT_);
                    float sg = 1.f / (1.f + __expf(-ALPHA_ * gt));
                    gated[(size_t)slot * ED_ + (c >> 1)] = (_Float16)((up + 1.f) * (gt * sg));
                }
            }
        }
}

__global__ __launch_bounds__(256) void k_moe2(const _Float16* __restrict__ G,
                                              const _Float16* __restrict__ W,
                                              const float* __restrict__ bias,
                                              const int* __restrict__ perm,
                                              const float* __restrict__ pw,
                                              const int* __restrict__ counts,
                                              const int* __restrict__ offs,
                                              float* __restrict__ out) {
    const int wg = xcd_swz(blockIdx.x, 4096);
    const int e = wg >> 8;
    const int ne = counts[e];
    const int m0 = (wg & 15) * 128;
    if (m0 >= ne) return;
    const int base = offs[e];
    const int col0 = ((wg >> 4) & 15) * 128;
    MOE_PROLOG();
    const _Float16* asrc[4];
    const _Float16* bsrc[4];
#pragma unroll
    for (int c = 0; c < 4; ++c) {
        int s = base + min(m0 + c * 32 + rloc, ne - 1);
        asrc[c] = G + (size_t)s * ED_ + ksw;
        bsrc[c] = W + ((size_t)e * H_ + col0 + c * 32 + rloc) * ED_ + ksw;
    }
    MOE_KLOOP(ED_);
#pragma unroll
    for (int mf = 0; mf < 4; ++mf)
#pragma unroll
        for (int i = 0; i < 4; ++i) {
            int r = m0 + wr * 64 + mf * 16 + ((lane >> 4) << 2) + i;
            if (r >= ne) continue;
            int slot = base + r;
            int tok = perm[slot];
            float wgt = pw[slot];
#pragma unroll
            for (int nf = 0; nf < 4; ++nf) {
                int c = col0 + wc * 64 + nf * 16 + (lane & 15);
                atomicAdd(&out[(size_t)tok * H_ + c], wgt * (acc[mf][nf][i] + bias[e * H_ + c]));
            }
        }
}

// ================= conversions =================
__global__ __launch_bounds__(256) void k_cvts(const float* __restrict__ s,
                                              _Float16* __restrict__ dh,
                                              _Float16* __restrict__ dl, int n8) {
    int i = blockIdx.x * 256 + threadIdx.x;
    if (i >= n8) return;
    float4 x = ((const float4*)s)[i * 2], y = ((const float4*)s)[i * 2 + 1];
    float xs[8] = {x.x, x.y, x.z, x.w, y.x, y.y, y.z, y.w};
    half8 h, l;
#pragma unroll
    for (int j = 0; j < 8; ++j) {
        _Float16 hv = (_Float16)xs[j];
        h[j] = hv;
        l[j] = (_Float16)((xs[j] - (float)hv) * SPLIT_);
    }
    ((half8*)dh)[i] = h;
    ((half8*)dl)[i] = l;
}

__global__ __launch_bounds__(256) void k_cvt_t(const float* __restrict__ src,
                                               _Float16* __restrict__ dst, int K, int N) {
    const int e = blockIdx.z;
    const int k0 = blockIdx.x * 32, n0 = blockIdx.y * 32;
    __shared__ float t[32][33];
    const int tid = threadIdx.x;
    {
        int kr = tid >> 3, nc = (tid & 7) * 4;
        float4 v = *(const float4*)(src + ((size_t)e * K + k0 + kr) * N + n0 + nc);
        t[kr][nc] = v.x; t[kr][nc + 1] = v.y; t[kr][nc + 2] = v.z; t[kr][nc + 3] = v.w;
    }
    __syncthreads();
    {
        int nr = tid >> 3, kc = (tid & 7) * 4;
        half4v o;
        o[0] = (_Float16)t[kc + 0][nr];
        o[1] = (_Float16)t[kc + 1][nr];
        o[2] = (_Float16)t[kc + 2][nr];
        o[3] = (_Float16)t[kc + 3][nr];
        *(half4v*)(dst + ((size_t)e * N + n0 + nr) * K + k0 + kc) = o;
    }
}

// v transpose-split: vbuf fp32 [b][s][kvh][64] -> vth/vtl [b][kvh][64 d][1024 s]
__global__ __launch_bounds__(256) void k_cvt_vt(const float* __restrict__ vbuf,
                                                _Float16* __restrict__ vth,
                                                _Float16* __restrict__ vtl) {
    const int s0 = blockIdx.x * 32, d0 = blockIdx.y * 32;
    const int bk = blockIdx.z;
    const int b = bk >> 3, kvh = bk & 7;
    __shared__ float tl[32][33];
    const int tid = threadIdx.x;
    {
        int sr = tid >> 3, dc = (tid & 7) * 4;
        float4 v = *(const float4*)(vbuf + (size_t)(b * 1024 + s0 + sr) * 512 + kvh * 64 + d0 + dc);
        tl[sr][dc] = v.x; tl[sr][dc + 1] = v.y; tl[sr][dc + 2] = v.z; tl[sr][dc + 3] = v.w;
    }
    __syncthreads();
    {
        int dr = tid >> 3, sc = (tid & 7) * 4;
        half4v h4, l4;
#pragma unroll
        for (int j = 0; j < 4; ++j) {
            float x = tl[sc + j][dr];
            _Float16 hv = (_Float16)x;
            h4[j] = hv;
            l4[j] = (_Float16)((x - (float)hv) * SPLIT_);
        }
        size_t dst = (size_t)(bk * 64 + d0 + dr) * 1024 + s0 + sc;
        *(half4v*)(vth + dst) = h4;
        *(half4v*)(vtl + dst) = l4;
    }
}

// ================= RMSNorm (fp32 + split f16 outputs) =================
__global__ __launch_bounds__(256) void k_rmsnorm(const float* __restrict__ x,
                                                 const float* __restrict__ w,
                                                 float* __restrict__ y,
                                                 _Float16* __restrict__ yh,
                                                 _Float16* __restrict__ yl) {
    int t = blockIdx.x;
    const float* row = x + (size_t)t * H_;
    float ss = 0.f;
    for (int i = threadIdx.x; i < H_ / 4; i += 256) {
        float4 v = ((const float4*)row)[i];
        ss += v.x * v.x + v.y * v.y + v.z * v.z + v.w * v.w;
    }
    for (int o = 32; o >= 1; o >>= 1) ss += __shfl_xor(ss, o);
    __shared__ float wsum[4];
    if ((threadIdx.x & 63) == 0) wsum[threadIdx.x >> 6] = ss;
    __syncthreads();
    float tot = wsum[0] + wsum[1] + wsum[2] + wsum[3];
    float r = rsqrtf(tot / (float)H_ + EPS_);
    float* yrow = y + (size_t)t * H_;
    _Float16* hrow = yh + (size_t)t * H_;
    _Float16* lrow = yl + (size_t)t * H_;
    for (int i = threadIdx.x; i < H_ / 4; i += 256) {
        float4 v = ((const float4*)row)[i];
        float4 g = ((const float4*)w)[i];
        float o4[4];
        o4[0] = v.x * r * g.x; o4[1] = v.y * r * g.y;
        o4[2] = v.z * r * g.z; o4[3] = v.w * r * g.w;
        ((float4*)yrow)[i] = *(float4*)o4;
        half4v h4, l4;
#pragma unroll
        for (int j = 0; j < 4; ++j) {
            _Float16 hv = (_Float16)o4[j];
            h4[j] = hv;
            l4[j] = (_Float16)((o4[j] - (float)hv) * SPLIT_);
        }
        ((half4v*)hrow)[i] = h4;
        ((half4v*)lrow)[i] = l4;
    }
}

// ================= RoPE -> head-major split q/k =================
__global__ __launch_bounds__(256) void k_rope_sp(const float* __restrict__ qbuf,
                                                 const float* __restrict__ kbuf,
                                                 const float* __restrict__ cs,
                                                 const float* __restrict__ sn,
                                                 _Float16* __restrict__ qh, _Float16* __restrict__ ql,
                                                 _Float16* __restrict__ kh, _Float16* __restrict__ kl) {
    int t = blockIdx.x;
    int b = t >> 10, s = t & 1023;
    size_t cb = (size_t)t * 64;
    for (int p = threadIdx.x; p < 40 * 32; p += 256) {
        int head = p >> 5, d = p & 31;
        float c1 = cs[cb + d],      s1v = sn[cb + d];
        float c2 = cs[cb + d + 32], s2v = sn[cb + d + 32];
        float x1, x2; size_t dst;
        _Float16 *oh, *ol;
        if (head < 32) {
            const float* src = qbuf + (size_t)t * 2048 + head * 64;
            x1 = src[d]; x2 = src[d + 32];
            dst = (((size_t)b * 32 + head) * 1024 + s) * 64 + d;
            oh = qh; ol = ql;
        } else {
            int hk = head - 32;
            const float* src = kbuf + (size_t)t * 512 + hk * 64;
            x1 = src[d]; x2 = src[d + 32];
            dst = (((size_t)b * 8 + hk) * 1024 + s) * 64 + d;
            oh = kh; ol = kl;
        }
        float r1 = x1 * c1 - x2 * s1v;
        float r2 = x2 * c2 + x1 * s2v;
        _Float16 h1 = (_Float16)r1;
        oh[dst] = h1; ol[dst] = (_Float16)((r1 - (float)h1) * SPLIT_);
        _Float16 h2 = (_Float16)r2;
        oh[dst + 32] = h2; ol[dst + 32] = (_Float16)((r2 - (float)h2) * SPLIT_);
    }
}

// ================= MFMA flash attention (split-fp16, fp32-accurate) ===========
// block = (b, kvh, 64-token tile); 4 waves = 4 GQA q-heads. 1 block/CU (102KB LDS).
#define PPITCH 68
union U8h { unsigned w[4]; half8 v; };

__global__ __launch_bounds__(256, 1) void k_attn_m(
        const _Float16* __restrict__ qhg, const _Float16* __restrict__ qlg,
        const _Float16* __restrict__ khg, const _Float16* __restrict__ klg,
        const _Float16* __restrict__ vthg, const _Float16* __restrict__ vtlg,
        const float* __restrict__ sinks, float* __restrict__ attnb) {
    __shared__ _Float16 Khs[4096], Kls[4096], Vhs[4096], Vls[4096];
    __shared__ unsigned Pp[4][64 * PPITCH];
    const int bx = blockIdx.x;
    const int b = bx >> 7, kvh = (bx >> 4) & 7, tile = bx & 15;
    const int i0 = tile * 64;
    const int tid = threadIdx.x, lane = tid & 63, wid = tid >> 6;
    const int l15 = lane & 15, g = lane >> 4;
    const int h = kvh * 4 + wid;
    const size_t kvbase = (size_t)(b * 8 + kvh) * 1024 * 64;  // K [bk][S][64]
    const size_t vbase  = (size_t)(b * 8 + kvh) * 64 * 1024;  // Vt [bk][64][S]
    // Q A-frags (rows t = 16mf + l15, k = 32ks + g*8 + ii)
    half8 aqh[4][2], aql[4][2];
    {
        const size_t qb0 = ((size_t)(b * 32 + h) * 1024 + i0) * 64;
#pragma unroll
        for (int mf = 0; mf < 4; ++mf)
#pragma unroll
            for (int ks = 0; ks < 2; ++ks) {
                size_t a = qb0 + (size_t)(16 * mf + l15) * 64 + ks * 32 + g * 8;
                aqh[mf][ks] = *(const half8*)(qhg + a);
                aql[mf][ks] = *(const half8*)(qlg + a);
            }
    }
    floatx4 o1[4][4], o2[4][4];
    float m_run[4][4], l_run[4][4];
#pragma unroll
    for (int mf = 0; mf < 4; ++mf)
#pragma unroll
        for (int x = 0; x < 4; ++x) {
            o1[mf][x] = (floatx4)0.f; o2[mf][x] = (floatx4)0.f;
            m_run[mf][x] = -1e20f; l_run[mf][x] = 0.f;
        }
    const int nch = tile >= 2 ? 3 : tile + 1;
    const int jr = tid >> 3, cc = tid & 7;
    unsigned* pw = &Pp[wid][0];
    for (int ci = 0; ci < nch; ++ci) {
        const int jb = i0 - 64 * (nch - 1 - ci);
        __syncthreads();
        // stage K + Vt chunk (XOR-swizzled source, linear LDS dest)
        {
            const int sw0 = (cc ^ (jr & 7)) * 8;
            const size_t k0 = kvbase + (size_t)(jb + jr) * 64 + sw0;
            const size_t k1 = kvbase + (size_t)(jb + jr + 32) * 64 + sw0;
            gload16(khg + k0, Khs + tid * 8);
            gload16(khg + k1, Khs + 2048 + tid * 8);
            gload16(klg + k0, Kls + tid * 8);
            gload16(klg + k1, Kls + 2048 + tid * 8);
            const size_t v0 = vbase + (size_t)jr * 1024 + jb + sw0;
            const size_t v1 = vbase + (size_t)(jr + 32) * 1024 + jb + sw0;
            gload16(vthg + v0, Vhs + tid * 8);
            gload16(vthg + v1, Vhs + 2048 + tid * 8);
            gload16(vtlg + v0, Vls + tid * 8);
            gload16(vtlg + v1, Vls + 2048 + tid * 8);
        }
        __syncthreads();
        // ---- QK^T (split): s = s1 + s2/2048 ----
        floatx4 s1[4][4], s2[4][4];
#pragma unroll
        for (int mf = 0; mf < 4; ++mf)
#pragma unroll
            for (int nf = 0; nf < 4; ++nf) { s1[mf][nf] = (floatx4)0.f; s2[mf][nf] = (floatx4)0.f; }
#pragma unroll
        for (int ks = 0; ks < 2; ++ks) {
            half8 kbh[4], kbl[4];
#pragma unroll
            for (int nf = 0; nf < 4; ++nf) {
                int j = l15 + 16 * nf;
                int c = (g + 4 * ks) ^ (j & 7);
                kbh[nf] = *(const half8*)&Khs[j * 64 + c * 8];
                kbl[nf] = *(const half8*)&Kls[j * 64 + c * 8];
            }
#pragma unroll
            for (int mf = 0; mf < 4; ++mf)
#pragma unroll
                for (int nf = 0; nf < 4; ++nf) {
                    s1[mf][nf] = MF16(aqh[mf][ks], kbh[nf], s1[mf][nf]);
                    s2[mf][nf] = MF16(aqh[mf][ks], kbl[nf], s2[mf][nf]);
                    s2[mf][nf] = MF16(aql[mf][ks], kbh[nf], s2[mf][nf]);
                }
        }
        // ---- scores, mask, online softmax ----
#pragma unroll
        for (int mf = 0; mf < 4; ++mf)
#pragma unroll
            for (int reg = 0; reg < 4; ++reg) {
                int i = i0 + 16 * mf + g * 4 + reg;
                float best = -1e30f;
#pragma unroll
                for (int nf = 0; nf < 4; ++nf) {
                    int j = jb + 16 * nf + l15;
                    float sv = (s1[mf][nf][reg] + s2[mf][nf][reg] * INV_SPLIT_) * SCALE_;
                    bool ok = (j <= i) && (i - j < WIN_);
                    sv = ok ? sv : -1e30f;
                    s1[mf][nf][reg] = sv;
                    best = fmaxf(best, sv);
                }
                for (int off = 1; off < 16; off <<= 1) best = fmaxf(best, __shfl_xor(best, off));
                float nm = fmaxf(m_run[mf][reg], best);   // >= -1e20 floor
                float sc = __expf(m_run[mf][reg] - nm);
                m_run[mf][reg] = nm;
                l_run[mf][reg] *= sc;
#pragma unroll
                for (int nf = 0; nf < 4; ++nf) { o1[mf][nf][reg] *= sc; o2[mf][nf][reg] *= sc; }
            }
        // ---- p = exp(s - m), split-pack to LDS u32 (ph | pl<<16) ----
#pragma unroll
        for (int mf = 0; mf < 4; ++mf)
#pragma unroll
            for (int nf = 0; nf < 4; ++nf)
#pragma unroll
                for (int reg = 0; reg < 4; ++reg) {
                    float pv = __expf(s1[mf][nf][reg] - m_run[mf][reg]);
                    l_run[mf][reg] += pv;
                    _Float16 hv = (_Float16)pv;
                    _Float16 lv = (_Float16)((pv - (float)hv) * SPLIT_);
                    union { _Float16 h; unsigned short u; } ch, cl;
                    ch.h = hv; cl.h = lv;
                    int t = 16 * mf + g * 4 + reg, jj = l15 + 16 * nf;
                    pw[t * PPITCH + jj] = (unsigned)ch.u | ((unsigned)cl.u << 16);
                }
        // ---- PV (split): o = o1 + o2/2048 ----
#pragma unroll
        for (int ks = 0; ks < 2; ++ks) {
            half8 bvh[4], bvl[4];
#pragma unroll
            for (int nf = 0; nf < 4; ++nf) {
                int d = l15 + 16 * nf;
                int c = (g + 4 * ks) ^ (d & 7);
                bvh[nf] = *(const half8*)&Vhs[d * 64 + c * 8];
                bvl[nf] = *(const half8*)&Vls[d * 64 + c * 8];
            }
#pragma unroll
            for (int mf = 0; mf < 4; ++mf) {
                const unsigned* pr = &pw[(16 * mf + l15) * PPITCH + 32 * ks + g * 8];
                int4 va = *(const int4*)pr;
                int4 vb = *(const int4*)(pr + 4);
                U8h ph, pl;
                ph.w[0] = ((unsigned)va.x & 0xffffu) | ((unsigned)va.y << 16);
                ph.w[1] = ((unsigned)va.z & 0xffffu) | ((unsigned)va.w << 16);
                ph.w[2] = ((unsigned)vb.x & 0xffffu) | ((unsigned)vb.y << 16);
                ph.w[3] = ((unsigned)vb.z & 0xffffu) | ((unsigned)vb.w << 16);
                pl.w[0] = ((unsigned)va.x >> 16) | ((unsigned)va.y & 0xffff0000u);
                pl.w[1] = ((unsigned)va.z >> 16) | ((unsigned)va.w & 0xffff0000u);
                pl.w[2] = ((unsigned)vb.x >> 16) | ((unsigned)vb.y & 0xffff0000u);
                pl.w[3] = ((unsigned)vb.z >> 16) | ((unsigned)vb.w & 0xffff0000u);
#pragma unroll
                for (int nf = 0; nf < 4; ++nf) {
                    o1[mf][nf] = MF16(ph.v, bvh[nf], o1[mf][nf]);
                    o2[mf][nf] = MF16(ph.v, bvl[nf], o2[mf][nf]);
                    o2[mf][nf] = MF16(pl.v, bvh[nf], o2[mf][nf]);
                }
            }
        }
    }
    // ---- finalize: row-sum l, sink, normalize, store fp32 ----
    const float sinkv = sinks[h];
    float inv[4][4];
#pragma unroll
    for (int mf = 0; mf < 4; ++mf)
#pragma unroll
        for (int reg = 0; reg < 4; ++reg) {
            float l = l_run[mf][reg];
            for (int off = 1; off < 16; off <<= 1) l += __shfl_xor(l, off);
            inv[mf][reg] = 1.f / (l + __expf(sinkv - m_run[mf][reg]));
        }
#pragma unroll
    for (int mf = 0; mf < 4; ++mf)
#pragma unroll
        for (int nf = 0; nf < 4; ++nf)
#pragma unroll
            for (int reg = 0; reg < 4; ++reg) {
                int t = i0 + 16 * mf + g * 4 + reg;
                int d = l15 + 16 * nf;
                float ov = (o1[mf][nf][reg] + o2[mf][nf][reg] * INV_SPLIT_) * inv[mf][reg];
                attnb[((size_t)(b * 1024 + t) * 32 + h) * 64 + d] = ov;
            }
}

// ================= Router =================
__global__ __launch_bounds__(256) void k_router(const float* __restrict__ x,
                                                const float* __restrict__ rw,
                                                const float* __restrict__ rb,
                                                int* __restrict__ topi,
                                                float* __restrict__ topw) {
    int t = blockIdx.x;
    int e = threadIdx.x >> 4, g = threadIdx.x & 15;
    const float* row = x + (size_t)t * H_;
    const float* wr = rw + (size_t)e * H_;
    float acc = 0.f;
    int kbeg = g * (H_ / 16);
    for (int kk = 0; kk < H_ / 16; kk += 4) {
        float4 xv = *(const float4*)(row + kbeg + kk);
        float4 wv = *(const float4*)(wr + kbeg + kk);
        acc += xv.x * wv.x + xv.y * wv.y + xv.z * wv.z + xv.w * wv.w;
    }
    __shared__ float part[16][17];
    part[e][g] = acc;
    __syncthreads();
    __shared__ float logits[16];
    if (threadIdx.x < 16) {
        float s2 = rb[threadIdx.x];
        for (int g2 = 0; g2 < 16; g2++) s2 += part[threadIdx.x][g2];
        logits[threadIdx.x] = s2;
    }
    __syncthreads();
    if (threadIdx.x == 0) {
        float tv[4]; int ti4[4];
        unsigned used = 0;
        for (int s3 = 0; s3 < 4; s3++) {
            float best = -3.0e38f; int bi = 0;
            for (int e2 = 0; e2 < 16; e2++)
                if (!((used >> e2) & 1) && logits[e2] > best) { best = logits[e2]; bi = e2; }
            used |= 1u << bi; tv[s3] = best; ti4[s3] = bi;
        }
        float mx = tv[0], pe[4], sum = 0.f;
        for (int s3 = 0; s3 < 4; s3++) { pe[s3] = __expf(tv[s3] - mx); sum += pe[s3]; }
        for (int s3 = 0; s3 < 4; s3++) {
            topw[t * 4 + s3] = pe[s3] / sum;
            topi[t * 4 + s3] = ti4[s3];
        }
    }
}

// ================= MoE prep =================
__global__ void k_zero(int* counts) { if (threadIdx.x < E_) counts[threadIdx.x] = 0; }

__global__ void k_hist(const int* __restrict__ topi, int* counts) {
    int g = blockIdx.x * 256 + threadIdx.x;
    if (g < T_ * TOPK_) atomicAdd(&counts[topi[g]], 1);
}

__global__ void k_scan(const int* __restrict__ counts, int* offs, int* cursor) {
    if (threadIdx.x == 0 && blockIdx.x == 0) {
        int run = 0;
        for (int e = 0; e < E_; e++) { offs[e] = run; cursor[e] = run; run += counts[e]; }
    }
}

__global__ void k_scatter(const int* __restrict__ topi, const float* __restrict__ topw,
                          int* cursor, int* __restrict__ perm, float* __restrict__ pw) {
    int g = blockIdx.x * 256 + threadIdx.x;
    if (g >= T_ * TOPK_) return;
    int e = topi[g];
    int pos = atomicAdd(&cursor[e], 1);
    perm[pos] = g >> 2;
    pw[pos] = topw[g];
}

// ================= launch =================
extern "C" void kernel_launch(void* const* d_in, const int* in_sizes, int n_in,
                              void* d_out, int out_size, void* d_ws, size_t ws_size,
                              hipStream_t stream) {
    const float* hidden = (const float*)d_in[0];
    const float* cosp  = (const float*)d_in[1];
    const float* sinp  = (const float*)d_in[2];
    const float* ln1   = (const float*)d_in[3];
    const float* ln2   = (const float*)d_in[4];
    const float* qw    = (const float*)d_in[5];
    const float* qb    = (const float*)d_in[6];
    const float* kw    = (const float*)d_in[7];
    const float* kbia  = (const float*)d_in[8];
    const float* vw    = (const float*)d_in[9];
    const float* vbia  = (const float*)d_in[10];
    const float* ow    = (const float*)d_in[11];
    const float* ob    = (const float*)d_in[12];
    const float* sinks = (const float*)d_in[13];
    const float* rw    = (const float*)d_in[14];
    const float* rb    = (const float*)d_in[15];
    const float* gup   = (const float*)d_in[16];
    const float* gub   = (const float*)d_in[17];
    const float* dwp   = (const float*)d_in[18];
    const float* dwb   = (const float*)d_in[19];
    float* out = (float*)d_out;

    char* p = (char*)d_ws;
    auto alloc = [&](size_t bytes) { char* r = p; p += (bytes + 255) & ~(size_t)255; return r; };
    float*     xnorm  = (float*)alloc((size_t)T_ * H_ * 4);
    _Float16*  xh     = (_Float16*)alloc((size_t)T_ * H_ * 2);
    _Float16*  xl     = (_Float16*)alloc((size_t)T_ * H_ * 2);
    float*     qbuf   = (float*)alloc((size_t)T_ * NH_ * HD_ * 4);
    float*     kbuf   = (float*)alloc((size_t)T_ * NKV_ * HD_ * 4);
    float*     vbuf   = (float*)alloc((size_t)T_ * NKV_ * HD_ * 4);
    float*     attnb  = (float*)alloc((size_t)T_ * NH_ * HD_ * 4);
    _Float16*  ath    = (_Float16*)alloc((size_t)T_ * NH_ * HD_ * 2);
    _Float16*  atl    = (_Float16*)alloc((size_t)T_ * NH_ * HD_ * 2);
    _Float16*  gatedh = (_Float16*)alloc((size_t)T_ * TOPK_ * ED_ * 2);
    _Float16*  qwh    = (_Float16*)alloc((size_t)2048 * H_ * 2);
    _Float16*  qwl    = (_Float16*)alloc((size_t)2048 * H_ * 2);
    _Float16*  kwh    = (_Float16*)alloc((size_t)512 * H_ * 2);
    _Float16*  kwl    = (_Float16*)alloc((size_t)512 * H_ * 2);
    _Float16*  vwh    = (_Float16*)alloc((size_t)512 * H_ * 2);
    _Float16*  vwl    = (_Float16*)alloc((size_t)512 * H_ * 2);
    _Float16*  owh    = (_Float16*)alloc((size_t)H_ * 2048 * 2);
    _Float16*  owl    = (_Float16*)alloc((size_t)H_ * 2048 * 2);
    _Float16*  gupt   = (_Float16*)alloc((size_t)E_ * 2048 * H_ * 2);
    _Float16*  dwnt   = (_Float16*)alloc((size_t)E_ * H_ * ED_ * 2);
    _Float16*  qhb    = (_Float16*)alloc((size_t)T_ * NH_ * HD_ * 2);
    _Float16*  qlb    = (_Float16*)alloc((size_t)T_ * NH_ * HD_ * 2);
    _Float16*  khb    = (_Float16*)alloc((size_t)T_ * NKV_ * HD_ * 2);
    _Float16*  klb    = (_Float16*)alloc((size_t)T_ * NKV_ * HD_ * 2);
    _Float16*  vthb   = (_Float16*)alloc((size_t)T_ * NKV_ * HD_ * 2);
    _Float16*  vtlb   = (_Float16*)alloc((size_t)T_ * NKV_ * HD_ * 2);
    float*     topw   = (float*)alloc(T_ * TOPK_ * 4);
    float*     pwb    = (float*)alloc(T_ * TOPK_ * 4);
    int*       topi   = (int*)alloc(T_ * TOPK_ * 4);
    int*       perm   = (int*)alloc(T_ * TOPK_ * 4);
    int*       counts = (int*)alloc(E_ * 4);
    int*       offs   = (int*)alloc(E_ * 4);
    int*       cursor = (int*)alloc(E_ * 4);

    // weight conversions
    k_cvts<<<2048, 256, 0, stream>>>(qw, qwh, qwl, 2048 * H_ / 8);
    k_cvts<<<512, 256, 0, stream>>>(kw, kwh, kwl, 512 * H_ / 8);
    k_cvts<<<512, 256, 0, stream>>>(vw, vwh, vwl, 512 * H_ / 8);
    k_cvts<<<2048, 256, 0, stream>>>(ow, owh, owl, H_ * 2048 / 8);
    k_cvt_t<<<dim3(H_ / 32, 2048 / 32, E_), 256, 0, stream>>>(gup, gupt, H_, 2048);
    k_cvt_t<<<dim3(ED_ / 32, H_ / 32, E_), 256, 0, stream>>>(dwp, dwnt, ED_, H_);

    k_rmsnorm<<<T_, 256, 0, stream>>>(hidden, ln1, xnorm, xh, xl);
    k_gemm_sp<<<256, 256, 0, stream>>>(xh, xl, qwh, qwl, qb, nullptr, qbuf, 2048, H_);
    k_gemm_sp<<<64, 256, 0, stream>>>(xh, xl, kwh, kwl, kbia, nullptr, kbuf, 512, H_);
    k_gemm_sp<<<64, 256, 0, stream>>>(xh, xl, vwh, vwl, vbia, nullptr, vbuf, 512, H_);
    k_rope_sp<<<T_, 256, 0, stream>>>(qbuf, kbuf, cosp, sinp, qhb, qlb, khb, klb);
    k_cvt_vt<<<dim3(32, 2, 16), 256, 0, stream>>>(vbuf, vthb, vtlb);
    k_attn_m<<<256, 256, 0, stream>>>(qhb, qlb, khb, klb, vthb, vtlb, sinks, attnb);
    k_cvts<<<2048, 256, 0, stream>>>(attnb, ath, atl, T_ * NH_ * HD_ / 8);
    k_gemm_sp<<<256, 256, 0, stream>>>(ath, atl, owh, owl, ob, hidden, out, 2048, H_);
    k_rmsnorm<<<T_, 256, 0, stream>>>(out, ln2, xnorm, xh, xl);
    k_router<<<T_, 256, 0, stream>>>(xnorm, rw, rb, topi, topw);
    k_zero<<<1, 64, 0, stream>>>(counts);
    k_hist<<<(T_ * TOPK_ + 255) / 256, 256, 0, stream>>>(topi, counts);
    k_scan<<<1, 1, 0, stream>>>(counts, offs, cursor);
    k_scatter<<<(T_ * TOPK_ + 255) / 256, 256, 0, stream>>>(topi, topw, cursor, perm, pwb);
    k_moe1<<<4096, 256, 0, stream>>>(xh, gupt, gub, perm, counts, offs, gatedh);
    k_moe2<<<4096, 256, 0, stream>>>(gatedh, dwnt, dwb, perm, pwb, counts, offs, out);
}

// Round 7
// 990.351 us; speedup vs baseline: 4.8981x; 1.1348x over previous
//
#include <hip/hip_runtime.h>
#include <hip/hip_bf16.h>
#include <cstdint>

#define B_    2
#define S_    1024
#define H_    2048
#define NH_   32
#define NKV_  8
#define HD_   64
#define T_    (B_*S_)
#define E_    16
#define ED_   1024
#define TOPK_ 4
#define WIN_  128
#define LIMIT_ 7.0f
#define ALPHA_ 1.702f
#define EPS_   1e-6f
#define SCALE_ 0.125f  /* HD^-0.5 */
#define SPLIT_ 2048.0f
#define INV_SPLIT_ 4.8828125e-4f
#define MAXT_ 80      /* max MoE row-tiles: 64 + 16 */

typedef _Float16 half8 __attribute__((ext_vector_type(8)));
typedef _Float16 half4v __attribute__((ext_vector_type(4)));
typedef float floatx4 __attribute__((ext_vector_type(4)));

#define MF16(a,b,c) __builtin_amdgcn_mfma_f32_16x16x32_f16(a,b,c,0,0,0)

__device__ __forceinline__ void gload16(const void* g, void* l) {
    __builtin_amdgcn_global_load_lds((const __attribute__((address_space(1))) void*)g,
                                     (__attribute__((address_space(3))) void*)l, 16, 0, 0);
}

// bijective chunked XCD swizzle (nwg % 8 == 0)
__device__ __forceinline__ int xcd_swz(int bid, int nwg) {
    int cpx = nwg >> 3;
    return (bid & 7) * cpx + (bid >> 3);
}

// ================= C init: C = bias (+res) =================
__global__ __launch_bounds__(256) void k_initc(const float* __restrict__ bias,
                                               const float* __restrict__ res,
                                               float* __restrict__ C, int N, int n4) {
    int i = blockIdx.x * 256 + threadIdx.x;
    if (i >= n4) return;
    int c4 = (i % (N >> 2)) << 2;
    float4 v = *(const float4*)(bias + c4);
    if (res) {
        float4 r = ((const float4*)res)[i];
        v.x += r.x; v.y += r.y; v.z += r.z; v.w += r.w;
    }
    ((float4*)C)[i] = v;
}

// ===== split-fp16 GEMM, split-K=4: atomicAdd into pre-initialized C =====
// grid = (N/128) * 16 * 4 (1D). wg: n = wg>>6, m = (wg&63)>>2, ks = wg&3.
// M fixed 2048. Each block: K/4 range, 128x128 tile, BK=32, 4 waves 2x2.
__global__ __launch_bounds__(256) void k_gemm_spk(const _Float16* __restrict__ Ah,
                                                  const _Float16* __restrict__ Al,
                                                  const _Float16* __restrict__ Bh,
                                                  const _Float16* __restrict__ Bl,
                                                  float* __restrict__ C, int N, int K) {
    __shared__ _Float16 Ahs[128 * 32];
    __shared__ _Float16 Als[128 * 32];
    __shared__ _Float16 Bhs[128 * 32];
    __shared__ _Float16 Bls[128 * 32];
    const int tid = threadIdx.x;
    const int lane = tid & 63;
    const int wid = tid >> 6;
    const int wr = wid >> 1, wc = wid & 1;
    const int wg = xcd_swz(blockIdx.x, gridDim.x);
    const int col0 = (wg >> 6) * 128;
    const int row0 = ((wg & 63) >> 2) * 128;
    const int ks4 = wg & 3;
    const int kbeg = ks4 * (K >> 2), kend = kbeg + (K >> 2);
    floatx4 acc1[4][4], acc2[4][4];
    for (int m = 0; m < 4; ++m)
        for (int n = 0; n < 4; ++n) { acc1[m][n] = (floatx4)0.f; acc2[m][n] = (floatx4)0.f; }
    const int rL = tid >> 2, koff = (tid & 3) * 8;
    const size_t o0 = (size_t)(row0 + rL) * K + koff;
    const size_t o1 = (size_t)(row0 + 64 + rL) * K + koff;
    const size_t p0 = (size_t)(col0 + rL) * K + koff;
    const size_t p1 = (size_t)(col0 + 64 + rL) * K + koff;
    for (int k0 = kbeg; k0 < kend; k0 += 32) {
        __syncthreads();
        gload16(Ah + o0 + k0, Ahs + tid * 8); gload16(Ah + o1 + k0, Ahs + 2048 + tid * 8);
        gload16(Al + o0 + k0, Als + tid * 8); gload16(Al + o1 + k0, Als + 2048 + tid * 8);
        gload16(Bh + p0 + k0, Bhs + tid * 8); gload16(Bh + p1 + k0, Bhs + 2048 + tid * 8);
        gload16(Bl + p0 + k0, Bls + tid * 8); gload16(Bl + p1 + k0, Bls + 2048 + tid * 8);
        __syncthreads();
        const int lk = (lane >> 4) * 8;
        half8 ah[4], al[4], bh[4], bl[4];
#pragma unroll
        for (int m = 0; m < 4; ++m) {
            int ro = (wr * 64 + m * 16 + (lane & 15)) * 32 + lk;
            ah[m] = *(const half8*)&Ahs[ro];
            al[m] = *(const half8*)&Als[ro];
        }
#pragma unroll
        for (int n = 0; n < 4; ++n) {
            int ro = (wc * 64 + n * 16 + (lane & 15)) * 32 + lk;
            bh[n] = *(const half8*)&Bhs[ro];
            bl[n] = *(const half8*)&Bls[ro];
        }
#pragma unroll
        for (int m = 0; m < 4; ++m)
#pragma unroll
            for (int n = 0; n < 4; ++n) {
                acc1[m][n] = MF16(ah[m], bh[n], acc1[m][n]);
                acc2[m][n] = MF16(ah[m], bl[n], acc2[m][n]);
                acc2[m][n] = MF16(al[m], bh[n], acc2[m][n]);
            }
    }
#pragma unroll
    for (int mf = 0; mf < 4; ++mf)
#pragma unroll
        for (int i = 0; i < 4; ++i) {
            int r = row0 + wr * 64 + mf * 16 + ((lane >> 4) << 2) + i;
#pragma unroll
            for (int nf = 0; nf < 4; ++nf) {
                int c = col0 + wc * 64 + nf * 16 + (lane & 15);
                atomicAdd(&C[(size_t)r * N + c], acc1[mf][nf][i] + acc2[mf][nf][i] * INV_SPLIT_);
            }
        }
}

// ================= MoE MFMA core: BK=64, XOR-swizzled LDS, 128x128 tile ========
#define MOE_PROLOG() \
    __shared__ _Float16 As[128 * 64]; \
    __shared__ _Float16 Bs[128 * 64]; \
    const int tid = threadIdx.x; \
    const int lane = tid & 63; \
    const int wid = tid >> 6; \
    const int wr = wid >> 1, wc = wid & 1; \
    const int rloc = tid >> 3; \
    const int ksw = ((tid & 7) ^ (rloc & 7)) * 8; \
    floatx4 acc[4][4]; \
    for (int m = 0; m < 4; ++m) for (int n = 0; n < 4; ++n) acc[m][n] = (floatx4)0.f;

#define MOE_KLOOP(KD) \
    for (int k0 = 0; k0 < (KD); k0 += 64) { \
        __syncthreads(); \
        _Pragma("unroll") for (int c = 0; c < 4; ++c) { \
            gload16(asrc[c] + k0, As + c * 2048 + tid * 8); \
            gload16(bsrc[c] + k0, Bs + c * 2048 + tid * 8); \
        } \
        __syncthreads(); \
        _Pragma("unroll") for (int s = 0; s < 2; ++s) { \
            const int gc = ((s * 4 + (lane >> 4)) ^ (lane & 7)) * 8; \
            half8 a[4], b[4]; \
            _Pragma("unroll") for (int m = 0; m < 4; ++m) \
                a[m] = *(const half8*)&As[(wr * 64 + m * 16 + (lane & 15)) * 64 + gc]; \
            _Pragma("unroll") for (int n = 0; n < 4; ++n) \
                b[n] = *(const half8*)&Bs[(wc * 64 + n * 16 + (lane & 15)) * 64 + gc]; \
            _Pragma("unroll") for (int m = 0; m < 4; ++m) \
                _Pragma("unroll") for (int n = 0; n < 4; ++n) \
                    acc[m][n] = MF16(a[m], b[n], acc[m][n]); \
        } \
    }

// MoE GEMM1: tile-table grid (80x16). gathered A rows; fused GLU -> gated f16
__global__ __launch_bounds__(256) void k_moe1(const _Float16* __restrict__ X,
                                              const _Float16* __restrict__ W,
                                              const float* __restrict__ bias,
                                              const int* __restrict__ perm,
                                              const int* __restrict__ counts,
                                              const int* __restrict__ offs,
                                              const int* __restrict__ te,
                                              const int* __restrict__ tm,
                                              const int* __restrict__ ntt,
                                              _Float16* __restrict__ gated) {
    const int wg = xcd_swz(blockIdx.x, MAXT_ * 16);
    const int tt = wg >> 4;
    if (tt >= ntt[0]) return;
    const int e = te[tt];
    const int m0 = tm[tt];
    const int ne = counts[e];
    const int base = offs[e];
    const int col0 = (wg & 15) * 128;
    MOE_PROLOG();
    const _Float16* asrc[4];
    const _Float16* bsrc[4];
#pragma unroll
    for (int c = 0; c < 4; ++c) {
        int t = perm[base + min(m0 + c * 32 + rloc, ne - 1)];
        asrc[c] = X + (size_t)t * H_ + ksw;
        bsrc[c] = W + ((size_t)e * 2048 + col0 + c * 32 + rloc) * H_ + ksw;
    }
    MOE_KLOOP(H_);
#pragma unroll
    for (int mf = 0; mf < 4; ++mf)
#pragma unroll
        for (int i = 0; i < 4; ++i) {
            int r = m0 + wr * 64 + mf * 16 + ((lane >> 4) << 2) + i;
            bool ok = r < ne;
            int slot = base + r;
#pragma unroll
            for (int nf = 0; nf < 4; ++nf) {
                int c = col0 + wc * 64 + nf * 16 + (lane & 15);
                float v = acc[mf][nf][i] + bias[e * 2048 + c];
                float o = __shfl_xor(v, 1);
                if (ok && !(lane & 1)) {
                    float gt = fminf(v, LIMIT_);
                    float up = fminf(fmaxf(o, -LIMIT_), LIMIT_);
                    float sg = 1.f / (1.f + __expf(-ALPHA_ * gt));
                    gated[(size_t)slot * ED_ + (c >> 1)] = (_Float16)((up + 1.f) * (gt * sg));
                }
            }
        }
}

__global__ __launch_bounds__(256) void k_moe2(const _Float16* __restrict__ G,
                                              const _Float16* __restrict__ W,
                                              const float* __restrict__ bias,
                                              const int* __restrict__ perm,
                                              const float* __restrict__ pw,
                                              const int* __restrict__ counts,
                                              const int* __restrict__ offs,
                                              const int* __restrict__ te,
                                              const int* __restrict__ tm,
                                              const int* __restrict__ ntt,
                                              float* __restrict__ out) {
    const int wg = xcd_swz(blockIdx.x, MAXT_ * 16);
    const int tt = wg >> 4;
    if (tt >= ntt[0]) return;
    const int e = te[tt];
    const int m0 = tm[tt];
    const int ne = counts[e];
    const int base = offs[e];
    const int col0 = (wg & 15) * 128;
    MOE_PROLOG();
    const _Float16* asrc[4];
    const _Float16* bsrc[4];
#pragma unroll
    for (int c = 0; c < 4; ++c) {
        int s = base + min(m0 + c * 32 + rloc, ne - 1);
        asrc[c] = G + (size_t)s * ED_ + ksw;
        bsrc[c] = W + ((size_t)e * H_ + col0 + c * 32 + rloc) * ED_ + ksw;
    }
    MOE_KLOOP(ED_);
#pragma unroll
    for (int mf = 0; mf < 4; ++mf)
#pragma unroll
        for (int i = 0; i < 4; ++i) {
            int r = m0 + wr * 64 + mf * 16 + ((lane >> 4) << 2) + i;
            if (r >= ne) continue;
            int slot = base + r;
            int tok = perm[slot];
            float wgt = pw[slot];
#pragma unroll
            for (int nf = 0; nf < 4; ++nf) {
                int c = col0 + wc * 64 + nf * 16 + (lane & 15);
                atomicAdd(&out[(size_t)tok * H_ + c], wgt * (acc[mf][nf][i] + bias[e * H_ + c]));
            }
        }
}

// ================= conversions =================
__global__ __launch_bounds__(256) void k_cvts(const float* __restrict__ s,
                                              _Float16* __restrict__ dh,
                                              _Float16* __restrict__ dl, int n8) {
    int i = blockIdx.x * 256 + threadIdx.x;
    if (i >= n8) return;
    float4 x = ((const float4*)s)[i * 2], y = ((const float4*)s)[i * 2 + 1];
    float xs[8] = {x.x, x.y, x.z, x.w, y.x, y.y, y.z, y.w};
    half8 h, l;
#pragma unroll
    for (int j = 0; j < 8; ++j) {
        _Float16 hv = (_Float16)xs[j];
        h[j] = hv;
        l[j] = (_Float16)((xs[j] - (float)hv) * SPLIT_);
    }
    ((half8*)dh)[i] = h;
    ((half8*)dl)[i] = l;
}

__global__ __launch_bounds__(256) void k_cvt_t(const float* __restrict__ src,
                                               _Float16* __restrict__ dst, int K, int N) {
    const int e = blockIdx.z;
    const int k0 = blockIdx.x * 32, n0 = blockIdx.y * 32;
    __shared__ float t[32][33];
    const int tid = threadIdx.x;
    {
        int kr = tid >> 3, nc = (tid & 7) * 4;
        float4 v = *(const float4*)(src + ((size_t)e * K + k0 + kr) * N + n0 + nc);
        t[kr][nc] = v.x; t[kr][nc + 1] = v.y; t[kr][nc + 2] = v.z; t[kr][nc + 3] = v.w;
    }
    __syncthreads();
    {
        int nr = tid >> 3, kc = (tid & 7) * 4;
        half4v o;
        o[0] = (_Float16)t[kc + 0][nr];
        o[1] = (_Float16)t[kc + 1][nr];
        o[2] = (_Float16)t[kc + 2][nr];
        o[3] = (_Float16)t[kc + 3][nr];
        *(half4v*)(dst + ((size_t)e * N + n0 + nr) * K + k0 + kc) = o;
    }
}

// v transpose-split: vbuf fp32 [b][s][kvh][64] -> vth/vtl [b][kvh][64 d][1024 s]
__global__ __launch_bounds__(256) void k_cvt_vt(const float* __restrict__ vbuf,
                                                _Float16* __restrict__ vth,
                                                _Float16* __restrict__ vtl) {
    const int s0 = blockIdx.x * 32, d0 = blockIdx.y * 32;
    const int bk = blockIdx.z;
    const int b = bk >> 3, kvh = bk & 7;
    __shared__ float tl[32][33];
    const int tid = threadIdx.x;
    {
        int sr = tid >> 3, dc = (tid & 7) * 4;
        float4 v = *(const float4*)(vbuf + (size_t)(b * 1024 + s0 + sr) * 512 + kvh * 64 + d0 + dc);
        tl[sr][dc] = v.x; tl[sr][dc + 1] = v.y; tl[sr][dc + 2] = v.z; tl[sr][dc + 3] = v.w;
    }
    __syncthreads();
    {
        int dr = tid >> 3, sc = (tid & 7) * 4;
        half4v h4, l4;
#pragma unroll
        for (int j = 0; j < 4; ++j) {
            float x = tl[sc + j][dr];
            _Float16 hv = (_Float16)x;
            h4[j] = hv;
            l4[j] = (_Float16)((x - (float)hv) * SPLIT_);
        }
        size_t dst = (size_t)(bk * 64 + d0 + dr) * 1024 + s0 + sc;
        *(half4v*)(vth + dst) = h4;
        *(half4v*)(vtl + dst) = l4;
    }
}

// ================= RMSNorm (fp32 + split f16 outputs) =================
__global__ __launch_bounds__(256) void k_rmsnorm(const float* __restrict__ x,
                                                 const float* __restrict__ w,
                                                 float* __restrict__ y,
                                                 _Float16* __restrict__ yh,
                                                 _Float16* __restrict__ yl) {
    int t = blockIdx.x;
    const float* row = x + (size_t)t * H_;
    float ss = 0.f;
    for (int i = threadIdx.x; i < H_ / 4; i += 256) {
        float4 v = ((const float4*)row)[i];
        ss += v.x * v.x + v.y * v.y + v.z * v.z + v.w * v.w;
    }
    for (int o = 32; o >= 1; o >>= 1) ss += __shfl_xor(ss, o);
    __shared__ float wsum[4];
    if ((threadIdx.x & 63) == 0) wsum[threadIdx.x >> 6] = ss;
    __syncthreads();
    float tot = wsum[0] + wsum[1] + wsum[2] + wsum[3];
    float r = rsqrtf(tot / (float)H_ + EPS_);
    float* yrow = y + (size_t)t * H_;
    _Float16* hrow = yh + (size_t)t * H_;
    _Float16* lrow = yl + (size_t)t * H_;
    for (int i = threadIdx.x; i < H_ / 4; i += 256) {
        float4 v = ((const float4*)row)[i];
        float4 g = ((const float4*)w)[i];
        float o4[4];
        o4[0] = v.x * r * g.x; o4[1] = v.y * r * g.y;
        o4[2] = v.z * r * g.z; o4[3] = v.w * r * g.w;
        ((float4*)yrow)[i] = *(float4*)o4;
        half4v h4, l4;
#pragma unroll
        for (int j = 0; j < 4; ++j) {
            _Float16 hv = (_Float16)o4[j];
            h4[j] = hv;
            l4[j] = (_Float16)((o4[j] - (float)hv) * SPLIT_);
        }
        ((half4v*)hrow)[i] = h4;
        ((half4v*)lrow)[i] = l4;
    }
}

// ================= RoPE -> head-major split q/k =================
__global__ __launch_bounds__(256) void k_rope_sp(const float* __restrict__ qbuf,
                                                 const float* __restrict__ kbuf,
                                                 const float* __restrict__ cs,
                                                 const float* __restrict__ sn,
                                                 _Float16* __restrict__ qh, _Float16* __restrict__ ql,
                                                 _Float16* __restrict__ kh, _Float16* __restrict__ kl) {
    int t = blockIdx.x;
    int b = t >> 10, s = t & 1023;
    size_t cb = (size_t)t * 64;
    for (int p = threadIdx.x; p < 40 * 32; p += 256) {
        int head = p >> 5, d = p & 31;
        float c1 = cs[cb + d],      s1v = sn[cb + d];
        float c2 = cs[cb + d + 32], s2v = sn[cb + d + 32];
        float x1, x2; size_t dst;
        _Float16 *oh, *ol;
        if (head < 32) {
            const float* src = qbuf + (size_t)t * 2048 + head * 64;
            x1 = src[d]; x2 = src[d + 32];
            dst = (((size_t)b * 32 + head) * 1024 + s) * 64 + d;
            oh = qh; ol = ql;
        } else {
            int hk = head - 32;
            const float* src = kbuf + (size_t)t * 512 + hk * 64;
            x1 = src[d]; x2 = src[d + 32];
            dst = (((size_t)b * 8 + hk) * 1024 + s) * 64 + d;
            oh = kh; ol = kl;
        }
        float r1 = x1 * c1 - x2 * s1v;
        float r2 = x2 * c2 + x1 * s2v;
        _Float16 h1 = (_Float16)r1;
        oh[dst] = h1; ol[dst] = (_Float16)((r1 - (float)h1) * SPLIT_);
        _Float16 h2 = (_Float16)r2;
        oh[dst + 32] = h2; ol[dst + 32] = (_Float16)((r2 - (float)h2) * SPLIT_);
    }
}

// ================= MFMA flash attention (split-fp16, fp32-accurate) ===========
#define PPITCH 68
union U8h { unsigned w[4]; half8 v; };

__global__ __launch_bounds__(256, 1) void k_attn_m(
        const _Float16* __restrict__ qhg, const _Float16* __restrict__ qlg,
        const _Float16* __restrict__ khg, const _Float16* __restrict__ klg,
        const _Float16* __restrict__ vthg, const _Float16* __restrict__ vtlg,
        const float* __restrict__ sinks, float* __restrict__ attnb) {
    __shared__ _Float16 Khs[4096], Kls[4096], Vhs[4096], Vls[4096];
    __shared__ unsigned Pp[4][64 * PPITCH];
    const int bx = blockIdx.x;
    const int b = bx >> 7, kvh = (bx >> 4) & 7, tile = bx & 15;
    const int i0 = tile * 64;
    const int tid = threadIdx.x, lane = tid & 63, wid = tid >> 6;
    const int l15 = lane & 15, g = lane >> 4;
    const int h = kvh * 4 + wid;
    const size_t kvbase = (size_t)(b * 8 + kvh) * 1024 * 64;
    const size_t vbase  = (size_t)(b * 8 + kvh) * 64 * 1024;
    half8 aqh[4][2], aql[4][2];
    {
        const size_t qb0 = ((size_t)(b * 32 + h) * 1024 + i0) * 64;
#pragma unroll
        for (int mf = 0; mf < 4; ++mf)
#pragma unroll
            for (int ks = 0; ks < 2; ++ks) {
                size_t a = qb0 + (size_t)(16 * mf + l15) * 64 + ks * 32 + g * 8;
                aqh[mf][ks] = *(const half8*)(qhg + a);
                aql[mf][ks] = *(const half8*)(qlg + a);
            }
    }
    floatx4 o1[4][4], o2[4][4];
    float m_run[4][4], l_run[4][4];
#pragma unroll
    for (int mf = 0; mf < 4; ++mf)
#pragma unroll
        for (int x = 0; x < 4; ++x) {
            o1[mf][x] = (floatx4)0.f; o2[mf][x] = (floatx4)0.f;
            m_run[mf][x] = -1e20f; l_run[mf][x] = 0.f;
        }
    const int nch = tile >= 2 ? 3 : tile + 1;
    const int jr = tid >> 3, cc = tid & 7;
    unsigned* pw = &Pp[wid][0];
    for (int ci = 0; ci < nch; ++ci) {
        const int jb = i0 - 64 * (nch - 1 - ci);
        __syncthreads();
        {
            const int sw0 = (cc ^ (jr & 7)) * 8;
            const size_t k0 = kvbase + (size_t)(jb + jr) * 64 + sw0;
            const size_t k1 = kvbase + (size_t)(jb + jr + 32) * 64 + sw0;
            gload16(khg + k0, Khs + tid * 8);
            gload16(khg + k1, Khs + 2048 + tid * 8);
            gload16(klg + k0, Kls + tid * 8);
            gload16(klg + k1, Kls + 2048 + tid * 8);
            const size_t v0 = vbase + (size_t)jr * 1024 + jb + sw0;
            const size_t v1 = vbase + (size_t)(jr + 32) * 1024 + jb + sw0;
            gload16(vthg + v0, Vhs + tid * 8);
            gload16(vthg + v1, Vhs + 2048 + tid * 8);
            gload16(vtlg + v0, Vls + tid * 8);
            gload16(vtlg + v1, Vls + 2048 + tid * 8);
        }
        __syncthreads();
        floatx4 s1[4][4], s2[4][4];
#pragma unroll
        for (int mf = 0; mf < 4; ++mf)
#pragma unroll
            for (int nf = 0; nf < 4; ++nf) { s1[mf][nf] = (floatx4)0.f; s2[mf][nf] = (floatx4)0.f; }
#pragma unroll
        for (int ks = 0; ks < 2; ++ks) {
            half8 kbh[4], kbl[4];
#pragma unroll
            for (int nf = 0; nf < 4; ++nf) {
                int j = l15 + 16 * nf;
                int c = (g + 4 * ks) ^ (j & 7);
                kbh[nf] = *(const half8*)&Khs[j * 64 + c * 8];
                kbl[nf] = *(const half8*)&Kls[j * 64 + c * 8];
            }
#pragma unroll
            for (int mf = 0; mf < 4; ++mf)
#pragma unroll
                for (int nf = 0; nf < 4; ++nf) {
                    s1[mf][nf] = MF16(aqh[mf][ks], kbh[nf], s1[mf][nf]);
                    s2[mf][nf] = MF16(aqh[mf][ks], kbl[nf], s2[mf][nf]);
                    s2[mf][nf] = MF16(aql[mf][ks], kbh[nf], s2[mf][nf]);
                }
        }
#pragma unroll
        for (int mf = 0; mf < 4; ++mf)
#pragma unroll
            for (int reg = 0; reg < 4; ++reg) {
                int i = i0 + 16 * mf + g * 4 + reg;
                float best = -1e30f;
#pragma unroll
                for (int nf = 0; nf < 4; ++nf) {
                    int j = jb + 16 * nf + l15;
                    float sv = (s1[mf][nf][reg] + s2[mf][nf][reg] * INV_SPLIT_) * SCALE_;
                    bool ok = (j <= i) && (i - j < WIN_);
                    sv = ok ? sv : -1e30f;
                    s1[mf][nf][reg] = sv;
                    best = fmaxf(best, sv);
                }
                for (int off = 1; off < 16; off <<= 1) best = fmaxf(best, __shfl_xor(best, off));
                float nm = fmaxf(m_run[mf][reg], best);
                float sc = __expf(m_run[mf][reg] - nm);
                m_run[mf][reg] = nm;
                l_run[mf][reg] *= sc;
#pragma unroll
                for (int nf = 0; nf < 4; ++nf) { o1[mf][nf][reg] *= sc; o2[mf][nf][reg] *= sc; }
            }
#pragma unroll
        for (int mf = 0; mf < 4; ++mf)
#pragma unroll
            for (int nf = 0; nf < 4; ++nf)
#pragma unroll
                for (int reg = 0; reg < 4; ++reg) {
                    float pv = __expf(s1[mf][nf][reg] - m_run[mf][reg]);
                    l_run[mf][reg] += pv;
                    _Float16 hv = (_Float16)pv;
                    _Float16 lv = (_Float16)((pv - (float)hv) * SPLIT_);
                    union { _Float16 h; unsigned short u; } ch, cl;
                    ch.h = hv; cl.h = lv;
                    int t = 16 * mf + g * 4 + reg, jj = l15 + 16 * nf;
                    pw[t * PPITCH + jj] = (unsigned)ch.u | ((unsigned)cl.u << 16);
                }
#pragma unroll
        for (int ks = 0; ks < 2; ++ks) {
            half8 bvh[4], bvl[4];
#pragma unroll
            for (int nf = 0; nf < 4; ++nf) {
                int d = l15 + 16 * nf;
                int c = (g + 4 * ks) ^ (d & 7);
                bvh[nf] = *(const half8*)&Vhs[d * 64 + c * 8];
                bvl[nf] = *(const half8*)&Vls[d * 64 + c * 8];
            }
#pragma unroll
            for (int mf = 0; mf < 4; ++mf) {
                const unsigned* pr = &pw[(16 * mf + l15) * PPITCH + 32 * ks + g * 8];
                int4 va = *(const int4*)pr;
                int4 vb = *(const int4*)(pr + 4);
                U8h ph, pl;
                ph.w[0] = ((unsigned)va.x & 0xffffu) | ((unsigned)va.y << 16);
                ph.w[1] = ((unsigned)va.z & 0xffffu) | ((unsigned)va.w << 16);
                ph.w[2] = ((unsigned)vb.x & 0xffffu) | ((unsigned)vb.y << 16);
                ph.w[3] = ((unsigned)vb.z & 0xffffu) | ((unsigned)vb.w << 16);
                pl.w[0] = ((unsigned)va.x >> 16) | ((unsigned)va.y & 0xffff0000u);
                pl.w[1] = ((unsigned)va.z >> 16) | ((unsigned)va.w & 0xffff0000u);
                pl.w[2] = ((unsigned)vb.x >> 16) | ((unsigned)vb.y & 0xffff0000u);
                pl.w[3] = ((unsigned)vb.z >> 16) | ((unsigned)vb.w & 0xffff0000u);
#pragma unroll
                for (int nf = 0; nf < 4; ++nf) {
                    o1[mf][nf] = MF16(ph.v, bvh[nf], o1[mf][nf]);
                    o2[mf][nf] = MF16(ph.v, bvl[nf], o2[mf][nf]);
                    o2[mf][nf] = MF16(pl.v, bvh[nf], o2[mf][nf]);
                }
            }
        }
    }
    const float sinkv = sinks[h];
    float inv[4][4];
#pragma unroll
    for (int mf = 0; mf < 4; ++mf)
#pragma unroll
        for (int reg = 0; reg < 4; ++reg) {
            float l = l_run[mf][reg];
            for (int off = 1; off < 16; off <<= 1) l += __shfl_xor(l, off);
            inv[mf][reg] = 1.f / (l + __expf(sinkv - m_run[mf][reg]));
        }
#pragma unroll
    for (int mf = 0; mf < 4; ++mf)
#pragma unroll
        for (int nf = 0; nf < 4; ++nf)
#pragma unroll
            for (int reg = 0; reg < 4; ++reg) {
                int t = i0 + 16 * mf + g * 4 + reg;
                int d = l15 + 16 * nf;
                float ov = (o1[mf][nf][reg] + o2[mf][nf][reg] * INV_SPLIT_) * inv[mf][reg];
                attnb[((size_t)(b * 1024 + t) * 32 + h) * 64 + d] = ov;
            }
}

// ================= Router =================
__global__ __launch_bounds__(256) void k_router(const float* __restrict__ x,
                                                const float* __restrict__ rw,
                                                const float* __restrict__ rb,
                                                int* __restrict__ topi,
                                                float* __restrict__ topw) {
    int t = blockIdx.x;
    int e = threadIdx.x >> 4, g = threadIdx.x & 15;
    const float* row = x + (size_t)t * H_;
    const float* wr = rw + (size_t)e * H_;
    float acc = 0.f;
    int kbeg = g * (H_ / 16);
    for (int kk = 0; kk < H_ / 16; kk += 4) {
        float4 xv = *(const float4*)(row + kbeg + kk);
        float4 wv = *(const float4*)(wr + kbeg + kk);
        acc += xv.x * wv.x + xv.y * wv.y + xv.z * wv.z + xv.w * wv.w;
    }
    __shared__ float part[16][17];
    part[e][g] = acc;
    __syncthreads();
    __shared__ float logits[16];
    if (threadIdx.x < 16) {
        float s2 = rb[threadIdx.x];
        for (int g2 = 0; g2 < 16; g2++) s2 += part[threadIdx.x][g2];
        logits[threadIdx.x] = s2;
    }
    __syncthreads();
    if (threadIdx.x == 0) {
        float tv[4]; int ti4[4];
        unsigned used = 0;
        for (int s3 = 0; s3 < 4; s3++) {
            float best = -3.0e38f; int bi = 0;
            for (int e2 = 0; e2 < 16; e2++)
                if (!((used >> e2) & 1) && logits[e2] > best) { best = logits[e2]; bi = e2; }
            used |= 1u << bi; tv[s3] = best; ti4[s3] = bi;
        }
        float mx = tv[0], pe[4], sum = 0.f;
        for (int s3 = 0; s3 < 4; s3++) { pe[s3] = __expf(tv[s3] - mx); sum += pe[s3]; }
        for (int s3 = 0; s3 < 4; s3++) {
            topw[t * 4 + s3] = pe[s3] / sum;
            topi[t * 4 + s3] = ti4[s3];
        }
    }
}

// ================= MoE prep =================
__global__ void k_zero(int* counts) { if (threadIdx.x < E_) counts[threadIdx.x] = 0; }

__global__ void k_hist(const int* __restrict__ topi, int* counts) {
    int g = blockIdx.x * 256 + threadIdx.x;
    if (g < T_ * TOPK_) atomicAdd(&counts[topi[g]], 1);
}

// scan + build compact MoE tile table (<=80 row-tiles of 128)
__global__ void k_scan(const int* __restrict__ counts, int* offs, int* cursor,
                       int* te, int* tm, int* ntt) {
    if (threadIdx.x == 0 && blockIdx.x == 0) {
        int run = 0, t = 0;
        for (int e = 0; e < E_; e++) {
            offs[e] = run; cursor[e] = run;
            for (int m0 = 0; m0 < counts[e]; m0 += 128) { te[t] = e; tm[t] = m0; t++; }
            run += counts[e];
        }
        ntt[0] = t;
    }
}

__global__ void k_scatter(const int* __restrict__ topi, const float* __restrict__ topw,
                          int* cursor, int* __restrict__ perm, float* __restrict__ pw) {
    int g = blockIdx.x * 256 + threadIdx.x;
    if (g >= T_ * TOPK_) return;
    int e = topi[g];
    int pos = atomicAdd(&cursor[e], 1);
    perm[pos] = g >> 2;
    pw[pos] = topw[g];
}

// ================= launch =================
extern "C" void kernel_launch(void* const* d_in, const int* in_sizes, int n_in,
                              void* d_out, int out_size, void* d_ws, size_t ws_size,
                              hipStream_t stream) {
    const float* hidden = (const float*)d_in[0];
    const float* cosp  = (const float*)d_in[1];
    const float* sinp  = (const float*)d_in[2];
    const float* ln1   = (const float*)d_in[3];
    const float* ln2   = (const float*)d_in[4];
    const float* qw    = (const float*)d_in[5];
    const float* qb    = (const float*)d_in[6];
    const float* kw    = (const float*)d_in[7];
    const float* kbia  = (const float*)d_in[8];
    const float* vw    = (const float*)d_in[9];
    const float* vbia  = (const float*)d_in[10];
    const float* ow    = (const float*)d_in[11];
    const float* ob    = (const float*)d_in[12];
    const float* sinks = (const float*)d_in[13];
    const float* rw    = (const float*)d_in[14];
    const float* rb    = (const float*)d_in[15];
    const float* gup   = (const float*)d_in[16];
    const float* gub   = (const float*)d_in[17];
    const float* dwp   = (const float*)d_in[18];
    const float* dwb   = (const float*)d_in[19];
    float* out = (float*)d_out;

    char* p = (char*)d_ws;
    auto alloc = [&](size_t bytes) { char* r = p; p += (bytes + 255) & ~(size_t)255; return r; };
    float*     xnorm  = (float*)alloc((size_t)T_ * H_ * 4);
    _Float16*  xh     = (_Float16*)alloc((size_t)T_ * H_ * 2);
    _Float16*  xl     = (_Float16*)alloc((size_t)T_ * H_ * 2);
    float*     qbuf   = (float*)alloc((size_t)T_ * NH_ * HD_ * 4);
    float*     kbuf   = (float*)alloc((size_t)T_ * NKV_ * HD_ * 4);
    float*     vbuf   = (float*)alloc((size_t)T_ * NKV_ * HD_ * 4);
    float*     attnb  = (float*)alloc((size_t)T_ * NH_ * HD_ * 4);
    _Float16*  ath    = (_Float16*)alloc((size_t)T_ * NH_ * HD_ * 2);
    _Float16*  atl    = (_Float16*)alloc((size_t)T_ * NH_ * HD_ * 2);
    _Float16*  gatedh = (_Float16*)alloc((size_t)T_ * TOPK_ * ED_ * 2);
    _Float16*  qwh    = (_Float16*)alloc((size_t)2048 * H_ * 2);
    _Float16*  qwl    = (_Float16*)alloc((size_t)2048 * H_ * 2);
    _Float16*  kwh    = (_Float16*)alloc((size_t)512 * H_ * 2);
    _Float16*  kwl    = (_Float16*)alloc((size_t)512 * H_ * 2);
    _Float16*  vwh    = (_Float16*)alloc((size_t)512 * H_ * 2);
    _Float16*  vwl    = (_Float16*)alloc((size_t)512 * H_ * 2);
    _Float16*  owh    = (_Float16*)alloc((size_t)H_ * 2048 * 2);
    _Float16*  owl    = (_Float16*)alloc((size_t)H_ * 2048 * 2);
    _Float16*  gupt   = (_Float16*)alloc((size_t)E_ * 2048 * H_ * 2);
    _Float16*  dwnt   = (_Float16*)alloc((size_t)E_ * H_ * ED_ * 2);
    _Float16*  qhb    = (_Float16*)alloc((size_t)T_ * NH_ * HD_ * 2);
    _Float16*  qlb    = (_Float16*)alloc((size_t)T_ * NH_ * HD_ * 2);
    _Float16*  khb    = (_Float16*)alloc((size_t)T_ * NKV_ * HD_ * 2);
    _Float16*  klb    = (_Float16*)alloc((size_t)T_ * NKV_ * HD_ * 2);
    _Float16*  vthb   = (_Float16*)alloc((size_t)T_ * NKV_ * HD_ * 2);
    _Float16*  vtlb   = (_Float16*)alloc((size_t)T_ * NKV_ * HD_ * 2);
    float*     topw   = (float*)alloc(T_ * TOPK_ * 4);
    float*     pwb    = (float*)alloc(T_ * TOPK_ * 4);
    int*       topi   = (int*)alloc(T_ * TOPK_ * 4);
    int*       perm   = (int*)alloc(T_ * TOPK_ * 4);
    int*       counts = (int*)alloc(E_ * 4);
    int*       offs   = (int*)alloc(E_ * 4);
    int*       cursor = (int*)alloc(E_ * 4);
    int*       te     = (int*)alloc(MAXT_ * 4);
    int*       tm     = (int*)alloc(MAXT_ * 4);
    int*       ntt    = (int*)alloc(4);

    // weight conversions
    k_cvts<<<2048, 256, 0, stream>>>(qw, qwh, qwl, 2048 * H_ / 8);
    k_cvts<<<512, 256, 0, stream>>>(kw, kwh, kwl, 512 * H_ / 8);
    k_cvts<<<512, 256, 0, stream>>>(vw, vwh, vwl, 512 * H_ / 8);
    k_cvts<<<2048, 256, 0, stream>>>(ow, owh, owl, H_ * 2048 / 8);
    k_cvt_t<<<dim3(H_ / 32, 2048 / 32, E_), 256, 0, stream>>>(gup, gupt, H_, 2048);
    k_cvt_t<<<dim3(ED_ / 32, H_ / 32, E_), 256, 0, stream>>>(dwp, dwnt, ED_, H_);

    k_rmsnorm<<<T_, 256, 0, stream>>>(hidden, ln1, xnorm, xh, xl);
    // QKV: init C with bias, split-K=4 GEMMs atomically accumulate
    k_initc<<<4096, 256, 0, stream>>>(qb, nullptr, qbuf, 2048, T_ * 2048 / 4);
    k_initc<<<1024, 256, 0, stream>>>(kbia, nullptr, kbuf, 512, T_ * 512 / 4);
    k_initc<<<1024, 256, 0, stream>>>(vbia, nullptr, vbuf, 512, T_ * 512 / 4);
    k_gemm_spk<<<1024, 256, 0, stream>>>(xh, xl, qwh, qwl, qbuf, 2048, H_);
    k_gemm_spk<<<256, 256, 0, stream>>>(xh, xl, kwh, kwl, kbuf, 512, H_);
    k_gemm_spk<<<256, 256, 0, stream>>>(xh, xl, vwh, vwl, vbuf, 512, H_);
    k_rope_sp<<<T_, 256, 0, stream>>>(qbuf, kbuf, cosp, sinp, qhb, qlb, khb, klb);
    k_cvt_vt<<<dim3(32, 2, 16), 256, 0, stream>>>(vbuf, vthb, vtlb);
    k_attn_m<<<256, 256, 0, stream>>>(qhb, qlb, khb, klb, vthb, vtlb, sinks, attnb);
    k_cvts<<<2048, 256, 0, stream>>>(attnb, ath, atl, T_ * NH_ * HD_ / 8);
    // O-proj: out = hidden + ob + attn @ ow^T (init + split-K atomic)
    k_initc<<<4096, 256, 0, stream>>>(ob, hidden, out, 2048, T_ * 2048 / 4);
    k_gemm_spk<<<1024, 256, 0, stream>>>(ath, atl, owh, owl, out, 2048, H_);
    k_rmsnorm<<<T_, 256, 0, stream>>>(out, ln2, xnorm, xh, xl);
    k_router<<<T_, 256, 0, stream>>>(xnorm, rw, rb, topi, topw);
    k_zero<<<1, 64, 0, stream>>>(counts);
    k_hist<<<(T_ * TOPK_ + 255) / 256, 256, 0, stream>>>(topi, counts);
    k_scan<<<1, 1, 0, stream>>>(counts, offs, cursor, te, tm, ntt);
    k_scatter<<<(T_ * TOPK_ + 255) / 256, 256, 0, stream>>>(topi, topw, cursor, perm, pwb);
    k_moe1<<<MAXT_ * 16, 256, 0, stream>>>(xh, gupt, gub, perm, counts, offs, te, tm, ntt, gatedh);
    k_moe2<<<MAXT_ * 16, 256, 0, stream>>>(gatedh, dwnt, dwb, perm, pwb, counts, offs, te, tm, ntt, out);
}

// Round 8
// 963.909 us; speedup vs baseline: 5.0325x; 1.0274x over previous
//
#include <hip/hip_runtime.h>
#include <hip/hip_bf16.h>
#include <cstdint>

#define B_    2
#define S_    1024
#define H_    2048
#define NH_   32
#define NKV_  8
#define HD_   64
#define T_    (B_*S_)
#define E_    16
#define ED_   1024
#define TOPK_ 4
#define WIN_  128
#define LIMIT_ 7.0f
#define ALPHA_ 1.702f
#define EPS_   1e-6f
#define SCALE_ 0.125f  /* HD^-0.5 */
#define SPLIT_ 2048.0f
#define INV_SPLIT_ 4.8828125e-4f
#define MAXT_ 80      /* max MoE row-tiles: 64 + 16 */

typedef _Float16 half8 __attribute__((ext_vector_type(8)));
typedef _Float16 half4v __attribute__((ext_vector_type(4)));
typedef float floatx4 __attribute__((ext_vector_type(4)));

#define MF16(a,b,c) __builtin_amdgcn_mfma_f32_16x16x32_f16(a,b,c,0,0,0)

__device__ __forceinline__ void gload16(const void* g, void* l) {
    __builtin_amdgcn_global_load_lds((const __attribute__((address_space(1))) void*)g,
                                     (__attribute__((address_space(3))) void*)l, 16, 0, 0);
}

// bijective chunked XCD swizzle (nwg % 8 == 0)
__device__ __forceinline__ int xcd_swz(int bid, int nwg) {
    int cpx = nwg >> 3;
    return (bid & 7) * cpx + (bid >> 3);
}

// ================= C init: C = bias (+res) =================
__global__ __launch_bounds__(256) void k_initc(const float* __restrict__ bias,
                                               const float* __restrict__ res,
                                               float* __restrict__ C, int N, int n4) {
    int i = blockIdx.x * 256 + threadIdx.x;
    if (i >= n4) return;
    int c4 = (i % (N >> 2)) << 2;
    float4 v = *(const float4*)(bias + c4);
    if (res) {
        float4 r = ((const float4*)res)[i];
        v.x += r.x; v.y += r.y; v.z += r.z; v.w += r.w;
    }
    ((float4*)C)[i] = v;
}

// ===== split-fp16 GEMM, split-K=4, 2-phase double-buffered LDS =====
// grid = (N/128) * 16 * 4 (1D). wg: n = wg>>6, m = (wg&63)>>2, ks = wg&3.
__global__ __launch_bounds__(256) void k_gemm_spk(const _Float16* __restrict__ Ah,
                                                  const _Float16* __restrict__ Al,
                                                  const _Float16* __restrict__ Bh,
                                                  const _Float16* __restrict__ Bl,
                                                  float* __restrict__ C, int N, int K) {
    __shared__ _Float16 Ahs[2][128 * 32];
    __shared__ _Float16 Als[2][128 * 32];
    __shared__ _Float16 Bhs[2][128 * 32];
    __shared__ _Float16 Bls[2][128 * 32];
    const int tid = threadIdx.x;
    const int lane = tid & 63;
    const int wid = tid >> 6;
    const int wr = wid >> 1, wc = wid & 1;
    const int wg = xcd_swz(blockIdx.x, gridDim.x);
    const int col0 = (wg >> 6) * 128;
    const int row0 = ((wg & 63) >> 2) * 128;
    const int ks4 = wg & 3;
    const int kbeg = ks4 * (K >> 2), kend = kbeg + (K >> 2);
    floatx4 acc1[4][4], acc2[4][4];
    for (int m = 0; m < 4; ++m)
        for (int n = 0; n < 4; ++n) { acc1[m][n] = (floatx4)0.f; acc2[m][n] = (floatx4)0.f; }
    const int rL = tid >> 2, koff = (tid & 3) * 8;
    const size_t o0 = (size_t)(row0 + rL) * K + koff;
    const size_t o1 = (size_t)(row0 + 64 + rL) * K + koff;
    const size_t p0 = (size_t)(col0 + rL) * K + koff;
    const size_t p1 = (size_t)(col0 + 64 + rL) * K + koff;
#define DSTAGE(buf, kk) do { \
        gload16(Ah + o0 + (kk), Ahs[buf] + tid * 8); gload16(Ah + o1 + (kk), Ahs[buf] + 2048 + tid * 8); \
        gload16(Al + o0 + (kk), Als[buf] + tid * 8); gload16(Al + o1 + (kk), Als[buf] + 2048 + tid * 8); \
        gload16(Bh + p0 + (kk), Bhs[buf] + tid * 8); gload16(Bh + p1 + (kk), Bhs[buf] + 2048 + tid * 8); \
        gload16(Bl + p0 + (kk), Bls[buf] + tid * 8); gload16(Bl + p1 + (kk), Bls[buf] + 2048 + tid * 8); \
    } while (0)
    DSTAGE(0, kbeg);
    int cur = 0;
    for (int k0 = kbeg; k0 < kend; k0 += 32) {
        __syncthreads();               // drains prefetch vmcnt + syncs prev compute
        if (k0 + 32 < kend) DSTAGE(cur ^ 1, k0 + 32);
        const int lk = (lane >> 4) * 8;
        half8 ah[4], al[4], bh[4], bl[4];
#pragma unroll
        for (int m = 0; m < 4; ++m) {
            int ro = (wr * 64 + m * 16 + (lane & 15)) * 32 + lk;
            ah[m] = *(const half8*)&Ahs[cur][ro];
            al[m] = *(const half8*)&Als[cur][ro];
        }
#pragma unroll
        for (int n = 0; n < 4; ++n) {
            int ro = (wc * 64 + n * 16 + (lane & 15)) * 32 + lk;
            bh[n] = *(const half8*)&Bhs[cur][ro];
            bl[n] = *(const half8*)&Bls[cur][ro];
        }
#pragma unroll
        for (int m = 0; m < 4; ++m)
#pragma unroll
            for (int n = 0; n < 4; ++n) {
                acc1[m][n] = MF16(ah[m], bh[n], acc1[m][n]);
                acc2[m][n] = MF16(ah[m], bl[n], acc2[m][n]);
                acc2[m][n] = MF16(al[m], bh[n], acc2[m][n]);
            }
        cur ^= 1;
    }
#undef DSTAGE
#pragma unroll
    for (int mf = 0; mf < 4; ++mf)
#pragma unroll
        for (int i = 0; i < 4; ++i) {
            int r = row0 + wr * 64 + mf * 16 + ((lane >> 4) << 2) + i;
#pragma unroll
            for (int nf = 0; nf < 4; ++nf) {
                int c = col0 + wc * 64 + nf * 16 + (lane & 15);
                atomicAdd(&C[(size_t)r * N + c], acc1[mf][nf][i] + acc2[mf][nf][i] * INV_SPLIT_);
            }
        }
}

// ======= MoE MFMA core: BK=64, XOR-swizzled LDS, 2-phase double buffer ========
#define MOE_PROLOG() \
    __shared__ _Float16 As[2][128 * 64]; \
    __shared__ _Float16 Bs[2][128 * 64]; \
    const int tid = threadIdx.x; \
    const int lane = tid & 63; \
    const int wid = tid >> 6; \
    const int wr = wid >> 1, wc = wid & 1; \
    const int rloc = tid >> 3; \
    const int ksw = ((tid & 7) ^ (rloc & 7)) * 8; \
    floatx4 acc[4][4]; \
    for (int m = 0; m < 4; ++m) for (int n = 0; n < 4; ++n) acc[m][n] = (floatx4)0.f;

#define MOE_STAGE(buf, kk) do { \
        _Pragma("unroll") for (int c = 0; c < 4; ++c) { \
            gload16(asrc[c] + (kk), As[buf] + c * 2048 + tid * 8); \
            gload16(bsrc[c] + (kk), Bs[buf] + c * 2048 + tid * 8); \
        } \
    } while (0)

#define MOE_KLOOP(KD) \
    MOE_STAGE(0, 0); \
    { int cur = 0; \
    for (int k0 = 0; k0 < (KD); k0 += 64) { \
        __syncthreads(); \
        if (k0 + 64 < (KD)) MOE_STAGE(cur ^ 1, k0 + 64); \
        _Pragma("unroll") for (int s = 0; s < 2; ++s) { \
            const int gc = ((s * 4 + (lane >> 4)) ^ (lane & 7)) * 8; \
            half8 a[4], b[4]; \
            _Pragma("unroll") for (int m = 0; m < 4; ++m) \
                a[m] = *(const half8*)&As[cur][(wr * 64 + m * 16 + (lane & 15)) * 64 + gc]; \
            _Pragma("unroll") for (int n = 0; n < 4; ++n) \
                b[n] = *(const half8*)&Bs[cur][(wc * 64 + n * 16 + (lane & 15)) * 64 + gc]; \
            _Pragma("unroll") for (int m = 0; m < 4; ++m) \
                _Pragma("unroll") for (int n = 0; n < 4; ++n) \
                    acc[m][n] = MF16(a[m], b[n], acc[m][n]); \
        } \
        cur ^= 1; \
    } }

// MoE GEMM1: tile-table grid (80x16). gathered A rows; fused GLU -> gated f16
__global__ __launch_bounds__(256) void k_moe1(const _Float16* __restrict__ X,
                                              const _Float16* __restrict__ W,
                                              const float* __restrict__ bias,
                                              const int* __restrict__ perm,
                                              const int* __restrict__ counts,
                                              const int* __restrict__ offs,
                                              const int* __restrict__ te,
                                              const int* __restrict__ tm,
                                              const int* __restrict__ ntt,
                                              _Float16* __restrict__ gated) {
    const int wg = xcd_swz(blockIdx.x, MAXT_ * 16);
    const int tt = wg >> 4;
    if (tt >= ntt[0]) return;
    const int e = te[tt];
    const int m0 = tm[tt];
    const int ne = counts[e];
    const int base = offs[e];
    const int col0 = (wg & 15) * 128;
    MOE_PROLOG();
    const _Float16* asrc[4];
    const _Float16* bsrc[4];
#pragma unroll
    for (int c = 0; c < 4; ++c) {
        int t = perm[base + min(m0 + c * 32 + rloc, ne - 1)];
        asrc[c] = X + (size_t)t * H_ + ksw;
        bsrc[c] = W + ((size_t)e * 2048 + col0 + c * 32 + rloc) * H_ + ksw;
    }
    MOE_KLOOP(H_);
#pragma unroll
    for (int mf = 0; mf < 4; ++mf)
#pragma unroll
        for (int i = 0; i < 4; ++i) {
            int r = m0 + wr * 64 + mf * 16 + ((lane >> 4) << 2) + i;
            bool ok = r < ne;
            int slot = base + r;
#pragma unroll
            for (int nf = 0; nf < 4; ++nf) {
                int c = col0 + wc * 64 + nf * 16 + (lane & 15);
                float v = acc[mf][nf][i] + bias[e * 2048 + c];
                float o = __shfl_xor(v, 1);
                if (ok && !(lane & 1)) {
                    float gt = fminf(v, LIMIT_);
                    float up = fminf(fmaxf(o, -LIMIT_), LIMIT_);
                    float sg = 1.f / (1.f + __expf(-ALPHA_ * gt));
                    gated[(size_t)slot * ED_ + (c >> 1)] = (_Float16)((up + 1.f) * (gt * sg));
                }
            }
        }
}

__global__ __launch_bounds__(256) void k_moe2(const _Float16* __restrict__ G,
                                              const _Float16* __restrict__ W,
                                              const float* __restrict__ bias,
                                              const int* __restrict__ perm,
                                              const float* __restrict__ pw,
                                              const int* __restrict__ counts,
                                              const int* __restrict__ offs,
                                              const int* __restrict__ te,
                                              const int* __restrict__ tm,
                                              const int* __restrict__ ntt,
                                              float* __restrict__ out) {
    const int wg = xcd_swz(blockIdx.x, MAXT_ * 16);
    const int tt = wg >> 4;
    if (tt >= ntt[0]) return;
    const int e = te[tt];
    const int m0 = tm[tt];
    const int ne = counts[e];
    const int base = offs[e];
    const int col0 = (wg & 15) * 128;
    MOE_PROLOG();
    const _Float16* asrc[4];
    const _Float16* bsrc[4];
#pragma unroll
    for (int c = 0; c < 4; ++c) {
        int s = base + min(m0 + c * 32 + rloc, ne - 1);
        asrc[c] = G + (size_t)s * ED_ + ksw;
        bsrc[c] = W + ((size_t)e * H_ + col0 + c * 32 + rloc) * ED_ + ksw;
    }
    MOE_KLOOP(ED_);
#pragma unroll
    for (int mf = 0; mf < 4; ++mf)
#pragma unroll
        for (int i = 0; i < 4; ++i) {
            int r = m0 + wr * 64 + mf * 16 + ((lane >> 4) << 2) + i;
            if (r >= ne) continue;
            int slot = base + r;
            int tok = perm[slot];
            float wgt = pw[slot];
#pragma unroll
            for (int nf = 0; nf < 4; ++nf) {
                int c = col0 + wc * 64 + nf * 16 + (lane & 15);
                atomicAdd(&out[(size_t)tok * H_ + c], wgt * (acc[mf][nf][i] + bias[e * H_ + c]));
            }
        }
}

// ================= conversions =================
__global__ __launch_bounds__(256) void k_cvts(const float* __restrict__ s,
                                              _Float16* __restrict__ dh,
                                              _Float16* __restrict__ dl, int n8) {
    int i = blockIdx.x * 256 + threadIdx.x;
    if (i >= n8) return;
    float4 x = ((const float4*)s)[i * 2], y = ((const float4*)s)[i * 2 + 1];
    float xs[8] = {x.x, x.y, x.z, x.w, y.x, y.y, y.z, y.w};
    half8 h, l;
#pragma unroll
    for (int j = 0; j < 8; ++j) {
        _Float16 hv = (_Float16)xs[j];
        h[j] = hv;
        l[j] = (_Float16)((xs[j] - (float)hv) * SPLIT_);
    }
    ((half8*)dh)[i] = h;
    ((half8*)dl)[i] = l;
}

__global__ __launch_bounds__(256) void k_cvt_t(const float* __restrict__ src,
                                               _Float16* __restrict__ dst, int K, int N) {
    const int e = blockIdx.z;
    const int k0 = blockIdx.x * 32, n0 = blockIdx.y * 32;
    __shared__ float t[32][33];
    const int tid = threadIdx.x;
    {
        int kr = tid >> 3, nc = (tid & 7) * 4;
        float4 v = *(const float4*)(src + ((size_t)e * K + k0 + kr) * N + n0 + nc);
        t[kr][nc] = v.x; t[kr][nc + 1] = v.y; t[kr][nc + 2] = v.z; t[kr][nc + 3] = v.w;
    }
    __syncthreads();
    {
        int nr = tid >> 3, kc = (tid & 7) * 4;
        half4v o;
        o[0] = (_Float16)t[kc + 0][nr];
        o[1] = (_Float16)t[kc + 1][nr];
        o[2] = (_Float16)t[kc + 2][nr];
        o[3] = (_Float16)t[kc + 3][nr];
        *(half4v*)(dst + ((size_t)e * N + n0 + nr) * K + k0 + kc) = o;
    }
}

// v transpose-split: vbuf fp32 [b][s][kvh][64] -> vth/vtl [b][kvh][64 d][1024 s]
__global__ __launch_bounds__(256) void k_cvt_vt(const float* __restrict__ vbuf,
                                                _Float16* __restrict__ vth,
                                                _Float16* __restrict__ vtl) {
    const int s0 = blockIdx.x * 32, d0 = blockIdx.y * 32;
    const int bk = blockIdx.z;
    const int b = bk >> 3, kvh = bk & 7;
    __shared__ float tl[32][33];
    const int tid = threadIdx.x;
    {
        int sr = tid >> 3, dc = (tid & 7) * 4;
        float4 v = *(const float4*)(vbuf + (size_t)(b * 1024 + s0 + sr) * 512 + kvh * 64 + d0 + dc);
        tl[sr][dc] = v.x; tl[sr][dc + 1] = v.y; tl[sr][dc + 2] = v.z; tl[sr][dc + 3] = v.w;
    }
    __syncthreads();
    {
        int dr = tid >> 3, sc = (tid & 7) * 4;
        half4v h4, l4;
#pragma unroll
        for (int j = 0; j < 4; ++j) {
            float x = tl[sc + j][dr];
            _Float16 hv = (_Float16)x;
            h4[j] = hv;
            l4[j] = (_Float16)((x - (float)hv) * SPLIT_);
        }
        size_t dst = (size_t)(bk * 64 + d0 + dr) * 1024 + s0 + sc;
        *(half4v*)(vth + dst) = h4;
        *(half4v*)(vtl + dst) = l4;
    }
}

// ================= RMSNorm (fp32 + split f16 outputs) =================
__global__ __launch_bounds__(256) void k_rmsnorm(const float* __restrict__ x,
                                                 const float* __restrict__ w,
                                                 float* __restrict__ y,
                                                 _Float16* __restrict__ yh,
                                                 _Float16* __restrict__ yl) {
    int t = blockIdx.x;
    const float* row = x + (size_t)t * H_;
    float ss = 0.f;
    for (int i = threadIdx.x; i < H_ / 4; i += 256) {
        float4 v = ((const float4*)row)[i];
        ss += v.x * v.x + v.y * v.y + v.z * v.z + v.w * v.w;
    }
    for (int o = 32; o >= 1; o >>= 1) ss += __shfl_xor(ss, o);
    __shared__ float wsum[4];
    if ((threadIdx.x & 63) == 0) wsum[threadIdx.x >> 6] = ss;
    __syncthreads();
    float tot = wsum[0] + wsum[1] + wsum[2] + wsum[3];
    float r = rsqrtf(tot / (float)H_ + EPS_);
    float* yrow = y + (size_t)t * H_;
    _Float16* hrow = yh + (size_t)t * H_;
    _Float16* lrow = yl + (size_t)t * H_;
    for (int i = threadIdx.x; i < H_ / 4; i += 256) {
        float4 v = ((const float4*)row)[i];
        float4 g = ((const float4*)w)[i];
        float o4[4];
        o4[0] = v.x * r * g.x; o4[1] = v.y * r * g.y;
        o4[2] = v.z * r * g.z; o4[3] = v.w * r * g.w;
        ((float4*)yrow)[i] = *(float4*)o4;
        half4v h4, l4;
#pragma unroll
        for (int j = 0; j < 4; ++j) {
            _Float16 hv = (_Float16)o4[j];
            h4[j] = hv;
            l4[j] = (_Float16)((o4[j] - (float)hv) * SPLIT_);
        }
        ((half4v*)hrow)[i] = h4;
        ((half4v*)lrow)[i] = l4;
    }
}

// ================= RoPE -> head-major split q/k =================
__global__ __launch_bounds__(256) void k_rope_sp(const float* __restrict__ qbuf,
                                                 const float* __restrict__ kbuf,
                                                 const float* __restrict__ cs,
                                                 const float* __restrict__ sn,
                                                 _Float16* __restrict__ qh, _Float16* __restrict__ ql,
                                                 _Float16* __restrict__ kh, _Float16* __restrict__ kl) {
    int t = blockIdx.x;
    int b = t >> 10, s = t & 1023;
    size_t cb = (size_t)t * 64;
    for (int p = threadIdx.x; p < 40 * 32; p += 256) {
        int head = p >> 5, d = p & 31;
        float c1 = cs[cb + d],      s1v = sn[cb + d];
        float c2 = cs[cb + d + 32], s2v = sn[cb + d + 32];
        float x1, x2; size_t dst;
        _Float16 *oh, *ol;
        if (head < 32) {
            const float* src = qbuf + (size_t)t * 2048 + head * 64;
            x1 = src[d]; x2 = src[d + 32];
            dst = (((size_t)b * 32 + head) * 1024 + s) * 64 + d;
            oh = qh; ol = ql;
        } else {
            int hk = head - 32;
            const float* src = kbuf + (size_t)t * 512 + hk * 64;
            x1 = src[d]; x2 = src[d + 32];
            dst = (((size_t)b * 8 + hk) * 1024 + s) * 64 + d;
            oh = kh; ol = kl;
        }
        float r1 = x1 * c1 - x2 * s1v;
        float r2 = x2 * c2 + x1 * s2v;
        _Float16 h1 = (_Float16)r1;
        oh[dst] = h1; ol[dst] = (_Float16)((r1 - (float)h1) * SPLIT_);
        _Float16 h2 = (_Float16)r2;
        oh[dst + 32] = h2; ol[dst + 32] = (_Float16)((r2 - (float)h2) * SPLIT_);
    }
}

// ================= MFMA flash attention (split-fp16, fp32-accurate) ===========
#define PPITCH 68
union U8h { unsigned w[4]; half8 v; };

__global__ __launch_bounds__(256, 1) void k_attn_m(
        const _Float16* __restrict__ qhg, const _Float16* __restrict__ qlg,
        const _Float16* __restrict__ khg, const _Float16* __restrict__ klg,
        const _Float16* __restrict__ vthg, const _Float16* __restrict__ vtlg,
        const float* __restrict__ sinks,
        _Float16* __restrict__ ath, _Float16* __restrict__ atl) {
    __shared__ _Float16 Khs[4096], Kls[4096], Vhs[4096], Vls[4096];
    __shared__ unsigned Pp[4][64 * PPITCH];
    const int bx = blockIdx.x;
    const int b = bx >> 7, kvh = (bx >> 4) & 7, tile = bx & 15;
    const int i0 = tile * 64;
    const int tid = threadIdx.x, lane = tid & 63, wid = tid >> 6;
    const int l15 = lane & 15, g = lane >> 4;
    const int h = kvh * 4 + wid;
    const size_t kvbase = (size_t)(b * 8 + kvh) * 1024 * 64;
    const size_t vbase  = (size_t)(b * 8 + kvh) * 64 * 1024;
    half8 aqh[4][2], aql[4][2];
    {
        const size_t qb0 = ((size_t)(b * 32 + h) * 1024 + i0) * 64;
#pragma unroll
        for (int mf = 0; mf < 4; ++mf)
#pragma unroll
            for (int ks = 0; ks < 2; ++ks) {
                size_t a = qb0 + (size_t)(16 * mf + l15) * 64 + ks * 32 + g * 8;
                aqh[mf][ks] = *(const half8*)(qhg + a);
                aql[mf][ks] = *(const half8*)(qlg + a);
            }
    }
    floatx4 o1[4][4], o2[4][4];
    float m_run[4][4], l_run[4][4];
#pragma unroll
    for (int mf = 0; mf < 4; ++mf)
#pragma unroll
        for (int x = 0; x < 4; ++x) {
            o1[mf][x] = (floatx4)0.f; o2[mf][x] = (floatx4)0.f;
            m_run[mf][x] = -1e20f; l_run[mf][x] = 0.f;
        }
    const int nch = tile >= 2 ? 3 : tile + 1;
    const int jr = tid >> 3, cc = tid & 7;
    unsigned* pw = &Pp[wid][0];
    for (int ci = 0; ci < nch; ++ci) {
        const int jb = i0 - 64 * (nch - 1 - ci);
        __syncthreads();
        {
            const int sw0 = (cc ^ (jr & 7)) * 8;
            const size_t k0 = kvbase + (size_t)(jb + jr) * 64 + sw0;
            const size_t k1 = kvbase + (size_t)(jb + jr + 32) * 64 + sw0;
            gload16(khg + k0, Khs + tid * 8);
            gload16(khg + k1, Khs + 2048 + tid * 8);
            gload16(klg + k0, Kls + tid * 8);
            gload16(klg + k1, Kls + 2048 + tid * 8);
            const size_t v0 = vbase + (size_t)jr * 1024 + jb + sw0;
            const size_t v1 = vbase + (size_t)(jr + 32) * 1024 + jb + sw0;
            gload16(vthg + v0, Vhs + tid * 8);
            gload16(vthg + v1, Vhs + 2048 + tid * 8);
            gload16(vtlg + v0, Vls + tid * 8);
            gload16(vtlg + v1, Vls + 2048 + tid * 8);
        }
        __syncthreads();
        floatx4 s1[4][4], s2[4][4];
#pragma unroll
        for (int mf = 0; mf < 4; ++mf)
#pragma unroll
            for (int nf = 0; nf < 4; ++nf) { s1[mf][nf] = (floatx4)0.f; s2[mf][nf] = (floatx4)0.f; }
#pragma unroll
        for (int ks = 0; ks < 2; ++ks) {
            half8 kbh[4], kbl[4];
#pragma unroll
            for (int nf = 0; nf < 4; ++nf) {
                int j = l15 + 16 * nf;
                int c = (g + 4 * ks) ^ (j & 7);
                kbh[nf] = *(const half8*)&Khs[j * 64 + c * 8];
                kbl[nf] = *(const half8*)&Kls[j * 64 + c * 8];
            }
#pragma unroll
            for (int mf = 0; mf < 4; ++mf)
#pragma unroll
                for (int nf = 0; nf < 4; ++nf) {
                    s1[mf][nf] = MF16(aqh[mf][ks], kbh[nf], s1[mf][nf]);
                    s2[mf][nf] = MF16(aqh[mf][ks], kbl[nf], s2[mf][nf]);
                    s2[mf][nf] = MF16(aql[mf][ks], kbh[nf], s2[mf][nf]);
                }
        }
#pragma unroll
        for (int mf = 0; mf < 4; ++mf)
#pragma unroll
            for (int reg = 0; reg < 4; ++reg) {
                int i = i0 + 16 * mf + g * 4 + reg;
                float best = -1e30f;
#pragma unroll
                for (int nf = 0; nf < 4; ++nf) {
                    int j = jb + 16 * nf + l15;
                    float sv = (s1[mf][nf][reg] + s2[mf][nf][reg] * INV_SPLIT_) * SCALE_;
                    bool ok = (j <= i) && (i - j < WIN_);
                    sv = ok ? sv : -1e30f;
                    s1[mf][nf][reg] = sv;
                    best = fmaxf(best, sv);
                }
                for (int off = 1; off < 16; off <<= 1) best = fmaxf(best, __shfl_xor(best, off));
                float nm = fmaxf(m_run[mf][reg], best);
                float sc = __expf(m_run[mf][reg] - nm);
                m_run[mf][reg] = nm;
                l_run[mf][reg] *= sc;
#pragma unroll
                for (int nf = 0; nf < 4; ++nf) { o1[mf][nf][reg] *= sc; o2[mf][nf][reg] *= sc; }
            }
#pragma unroll
        for (int mf = 0; mf < 4; ++mf)
#pragma unroll
            for (int nf = 0; nf < 4; ++nf)
#pragma unroll
                for (int reg = 0; reg < 4; ++reg) {
                    float pv = __expf(s1[mf][nf][reg] - m_run[mf][reg]);
                    l_run[mf][reg] += pv;
                    _Float16 hv = (_Float16)pv;
                    _Float16 lv = (_Float16)((pv - (float)hv) * SPLIT_);
                    union { _Float16 h; unsigned short u; } ch, cl;
                    ch.h = hv; cl.h = lv;
                    int t = 16 * mf + g * 4 + reg, jj = l15 + 16 * nf;
                    pw[t * PPITCH + jj] = (unsigned)ch.u | ((unsigned)cl.u << 16);
                }
#pragma unroll
        for (int ks = 0; ks < 2; ++ks) {
            half8 bvh[4], bvl[4];
#pragma unroll
            for (int nf = 0; nf < 4; ++nf) {
                int d = l15 + 16 * nf;
                int c = (g + 4 * ks) ^ (d & 7);
                bvh[nf] = *(const half8*)&Vhs[d * 64 + c * 8];
                bvl[nf] = *(const half8*)&Vls[d * 64 + c * 8];
            }
#pragma unroll
            for (int mf = 0; mf < 4; ++mf) {
                const unsigned* pr = &pw[(16 * mf + l15) * PPITCH + 32 * ks + g * 8];
                int4 va = *(const int4*)pr;
                int4 vb = *(const int4*)(pr + 4);
                U8h ph, pl;
                ph.w[0] = ((unsigned)va.x & 0xffffu) | ((unsigned)va.y << 16);
                ph.w[1] = ((unsigned)va.z & 0xffffu) | ((unsigned)va.w << 16);
                ph.w[2] = ((unsigned)vb.x & 0xffffu) | ((unsigned)vb.y << 16);
                ph.w[3] = ((unsigned)vb.z & 0xffffu) | ((unsigned)vb.w << 16);
                pl.w[0] = ((unsigned)va.x >> 16) | ((unsigned)va.y & 0xffff0000u);
                pl.w[1] = ((unsigned)va.z >> 16) | ((unsigned)va.w & 0xffff0000u);
                pl.w[2] = ((unsigned)vb.x >> 16) | ((unsigned)vb.y & 0xffff0000u);
                pl.w[3] = ((unsigned)vb.z >> 16) | ((unsigned)vb.w & 0xffff0000u);
#pragma unroll
                for (int nf = 0; nf < 4; ++nf) {
                    o1[mf][nf] = MF16(ph.v, bvh[nf], o1[mf][nf]);
                    o2[mf][nf] = MF16(ph.v, bvl[nf], o2[mf][nf]);
                    o2[mf][nf] = MF16(pl.v, bvh[nf], o2[mf][nf]);
                }
            }
        }
    }
    const float sinkv = sinks[h];
    float inv[4][4];
#pragma unroll
    for (int mf = 0; mf < 4; ++mf)
#pragma unroll
        for (int reg = 0; reg < 4; ++reg) {
            float l = l_run[mf][reg];
            for (int off = 1; off < 16; off <<= 1) l += __shfl_xor(l, off);
            inv[mf][reg] = 1.f / (l + __expf(sinkv - m_run[mf][reg]));
        }
    // fused split-fp16 output (feeds o-proj A operand directly)
#pragma unroll
    for (int mf = 0; mf < 4; ++mf)
#pragma unroll
        for (int nf = 0; nf < 4; ++nf)
#pragma unroll
            for (int reg = 0; reg < 4; ++reg) {
                int t = i0 + 16 * mf + g * 4 + reg;
                int d = l15 + 16 * nf;
                float ov = (o1[mf][nf][reg] + o2[mf][nf][reg] * INV_SPLIT_) * inv[mf][reg];
                size_t idx = ((size_t)(b * 1024 + t) * 32 + h) * 64 + d;
                _Float16 hv = (_Float16)ov;
                ath[idx] = hv;
                atl[idx] = (_Float16)((ov - (float)hv) * SPLIT_);
            }
}

// ================= Router =================
__global__ __launch_bounds__(256) void k_router(const float* __restrict__ x,
                                                const float* __restrict__ rw,
                                                const float* __restrict__ rb,
                                                int* __restrict__ topi,
                                                float* __restrict__ topw) {
    int t = blockIdx.x;
    int e = threadIdx.x >> 4, g = threadIdx.x & 15;
    const float* row = x + (size_t)t * H_;
    const float* wr = rw + (size_t)e * H_;
    float acc = 0.f;
    int kbeg = g * (H_ / 16);
    for (int kk = 0; kk < H_ / 16; kk += 4) {
        float4 xv = *(const float4*)(row + kbeg + kk);
        float4 wv = *(const float4*)(wr + kbeg + kk);
        acc += xv.x * wv.x + xv.y * wv.y + xv.z * wv.z + xv.w * wv.w;
    }
    __shared__ float part[16][17];
    part[e][g] = acc;
    __syncthreads();
    __shared__ float logits[16];
    if (threadIdx.x < 16) {
        float s2 = rb[threadIdx.x];
        for (int g2 = 0; g2 < 16; g2++) s2 += part[threadIdx.x][g2];
        logits[threadIdx.x] = s2;
    }
    __syncthreads();
    if (threadIdx.x == 0) {
        float tv[4]; int ti4[4];
        unsigned used = 0;
        for (int s3 = 0; s3 < 4; s3++) {
            float best = -3.0e38f; int bi = 0;
            for (int e2 = 0; e2 < 16; e2++)
                if (!((used >> e2) & 1) && logits[e2] > best) { best = logits[e2]; bi = e2; }
            used |= 1u << bi; tv[s3] = best; ti4[s3] = bi;
        }
        float mx = tv[0], pe[4], sum = 0.f;
        for (int s3 = 0; s3 < 4; s3++) { pe[s3] = __expf(tv[s3] - mx); sum += pe[s3]; }
        for (int s3 = 0; s3 < 4; s3++) {
            topw[t * 4 + s3] = pe[s3] / sum;
            topi[t * 4 + s3] = ti4[s3];
        }
    }
}

// ================= MoE prep =================
__global__ void k_zero(int* counts) { if (threadIdx.x < E_) counts[threadIdx.x] = 0; }

__global__ void k_hist(const int* __restrict__ topi, int* counts) {
    int g = blockIdx.x * 256 + threadIdx.x;
    if (g < T_ * TOPK_) atomicAdd(&counts[topi[g]], 1);
}

// scan + build compact MoE tile table (<=80 row-tiles of 128)
__global__ void k_scan(const int* __restrict__ counts, int* offs, int* cursor,
                       int* te, int* tm, int* ntt) {
    if (threadIdx.x == 0 && blockIdx.x == 0) {
        int run = 0, t = 0;
        for (int e = 0; e < E_; e++) {
            offs[e] = run; cursor[e] = run;
            for (int m0 = 0; m0 < counts[e]; m0 += 128) { te[t] = e; tm[t] = m0; t++; }
            run += counts[e];
        }
        ntt[0] = t;
    }
}

__global__ void k_scatter(const int* __restrict__ topi, const float* __restrict__ topw,
                          int* cursor, int* __restrict__ perm, float* __restrict__ pw) {
    int g = blockIdx.x * 256 + threadIdx.x;
    if (g >= T_ * TOPK_) return;
    int e = topi[g];
    int pos = atomicAdd(&cursor[e], 1);
    perm[pos] = g >> 2;
    pw[pos] = topw[g];
}

// ================= launch =================
extern "C" void kernel_launch(void* const* d_in, const int* in_sizes, int n_in,
                              void* d_out, int out_size, void* d_ws, size_t ws_size,
                              hipStream_t stream) {
    const float* hidden = (const float*)d_in[0];
    const float* cosp  = (const float*)d_in[1];
    const float* sinp  = (const float*)d_in[2];
    const float* ln1   = (const float*)d_in[3];
    const float* ln2   = (const float*)d_in[4];
    const float* qw    = (const float*)d_in[5];
    const float* qb    = (const float*)d_in[6];
    const float* kw    = (const float*)d_in[7];
    const float* kbia  = (const float*)d_in[8];
    const float* vw    = (const float*)d_in[9];
    const float* vbia  = (const float*)d_in[10];
    const float* ow    = (const float*)d_in[11];
    const float* ob    = (const float*)d_in[12];
    const float* sinks = (const float*)d_in[13];
    const float* rw    = (const float*)d_in[14];
    const float* rb    = (const float*)d_in[15];
    const float* gup   = (const float*)d_in[16];
    const float* gub   = (const float*)d_in[17];
    const float* dwp   = (const float*)d_in[18];
    const float* dwb   = (const float*)d_in[19];
    float* out = (float*)d_out;

    char* p = (char*)d_ws;
    auto alloc = [&](size_t bytes) { char* r = p; p += (bytes + 255) & ~(size_t)255; return r; };
    float*     xnorm  = (float*)alloc((size_t)T_ * H_ * 4);
    _Float16*  xh     = (_Float16*)alloc((size_t)T_ * H_ * 2);
    _Float16*  xl     = (_Float16*)alloc((size_t)T_ * H_ * 2);
    float*     qbuf   = (float*)alloc((size_t)T_ * NH_ * HD_ * 4);
    float*     kbuf   = (float*)alloc((size_t)T_ * NKV_ * HD_ * 4);
    float*     vbuf   = (float*)alloc((size_t)T_ * NKV_ * HD_ * 4);
    _Float16*  ath    = (_Float16*)alloc((size_t)T_ * NH_ * HD_ * 2);
    _Float16*  atl    = (_Float16*)alloc((size_t)T_ * NH_ * HD_ * 2);
    _Float16*  gatedh = (_Float16*)alloc((size_t)T_ * TOPK_ * ED_ * 2);
    _Float16*  qwh    = (_Float16*)alloc((size_t)2048 * H_ * 2);
    _Float16*  qwl    = (_Float16*)alloc((size_t)2048 * H_ * 2);
    _Float16*  kwh    = (_Float16*)alloc((size_t)512 * H_ * 2);
    _Float16*  kwl    = (_Float16*)alloc((size_t)512 * H_ * 2);
    _Float16*  vwh    = (_Float16*)alloc((size_t)512 * H_ * 2);
    _Float16*  vwl    = (_Float16*)alloc((size_t)512 * H_ * 2);
    _Float16*  owh    = (_Float16*)alloc((size_t)H_ * 2048 * 2);
    _Float16*  owl    = (_Float16*)alloc((size_t)H_ * 2048 * 2);
    _Float16*  gupt   = (_Float16*)alloc((size_t)E_ * 2048 * H_ * 2);
    _Float16*  dwnt   = (_Float16*)alloc((size_t)E_ * H_ * ED_ * 2);
    _Float16*  qhb    = (_Float16*)alloc((size_t)T_ * NH_ * HD_ * 2);
    _Float16*  qlb    = (_Float16*)alloc((size_t)T_ * NH_ * HD_ * 2);
    _Float16*  khb    = (_Float16*)alloc((size_t)T_ * NKV_ * HD_ * 2);
    _Float16*  klb    = (_Float16*)alloc((size_t)T_ * NKV_ * HD_ * 2);
    _Float16*  vthb   = (_Float16*)alloc((size_t)T_ * NKV_ * HD_ * 2);
    _Float16*  vtlb   = (_Float16*)alloc((size_t)T_ * NKV_ * HD_ * 2);
    float*     topw   = (float*)alloc(T_ * TOPK_ * 4);
    float*     pwb    = (float*)alloc(T_ * TOPK_ * 4);
    int*       topi   = (int*)alloc(T_ * TOPK_ * 4);
    int*       perm   = (int*)alloc(T_ * TOPK_ * 4);
    int*       counts = (int*)alloc(E_ * 4);
    int*       offs   = (int*)alloc(E_ * 4);
    int*       cursor = (int*)alloc(E_ * 4);
    int*       te     = (int*)alloc(MAXT_ * 4);
    int*       tm     = (int*)alloc(MAXT_ * 4);
    int*       ntt    = (int*)alloc(4);

    // weight conversions
    k_cvts<<<2048, 256, 0, stream>>>(qw, qwh, qwl, 2048 * H_ / 8);
    k_cvts<<<512, 256, 0, stream>>>(kw, kwh, kwl, 512 * H_ / 8);
    k_cvts<<<512, 256, 0, stream>>>(vw, vwh, vwl, 512 * H_ / 8);
    k_cvts<<<2048, 256, 0, stream>>>(ow, owh, owl, H_ * 2048 / 8);
    k_cvt_t<<<dim3(H_ / 32, 2048 / 32, E_), 256, 0, stream>>>(gup, gupt, H_, 2048);
    k_cvt_t<<<dim3(ED_ / 32, H_ / 32, E_), 256, 0, stream>>>(dwp, dwnt, ED_, H_);

    k_rmsnorm<<<T_, 256, 0, stream>>>(hidden, ln1, xnorm, xh, xl);
    // QKV: init C with bias, split-K=4 GEMMs atomically accumulate
    k_initc<<<4096, 256, 0, stream>>>(qb, nullptr, qbuf, 2048, T_ * 2048 / 4);
    k_initc<<<1024, 256, 0, stream>>>(kbia, nullptr, kbuf, 512, T_ * 512 / 4);
    k_initc<<<1024, 256, 0, stream>>>(vbia, nullptr, vbuf, 512, T_ * 512 / 4);
    k_gemm_spk<<<1024, 256, 0, stream>>>(xh, xl, qwh, qwl, qbuf, 2048, H_);
    k_gemm_spk<<<256, 256, 0, stream>>>(xh, xl, kwh, kwl, kbuf, 512, H_);
    k_gemm_spk<<<256, 256, 0, stream>>>(xh, xl, vwh, vwl, vbuf, 512, H_);
    k_rope_sp<<<T_, 256, 0, stream>>>(qbuf, kbuf, cosp, sinp, qhb, qlb, khb, klb);
    k_cvt_vt<<<dim3(32, 2, 16), 256, 0, stream>>>(vbuf, vthb, vtlb);
    k_attn_m<<<256, 256, 0, stream>>>(qhb, qlb, khb, klb, vthb, vtlb, sinks, ath, atl);
    // O-proj: out = hidden + ob + attn @ ow^T (init + split-K atomic)
    k_initc<<<4096, 256, 0, stream>>>(ob, hidden, out, 2048, T_ * 2048 / 4);
    k_gemm_spk<<<1024, 256, 0, stream>>>(ath, atl, owh, owl, out, 2048, H_);
    k_rmsnorm<<<T_, 256, 0, stream>>>(out, ln2, xnorm, xh, xl);
    k_router<<<T_, 256, 0, stream>>>(xnorm, rw, rb, topi, topw);
    k_zero<<<1, 64, 0, stream>>>(counts);
    k_hist<<<(T_ * TOPK_ + 255) / 256, 256, 0, stream>>>(topi, counts);
    k_scan<<<1, 1, 0, stream>>>(counts, offs, cursor, te, tm, ntt);
    k_scatter<<<(T_ * TOPK_ + 255) / 256, 256, 0, stream>>>(topi, topw, cursor, perm, pwb);
    k_moe1<<<MAXT_ * 16, 256, 0, stream>>>(xh, gupt, gub, perm, counts, offs, te, tm, ntt, gatedh);
    k_moe2<<<MAXT_ * 16, 256, 0, stream>>>(gatedh, dwnt, dwb, perm, pwb, counts, offs, te, tm, ntt, out);
}

// Round 9
// 957.858 us; speedup vs baseline: 5.0643x; 1.0063x over previous
//
#include <hip/hip_runtime.h>
#include <hip/hip_bf16.h>
#include <cstdint>

#define B_    2
#define S_    1024
#define H_    2048
#define NH_   32
#define NKV_  8
#define HD_   64
#define T_    (B_*S_)
#define E_    16
#define ED_   1024
#define TOPK_ 4
#define WIN_  128
#define LIMIT_ 7.0f
#define ALPHA_ 1.702f
#define EPS_   1e-6f
#define SCALE_ 0.125f  /* HD^-0.5 */
#define SPLIT_ 2048.0f
#define INV_SPLIT_ 4.8828125e-4f
#define MAXT_ 80      /* max MoE row-tiles: 64 + 16 */

typedef _Float16 half8 __attribute__((ext_vector_type(8)));
typedef _Float16 half4v __attribute__((ext_vector_type(4)));
typedef float floatx4 __attribute__((ext_vector_type(4)));

#define MF16(a,b,c) __builtin_amdgcn_mfma_f32_16x16x32_f16(a,b,c,0,0,0)

__device__ __forceinline__ void gload16(const void* g, void* l) {
    __builtin_amdgcn_global_load_lds((const __attribute__((address_space(1))) void*)g,
                                     (__attribute__((address_space(3))) void*)l, 16, 0, 0);
}

// bijective chunked XCD swizzle (nwg % 8 == 0)
__device__ __forceinline__ int xcd_swz(int bid, int nwg) {
    int cpx = nwg >> 3;
    return (bid & 7) * cpx + (bid >> 3);
}

// ================= C init: C = bias (+res) =================
__global__ __launch_bounds__(256) void k_initc(const float* __restrict__ bias,
                                               const float* __restrict__ res,
                                               float* __restrict__ C, int N, int n4) {
    int i = blockIdx.x * 256 + threadIdx.x;
    if (i >= n4) return;
    int c4 = (i % (N >> 2)) << 2;
    float4 v = *(const float4*)(bias + c4);
    if (res) {
        float4 r = ((const float4*)res)[i];
        v.x += r.x; v.y += r.y; v.z += r.z; v.w += r.w;
    }
    ((float4*)C)[i] = v;
}

// ===== split-fp16 GEMM, split-K=4, double-buffered LDS + COUNTED vmcnt =====
// Prefetch's 8 global_load_lds stay in flight across the barrier (T4):
// s_waitcnt vmcnt(8) waits only for the CURRENT buffer's loads.
__global__ __launch_bounds__(256) void k_gemm_spk(const _Float16* __restrict__ Ah,
                                                  const _Float16* __restrict__ Al,
                                                  const _Float16* __restrict__ Bh,
                                                  const _Float16* __restrict__ Bl,
                                                  float* __restrict__ C, int N, int K) {
    __shared__ _Float16 Ahs[2][128 * 32];
    __shared__ _Float16 Als[2][128 * 32];
    __shared__ _Float16 Bhs[2][128 * 32];
    __shared__ _Float16 Bls[2][128 * 32];
    const int tid = threadIdx.x;
    const int lane = tid & 63;
    const int wid = tid >> 6;
    const int wr = wid >> 1, wc = wid & 1;
    const int wg = xcd_swz(blockIdx.x, gridDim.x);
    const int col0 = (wg >> 6) * 128;
    const int row0 = ((wg & 63) >> 2) * 128;
    const int ks4 = wg & 3;
    const int kbeg = ks4 * (K >> 2), kend = kbeg + (K >> 2);
    floatx4 acc1[4][4], acc2[4][4];
    for (int m = 0; m < 4; ++m)
        for (int n = 0; n < 4; ++n) { acc1[m][n] = (floatx4)0.f; acc2[m][n] = (floatx4)0.f; }
    const int rL = tid >> 2, koff = (tid & 3) * 8;
    const size_t o0 = (size_t)(row0 + rL) * K + koff;
    const size_t o1 = (size_t)(row0 + 64 + rL) * K + koff;
    const size_t p0 = (size_t)(col0 + rL) * K + koff;
    const size_t p1 = (size_t)(col0 + 64 + rL) * K + koff;
#define DSTAGE(buf, kk) do { \
        gload16(Ah + o0 + (kk), Ahs[buf] + tid * 8); gload16(Ah + o1 + (kk), Ahs[buf] + 2048 + tid * 8); \
        gload16(Al + o0 + (kk), Als[buf] + tid * 8); gload16(Al + o1 + (kk), Als[buf] + 2048 + tid * 8); \
        gload16(Bh + p0 + (kk), Bhs[buf] + tid * 8); gload16(Bh + p1 + (kk), Bhs[buf] + 2048 + tid * 8); \
        gload16(Bl + p0 + (kk), Bls[buf] + tid * 8); gload16(Bl + p1 + (kk), Bls[buf] + 2048 + tid * 8); \
    } while (0)
    DSTAGE(0, kbeg);
    int cur = 0;
    for (int k0 = kbeg; k0 < kend; k0 += 32) {
        if (k0 + 32 < kend) {
            DSTAGE(cur ^ 1, k0 + 32);
            asm volatile("s_waitcnt vmcnt(8)" ::: "memory");
        } else {
            asm volatile("s_waitcnt vmcnt(0)" ::: "memory");
        }
        __builtin_amdgcn_s_barrier();
        __builtin_amdgcn_sched_barrier(0);
        const int lk = (lane >> 4) * 8;
        half8 ah[4], al[4], bh[4], bl[4];
#pragma unroll
        for (int m = 0; m < 4; ++m) {
            int ro = (wr * 64 + m * 16 + (lane & 15)) * 32 + lk;
            ah[m] = *(const half8*)&Ahs[cur][ro];
            al[m] = *(const half8*)&Als[cur][ro];
        }
#pragma unroll
        for (int n = 0; n < 4; ++n) {
            int ro = (wc * 64 + n * 16 + (lane & 15)) * 32 + lk;
            bh[n] = *(const half8*)&Bhs[cur][ro];
            bl[n] = *(const half8*)&Bls[cur][ro];
        }
#pragma unroll
        for (int m = 0; m < 4; ++m)
#pragma unroll
            for (int n = 0; n < 4; ++n) {
                acc1[m][n] = MF16(ah[m], bh[n], acc1[m][n]);
                acc2[m][n] = MF16(ah[m], bl[n], acc2[m][n]);
                acc2[m][n] = MF16(al[m], bh[n], acc2[m][n]);
            }
        __builtin_amdgcn_sched_barrier(0);
        __builtin_amdgcn_s_barrier();   // all waves done reading cur before overwrite
        cur ^= 1;
    }
#undef DSTAGE
#pragma unroll
    for (int mf = 0; mf < 4; ++mf)
#pragma unroll
        for (int i = 0; i < 4; ++i) {
            int r = row0 + wr * 64 + mf * 16 + ((lane >> 4) << 2) + i;
#pragma unroll
            for (int nf = 0; nf < 4; ++nf) {
                int c = col0 + wc * 64 + nf * 16 + (lane & 15);
                atomicAdd(&C[(size_t)r * N + c], acc1[mf][nf][i] + acc2[mf][nf][i] * INV_SPLIT_);
            }
        }
}

// ===== MoE MFMA core: BK=64, XOR-swizzled LDS, dbuf + COUNTED vmcnt =====
#define MOE_PROLOG() \
    __shared__ _Float16 As[2][128 * 64]; \
    __shared__ _Float16 Bs[2][128 * 64]; \
    const int tid = threadIdx.x; \
    const int lane = tid & 63; \
    const int wid = tid >> 6; \
    const int wr = wid >> 1, wc = wid & 1; \
    const int rloc = tid >> 3; \
    const int ksw = ((tid & 7) ^ (rloc & 7)) * 8; \
    floatx4 acc[4][4]; \
    for (int m = 0; m < 4; ++m) for (int n = 0; n < 4; ++n) acc[m][n] = (floatx4)0.f;

#define MOE_STAGE(buf, kk) do { \
        _Pragma("unroll") for (int c = 0; c < 4; ++c) { \
            gload16(asrc[c] + (kk), As[buf] + c * 2048 + tid * 8); \
            gload16(bsrc[c] + (kk), Bs[buf] + c * 2048 + tid * 8); \
        } \
    } while (0)

#define MOE_KLOOP(KD) \
    MOE_STAGE(0, 0); \
    { int cur = 0; \
    for (int k0 = 0; k0 < (KD); k0 += 64) { \
        if (k0 + 64 < (KD)) { \
            MOE_STAGE(cur ^ 1, k0 + 64); \
            asm volatile("s_waitcnt vmcnt(8)" ::: "memory"); \
        } else { \
            asm volatile("s_waitcnt vmcnt(0)" ::: "memory"); \
        } \
        __builtin_amdgcn_s_barrier(); \
        __builtin_amdgcn_sched_barrier(0); \
        _Pragma("unroll") for (int s = 0; s < 2; ++s) { \
            const int gc = ((s * 4 + (lane >> 4)) ^ (lane & 7)) * 8; \
            half8 a[4], b[4]; \
            _Pragma("unroll") for (int m = 0; m < 4; ++m) \
                a[m] = *(const half8*)&As[cur][(wr * 64 + m * 16 + (lane & 15)) * 64 + gc]; \
            _Pragma("unroll") for (int n = 0; n < 4; ++n) \
                b[n] = *(const half8*)&Bs[cur][(wc * 64 + n * 16 + (lane & 15)) * 64 + gc]; \
            _Pragma("unroll") for (int m = 0; m < 4; ++m) \
                _Pragma("unroll") for (int n = 0; n < 4; ++n) \
                    acc[m][n] = MF16(a[m], b[n], acc[m][n]); \
        } \
        __builtin_amdgcn_sched_barrier(0); \
        __builtin_amdgcn_s_barrier(); \
        cur ^= 1; \
    } }

// MoE GEMM1: tile-table grid (80x16). gathered A rows; fused GLU -> gated f16
__global__ __launch_bounds__(256) void k_moe1(const _Float16* __restrict__ X,
                                              const _Float16* __restrict__ W,
                                              const float* __restrict__ bias,
                                              const int* __restrict__ perm,
                                              const int* __restrict__ counts,
                                              const int* __restrict__ offs,
                                              const int* __restrict__ te,
                                              const int* __restrict__ tm,
                                              const int* __restrict__ ntt,
                                              _Float16* __restrict__ gated) {
    const int wg = xcd_swz(blockIdx.x, MAXT_ * 16);
    const int tt = wg >> 4;
    if (tt >= ntt[0]) return;
    const int e = te[tt];
    const int m0 = tm[tt];
    const int ne = counts[e];
    const int base = offs[e];
    const int col0 = (wg & 15) * 128;
    MOE_PROLOG();
    const _Float16* asrc[4];
    const _Float16* bsrc[4];
#pragma unroll
    for (int c = 0; c < 4; ++c) {
        int t = perm[base + min(m0 + c * 32 + rloc, ne - 1)];
        asrc[c] = X + (size_t)t * H_ + ksw;
        bsrc[c] = W + ((size_t)e * 2048 + col0 + c * 32 + rloc) * H_ + ksw;
    }
    MOE_KLOOP(H_);
#pragma unroll
    for (int mf = 0; mf < 4; ++mf)
#pragma unroll
        for (int i = 0; i < 4; ++i) {
            int r = m0 + wr * 64 + mf * 16 + ((lane >> 4) << 2) + i;
            bool ok = r < ne;
            int slot = base + r;
#pragma unroll
            for (int nf = 0; nf < 4; ++nf) {
                int c = col0 + wc * 64 + nf * 16 + (lane & 15);
                float v = acc[mf][nf][i] + bias[e * 2048 + c];
                float o = __shfl_xor(v, 1);
                if (ok && !(lane & 1)) {
                    float gt = fminf(v, LIMIT_);
                    float up = fminf(fmaxf(o, -LIMIT_), LIMIT_);
                    float sg = 1.f / (1.f + __expf(-ALPHA_ * gt));
                    gated[(size_t)slot * ED_ + (c >> 1)] = (_Float16)((up + 1.f) * (gt * sg));
                }
            }
        }
}

__global__ __launch_bounds__(256) void k_moe2(const _Float16* __restrict__ G,
                                              const _Float16* __restrict__ W,
                                              const float* __restrict__ bias,
                                              const int* __restrict__ perm,
                                              const float* __restrict__ pw,
                                              const int* __restrict__ counts,
                                              const int* __restrict__ offs,
                                              const int* __restrict__ te,
                                              const int* __restrict__ tm,
                                              const int* __restrict__ ntt,
                                              float* __restrict__ out) {
    const int wg = xcd_swz(blockIdx.x, MAXT_ * 16);
    const int tt = wg >> 4;
    if (tt >= ntt[0]) return;
    const int e = te[tt];
    const int m0 = tm[tt];
    const int ne = counts[e];
    const int base = offs[e];
    const int col0 = (wg & 15) * 128;
    MOE_PROLOG();
    const _Float16* asrc[4];
    const _Float16* bsrc[4];
#pragma unroll
    for (int c = 0; c < 4; ++c) {
        int s = base + min(m0 + c * 32 + rloc, ne - 1);
        asrc[c] = G + (size_t)s * ED_ + ksw;
        bsrc[c] = W + ((size_t)e * H_ + col0 + c * 32 + rloc) * ED_ + ksw;
    }
    MOE_KLOOP(ED_);
#pragma unroll
    for (int mf = 0; mf < 4; ++mf)
#pragma unroll
        for (int i = 0; i < 4; ++i) {
            int r = m0 + wr * 64 + mf * 16 + ((lane >> 4) << 2) + i;
            if (r >= ne) continue;
            int slot = base + r;
            int tok = perm[slot];
            float wgt = pw[slot];
#pragma unroll
            for (int nf = 0; nf < 4; ++nf) {
                int c = col0 + wc * 64 + nf * 16 + (lane & 15);
                atomicAdd(&out[(size_t)tok * H_ + c], wgt * (acc[mf][nf][i] + bias[e * H_ + c]));
            }
        }
}

// ================= conversions =================
__global__ __launch_bounds__(256) void k_cvts(const float* __restrict__ s,
                                              _Float16* __restrict__ dh,
                                              _Float16* __restrict__ dl, int n8) {
    int i = blockIdx.x * 256 + threadIdx.x;
    if (i >= n8) return;
    float4 x = ((const float4*)s)[i * 2], y = ((const float4*)s)[i * 2 + 1];
    float xs[8] = {x.x, x.y, x.z, x.w, y.x, y.y, y.z, y.w};
    half8 h, l;
#pragma unroll
    for (int j = 0; j < 8; ++j) {
        _Float16 hv = (_Float16)xs[j];
        h[j] = hv;
        l[j] = (_Float16)((xs[j] - (float)hv) * SPLIT_);
    }
    ((half8*)dh)[i] = h;
    ((half8*)dl)[i] = l;
}

__global__ __launch_bounds__(256) void k_cvt_t(const float* __restrict__ src,
                                               _Float16* __restrict__ dst, int K, int N) {
    const int e = blockIdx.z;
    const int k0 = blockIdx.x * 32, n0 = blockIdx.y * 32;
    __shared__ float t[32][33];
    const int tid = threadIdx.x;
    {
        int kr = tid >> 3, nc = (tid & 7) * 4;
        float4 v = *(const float4*)(src + ((size_t)e * K + k0 + kr) * N + n0 + nc);
        t[kr][nc] = v.x; t[kr][nc + 1] = v.y; t[kr][nc + 2] = v.z; t[kr][nc + 3] = v.w;
    }
    __syncthreads();
    {
        int nr = tid >> 3, kc = (tid & 7) * 4;
        half4v o;
        o[0] = (_Float16)t[kc + 0][nr];
        o[1] = (_Float16)t[kc + 1][nr];
        o[2] = (_Float16)t[kc + 2][nr];
        o[3] = (_Float16)t[kc + 3][nr];
        *(half4v*)(dst + ((size_t)e * N + n0 + nr) * K + k0 + kc) = o;
    }
}

// v transpose-split: vbuf fp32 [b][s][kvh][64] -> vth/vtl [b][kvh][64 d][1024 s]
__global__ __launch_bounds__(256) void k_cvt_vt(const float* __restrict__ vbuf,
                                                _Float16* __restrict__ vth,
                                                _Float16* __restrict__ vtl) {
    const int s0 = blockIdx.x * 32, d0 = blockIdx.y * 32;
    const int bk = blockIdx.z;
    const int b = bk >> 3, kvh = bk & 7;
    __shared__ float tl[32][33];
    const int tid = threadIdx.x;
    {
        int sr = tid >> 3, dc = (tid & 7) * 4;
        float4 v = *(const float4*)(vbuf + (size_t)(b * 1024 + s0 + sr) * 512 + kvh * 64 + d0 + dc);
        tl[sr][dc] = v.x; tl[sr][dc + 1] = v.y; tl[sr][dc + 2] = v.z; tl[sr][dc + 3] = v.w;
    }
    __syncthreads();
    {
        int dr = tid >> 3, sc = (tid & 7) * 4;
        half4v h4, l4;
#pragma unroll
        for (int j = 0; j < 4; ++j) {
            float x = tl[sc + j][dr];
            _Float16 hv = (_Float16)x;
            h4[j] = hv;
            l4[j] = (_Float16)((x - (float)hv) * SPLIT_);
        }
        size_t dst = (size_t)(bk * 64 + d0 + dr) * 1024 + s0 + sc;
        *(half4v*)(vth + dst) = h4;
        *(half4v*)(vtl + dst) = l4;
    }
}

// ================= RMSNorm (fp32 + split f16 outputs) =================
__global__ __launch_bounds__(256) void k_rmsnorm(const float* __restrict__ x,
                                                 const float* __restrict__ w,
                                                 float* __restrict__ y,
                                                 _Float16* __restrict__ yh,
                                                 _Float16* __restrict__ yl) {
    int t = blockIdx.x;
    const float* row = x + (size_t)t * H_;
    float ss = 0.f;
    for (int i = threadIdx.x; i < H_ / 4; i += 256) {
        float4 v = ((const float4*)row)[i];
        ss += v.x * v.x + v.y * v.y + v.z * v.z + v.w * v.w;
    }
    for (int o = 32; o >= 1; o >>= 1) ss += __shfl_xor(ss, o);
    __shared__ float wsum[4];
    if ((threadIdx.x & 63) == 0) wsum[threadIdx.x >> 6] = ss;
    __syncthreads();
    float tot = wsum[0] + wsum[1] + wsum[2] + wsum[3];
    float r = rsqrtf(tot / (float)H_ + EPS_);
    float* yrow = y + (size_t)t * H_;
    _Float16* hrow = yh + (size_t)t * H_;
    _Float16* lrow = yl + (size_t)t * H_;
    for (int i = threadIdx.x; i < H_ / 4; i += 256) {
        float4 v = ((const float4*)row)[i];
        float4 g = ((const float4*)w)[i];
        float o4[4];
        o4[0] = v.x * r * g.x; o4[1] = v.y * r * g.y;
        o4[2] = v.z * r * g.z; o4[3] = v.w * r * g.w;
        ((float4*)yrow)[i] = *(float4*)o4;
        half4v h4, l4;
#pragma unroll
        for (int j = 0; j < 4; ++j) {
            _Float16 hv = (_Float16)o4[j];
            h4[j] = hv;
            l4[j] = (_Float16)((o4[j] - (float)hv) * SPLIT_);
        }
        ((half4v*)hrow)[i] = h4;
        ((half4v*)lrow)[i] = l4;
    }
}

// ================= RoPE -> head-major split q/k =================
__global__ __launch_bounds__(256) void k_rope_sp(const float* __restrict__ qbuf,
                                                 const float* __restrict__ kbuf,
                                                 const float* __restrict__ cs,
                                                 const float* __restrict__ sn,
                                                 _Float16* __restrict__ qh, _Float16* __restrict__ ql,
                                                 _Float16* __restrict__ kh, _Float16* __restrict__ kl) {
    int t = blockIdx.x;
    int b = t >> 10, s = t & 1023;
    size_t cb = (size_t)t * 64;
    for (int p = threadIdx.x; p < 40 * 32; p += 256) {
        int head = p >> 5, d = p & 31;
        float c1 = cs[cb + d],      s1v = sn[cb + d];
        float c2 = cs[cb + d + 32], s2v = sn[cb + d + 32];
        float x1, x2; size_t dst;
        _Float16 *oh, *ol;
        if (head < 32) {
            const float* src = qbuf + (size_t)t * 2048 + head * 64;
            x1 = src[d]; x2 = src[d + 32];
            dst = (((size_t)b * 32 + head) * 1024 + s) * 64 + d;
            oh = qh; ol = ql;
        } else {
            int hk = head - 32;
            const float* src = kbuf + (size_t)t * 512 + hk * 64;
            x1 = src[d]; x2 = src[d + 32];
            dst = (((size_t)b * 8 + hk) * 1024 + s) * 64 + d;
            oh = kh; ol = kl;
        }
        float r1 = x1 * c1 - x2 * s1v;
        float r2 = x2 * c2 + x1 * s2v;
        _Float16 h1 = (_Float16)r1;
        oh[dst] = h1; ol[dst] = (_Float16)((r1 - (float)h1) * SPLIT_);
        _Float16 h2 = (_Float16)r2;
        oh[dst + 32] = h2; ol[dst + 32] = (_Float16)((r2 - (float)h2) * SPLIT_);
    }
}

// ================= MFMA flash attention (split-fp16, fp32-accurate) ===========
#define PPITCH 68
union U8h { unsigned w[4]; half8 v; };

__global__ __launch_bounds__(256, 1) void k_attn_m(
        const _Float16* __restrict__ qhg, const _Float16* __restrict__ qlg,
        const _Float16* __restrict__ khg, const _Float16* __restrict__ klg,
        const _Float16* __restrict__ vthg, const _Float16* __restrict__ vtlg,
        const float* __restrict__ sinks,
        _Float16* __restrict__ ath, _Float16* __restrict__ atl) {
    __shared__ _Float16 Khs[4096], Kls[4096], Vhs[4096], Vls[4096];
    __shared__ unsigned Pp[4][64 * PPITCH];
    const int bx = blockIdx.x;
    const int b = bx >> 7, kvh = (bx >> 4) & 7, tile = bx & 15;
    const int i0 = tile * 64;
    const int tid = threadIdx.x, lane = tid & 63, wid = tid >> 6;
    const int l15 = lane & 15, g = lane >> 4;
    const int h = kvh * 4 + wid;
    const size_t kvbase = (size_t)(b * 8 + kvh) * 1024 * 64;
    const size_t vbase  = (size_t)(b * 8 + kvh) * 64 * 1024;
    half8 aqh[4][2], aql[4][2];
    {
        const size_t qb0 = ((size_t)(b * 32 + h) * 1024 + i0) * 64;
#pragma unroll
        for (int mf = 0; mf < 4; ++mf)
#pragma unroll
            for (int ks = 0; ks < 2; ++ks) {
                size_t a = qb0 + (size_t)(16 * mf + l15) * 64 + ks * 32 + g * 8;
                aqh[mf][ks] = *(const half8*)(qhg + a);
                aql[mf][ks] = *(const half8*)(qlg + a);
            }
    }
    floatx4 o1[4][4], o2[4][4];
    float m_run[4][4], l_run[4][4];
#pragma unroll
    for (int mf = 0; mf < 4; ++mf)
#pragma unroll
        for (int x = 0; x < 4; ++x) {
            o1[mf][x] = (floatx4)0.f; o2[mf][x] = (floatx4)0.f;
            m_run[mf][x] = -1e20f; l_run[mf][x] = 0.f;
        }
    const int nch = tile >= 2 ? 3 : tile + 1;
    const int jr = tid >> 3, cc = tid & 7;
    unsigned* pw = &Pp[wid][0];
    for (int ci = 0; ci < nch; ++ci) {
        const int jb = i0 - 64 * (nch - 1 - ci);
        __syncthreads();
        {
            const int sw0 = (cc ^ (jr & 7)) * 8;
            const size_t k0 = kvbase + (size_t)(jb + jr) * 64 + sw0;
            const size_t k1 = kvbase + (size_t)(jb + jr + 32) * 64 + sw0;
            gload16(khg + k0, Khs + tid * 8);
            gload16(khg + k1, Khs + 2048 + tid * 8);
            gload16(klg + k0, Kls + tid * 8);
            gload16(klg + k1, Kls + 2048 + tid * 8);
            const size_t v0 = vbase + (size_t)jr * 1024 + jb + sw0;
            const size_t v1 = vbase + (size_t)(jr + 32) * 1024 + jb + sw0;
            gload16(vthg + v0, Vhs + tid * 8);
            gload16(vthg + v1, Vhs + 2048 + tid * 8);
            gload16(vtlg + v0, Vls + tid * 8);
            gload16(vtlg + v1, Vls + 2048 + tid * 8);
        }
        __syncthreads();
        floatx4 s1[4][4], s2[4][4];
#pragma unroll
        for (int mf = 0; mf < 4; ++mf)
#pragma unroll
            for (int nf = 0; nf < 4; ++nf) { s1[mf][nf] = (floatx4)0.f; s2[mf][nf] = (floatx4)0.f; }
#pragma unroll
        for (int ks = 0; ks < 2; ++ks) {
            half8 kbh[4], kbl[4];
#pragma unroll
            for (int nf = 0; nf < 4; ++nf) {
                int j = l15 + 16 * nf;
                int c = (g + 4 * ks) ^ (j & 7);
                kbh[nf] = *(const half8*)&Khs[j * 64 + c * 8];
                kbl[nf] = *(const half8*)&Kls[j * 64 + c * 8];
            }
#pragma unroll
            for (int mf = 0; mf < 4; ++mf)
#pragma unroll
                for (int nf = 0; nf < 4; ++nf) {
                    s1[mf][nf] = MF16(aqh[mf][ks], kbh[nf], s1[mf][nf]);
                    s2[mf][nf] = MF16(aqh[mf][ks], kbl[nf], s2[mf][nf]);
                    s2[mf][nf] = MF16(aql[mf][ks], kbh[nf], s2[mf][nf]);
                }
        }
#pragma unroll
        for (int mf = 0; mf < 4; ++mf)
#pragma unroll
            for (int reg = 0; reg < 4; ++reg) {
                int i = i0 + 16 * mf + g * 4 + reg;
                float best = -1e30f;
#pragma unroll
                for (int nf = 0; nf < 4; ++nf) {
                    int j = jb + 16 * nf + l15;
                    float sv = (s1[mf][nf][reg] + s2[mf][nf][reg] * INV_SPLIT_) * SCALE_;
                    bool ok = (j <= i) && (i - j < WIN_);
                    sv = ok ? sv : -1e30f;
                    s1[mf][nf][reg] = sv;
                    best = fmaxf(best, sv);
                }
                for (int off = 1; off < 16; off <<= 1) best = fmaxf(best, __shfl_xor(best, off));
                float nm = fmaxf(m_run[mf][reg], best);
                float sc = __expf(m_run[mf][reg] - nm);
                m_run[mf][reg] = nm;
                l_run[mf][reg] *= sc;
#pragma unroll
                for (int nf = 0; nf < 4; ++nf) { o1[mf][nf][reg] *= sc; o2[mf][nf][reg] *= sc; }
            }
#pragma unroll
        for (int mf = 0; mf < 4; ++mf)
#pragma unroll
            for (int nf = 0; nf < 4; ++nf)
#pragma unroll
                for (int reg = 0; reg < 4; ++reg) {
                    float pv = __expf(s1[mf][nf][reg] - m_run[mf][reg]);
                    l_run[mf][reg] += pv;
                    _Float16 hv = (_Float16)pv;
                    _Float16 lv = (_Float16)((pv - (float)hv) * SPLIT_);
                    union { _Float16 h; unsigned short u; } ch, cl;
                    ch.h = hv; cl.h = lv;
                    int t = 16 * mf + g * 4 + reg, jj = l15 + 16 * nf;
                    pw[t * PPITCH + jj] = (unsigned)ch.u | ((unsigned)cl.u << 16);
                }
#pragma unroll
        for (int ks = 0; ks < 2; ++ks) {
            half8 bvh[4], bvl[4];
#pragma unroll
            for (int nf = 0; nf < 4; ++nf) {
                int d = l15 + 16 * nf;
                int c = (g + 4 * ks) ^ (d & 7);
                bvh[nf] = *(const half8*)&Vhs[d * 64 + c * 8];
                bvl[nf] = *(const half8*)&Vls[d * 64 + c * 8];
            }
#pragma unroll
            for (int mf = 0; mf < 4; ++mf) {
                const unsigned* pr = &pw[(16 * mf + l15) * PPITCH + 32 * ks + g * 8];
                int4 va = *(const int4*)pr;
                int4 vb = *(const int4*)(pr + 4);
                U8h ph, pl;
                ph.w[0] = ((unsigned)va.x & 0xffffu) | ((unsigned)va.y << 16);
                ph.w[1] = ((unsigned)va.z & 0xffffu) | ((unsigned)va.w << 16);
                ph.w[2] = ((unsigned)vb.x & 0xffffu) | ((unsigned)vb.y << 16);
                ph.w[3] = ((unsigned)vb.z & 0xffffu) | ((unsigned)vb.w << 16);
                pl.w[0] = ((unsigned)va.x >> 16) | ((unsigned)va.y & 0xffff0000u);
                pl.w[1] = ((unsigned)va.z >> 16) | ((unsigned)va.w & 0xffff0000u);
                pl.w[2] = ((unsigned)vb.x >> 16) | ((unsigned)vb.y & 0xffff0000u);
                pl.w[3] = ((unsigned)vb.z >> 16) | ((unsigned)vb.w & 0xffff0000u);
#pragma unroll
                for (int nf = 0; nf < 4; ++nf) {
                    o1[mf][nf] = MF16(ph.v, bvh[nf], o1[mf][nf]);
                    o2[mf][nf] = MF16(ph.v, bvl[nf], o2[mf][nf]);
                    o2[mf][nf] = MF16(pl.v, bvh[nf], o2[mf][nf]);
                }
            }
        }
    }
    const float sinkv = sinks[h];
    float inv[4][4];
#pragma unroll
    for (int mf = 0; mf < 4; ++mf)
#pragma unroll
        for (int reg = 0; reg < 4; ++reg) {
            float l = l_run[mf][reg];
            for (int off = 1; off < 16; off <<= 1) l += __shfl_xor(l, off);
            inv[mf][reg] = 1.f / (l + __expf(sinkv - m_run[mf][reg]));
        }
    // fused split-fp16 output (feeds o-proj A operand directly)
#pragma unroll
    for (int mf = 0; mf < 4; ++mf)
#pragma unroll
        for (int nf = 0; nf < 4; ++nf)
#pragma unroll
            for (int reg = 0; reg < 4; ++reg) {
                int t = i0 + 16 * mf + g * 4 + reg;
                int d = l15 + 16 * nf;
                float ov = (o1[mf][nf][reg] + o2[mf][nf][reg] * INV_SPLIT_) * inv[mf][reg];
                size_t idx = ((size_t)(b * 1024 + t) * 32 + h) * 64 + d;
                _Float16 hv = (_Float16)ov;
                ath[idx] = hv;
                atl[idx] = (_Float16)((ov - (float)hv) * SPLIT_);
            }
}

// ================= Router =================
__global__ __launch_bounds__(256) void k_router(const float* __restrict__ x,
                                                const float* __restrict__ rw,
                                                const float* __restrict__ rb,
                                                int* __restrict__ topi,
                                                float* __restrict__ topw) {
    int t = blockIdx.x;
    int e = threadIdx.x >> 4, g = threadIdx.x & 15;
    const float* row = x + (size_t)t * H_;
    const float* wr = rw + (size_t)e * H_;
    float acc = 0.f;
    int kbeg = g * (H_ / 16);
    for (int kk = 0; kk < H_ / 16; kk += 4) {
        float4 xv = *(const float4*)(row + kbeg + kk);
        float4 wv = *(const float4*)(wr + kbeg + kk);
        acc += xv.x * wv.x + xv.y * wv.y + xv.z * wv.z + xv.w * wv.w;
    }
    __shared__ float part[16][17];
    part[e][g] = acc;
    __syncthreads();
    __shared__ float logits[16];
    if (threadIdx.x < 16) {
        float s2 = rb[threadIdx.x];
        for (int g2 = 0; g2 < 16; g2++) s2 += part[threadIdx.x][g2];
        logits[threadIdx.x] = s2;
    }
    __syncthreads();
    if (threadIdx.x == 0) {
        float tv[4]; int ti4[4];
        unsigned used = 0;
        for (int s3 = 0; s3 < 4; s3++) {
            float best = -3.0e38f; int bi = 0;
            for (int e2 = 0; e2 < 16; e2++)
                if (!((used >> e2) & 1) && logits[e2] > best) { best = logits[e2]; bi = e2; }
            used |= 1u << bi; tv[s3] = best; ti4[s3] = bi;
        }
        float mx = tv[0], pe[4], sum = 0.f;
        for (int s3 = 0; s3 < 4; s3++) { pe[s3] = __expf(tv[s3] - mx); sum += pe[s3]; }
        for (int s3 = 0; s3 < 4; s3++) {
            topw[t * 4 + s3] = pe[s3] / sum;
            topi[t * 4 + s3] = ti4[s3];
        }
    }
}

// ================= MoE prep =================
__global__ void k_zero(int* counts) { if (threadIdx.x < E_) counts[threadIdx.x] = 0; }

__global__ void k_hist(const int* __restrict__ topi, int* counts) {
    int g = blockIdx.x * 256 + threadIdx.x;
    if (g < T_ * TOPK_) atomicAdd(&counts[topi[g]], 1);
}

// scan + build compact MoE tile table (<=80 row-tiles of 128)
__global__ void k_scan(const int* __restrict__ counts, int* offs, int* cursor,
                       int* te, int* tm, int* ntt) {
    if (threadIdx.x == 0 && blockIdx.x == 0) {
        int run = 0, t = 0;
        for (int e = 0; e < E_; e++) {
            offs[e] = run; cursor[e] = run;
            for (int m0 = 0; m0 < counts[e]; m0 += 128) { te[t] = e; tm[t] = m0; t++; }
            run += counts[e];
        }
        ntt[0] = t;
    }
}

__global__ void k_scatter(const int* __restrict__ topi, const float* __restrict__ topw,
                          int* cursor, int* __restrict__ perm, float* __restrict__ pw) {
    int g = blockIdx.x * 256 + threadIdx.x;
    if (g >= T_ * TOPK_) return;
    int e = topi[g];
    int pos = atomicAdd(&cursor[e], 1);
    perm[pos] = g >> 2;
    pw[pos] = topw[g];
}

// ================= launch =================
extern "C" void kernel_launch(void* const* d_in, const int* in_sizes, int n_in,
                              void* d_out, int out_size, void* d_ws, size_t ws_size,
                              hipStream_t stream) {
    const float* hidden = (const float*)d_in[0];
    const float* cosp  = (const float*)d_in[1];
    const float* sinp  = (const float*)d_in[2];
    const float* ln1   = (const float*)d_in[3];
    const float* ln2   = (const float*)d_in[4];
    const float* qw    = (const float*)d_in[5];
    const float* qb    = (const float*)d_in[6];
    const float* kw    = (const float*)d_in[7];
    const float* kbia  = (const float*)d_in[8];
    const float* vw    = (const float*)d_in[9];
    const float* vbia  = (const float*)d_in[10];
    const float* ow    = (const float*)d_in[11];
    const float* ob    = (const float*)d_in[12];
    const float* sinks = (const float*)d_in[13];
    const float* rw    = (const float*)d_in[14];
    const float* rb    = (const float*)d_in[15];
    const float* gup   = (const float*)d_in[16];
    const float* gub   = (const float*)d_in[17];
    const float* dwp   = (const float*)d_in[18];
    const float* dwb   = (const float*)d_in[19];
    float* out = (float*)d_out;

    char* p = (char*)d_ws;
    auto alloc = [&](size_t bytes) { char* r = p; p += (bytes + 255) & ~(size_t)255; return r; };
    float*     xnorm  = (float*)alloc((size_t)T_ * H_ * 4);
    _Float16*  xh     = (_Float16*)alloc((size_t)T_ * H_ * 2);
    _Float16*  xl     = (_Float16*)alloc((size_t)T_ * H_ * 2);
    float*     qbuf   = (float*)alloc((size_t)T_ * NH_ * HD_ * 4);
    float*     kbuf   = (float*)alloc((size_t)T_ * NKV_ * HD_ * 4);
    float*     vbuf   = (float*)alloc((size_t)T_ * NKV_ * HD_ * 4);
    _Float16*  ath    = (_Float16*)alloc((size_t)T_ * NH_ * HD_ * 2);
    _Float16*  atl    = (_Float16*)alloc((size_t)T_ * NH_ * HD_ * 2);
    _Float16*  gatedh = (_Float16*)alloc((size_t)T_ * TOPK_ * ED_ * 2);
    _Float16*  qwh    = (_Float16*)alloc((size_t)2048 * H_ * 2);
    _Float16*  qwl    = (_Float16*)alloc((size_t)2048 * H_ * 2);
    _Float16*  kwh    = (_Float16*)alloc((size_t)512 * H_ * 2);
    _Float16*  kwl    = (_Float16*)alloc((size_t)512 * H_ * 2);
    _Float16*  vwh    = (_Float16*)alloc((size_t)512 * H_ * 2);
    _Float16*  vwl    = (_Float16*)alloc((size_t)512 * H_ * 2);
    _Float16*  owh    = (_Float16*)alloc((size_t)H_ * 2048 * 2);
    _Float16*  owl    = (_Float16*)alloc((size_t)H_ * 2048 * 2);
    _Float16*  gupt   = (_Float16*)alloc((size_t)E_ * 2048 * H_ * 2);
    _Float16*  dwnt   = (_Float16*)alloc((size_t)E_ * H_ * ED_ * 2);
    _Float16*  qhb    = (_Float16*)alloc((size_t)T_ * NH_ * HD_ * 2);
    _Float16*  qlb    = (_Float16*)alloc((size_t)T_ * NH_ * HD_ * 2);
    _Float16*  khb    = (_Float16*)alloc((size_t)T_ * NKV_ * HD_ * 2);
    _Float16*  klb    = (_Float16*)alloc((size_t)T_ * NKV_ * HD_ * 2);
    _Float16*  vthb   = (_Float16*)alloc((size_t)T_ * NKV_ * HD_ * 2);
    _Float16*  vtlb   = (_Float16*)alloc((size_t)T_ * NKV_ * HD_ * 2);
    float*     topw   = (float*)alloc(T_ * TOPK_ * 4);
    float*     pwb    = (float*)alloc(T_ * TOPK_ * 4);
    int*       topi   = (int*)alloc(T_ * TOPK_ * 4);
    int*       perm   = (int*)alloc(T_ * TOPK_ * 4);
    int*       counts = (int*)alloc(E_ * 4);
    int*       offs   = (int*)alloc(E_ * 4);
    int*       cursor = (int*)alloc(E_ * 4);
    int*       te     = (int*)alloc(MAXT_ * 4);
    int*       tm     = (int*)alloc(MAXT_ * 4);
    int*       ntt    = (int*)alloc(4);

    // weight conversions
    k_cvts<<<2048, 256, 0, stream>>>(qw, qwh, qwl, 2048 * H_ / 8);
    k_cvts<<<512, 256, 0, stream>>>(kw, kwh, kwl, 512 * H_ / 8);
    k_cvts<<<512, 256, 0, stream>>>(vw, vwh, vwl, 512 * H_ / 8);
    k_cvts<<<2048, 256, 0, stream>>>(ow, owh, owl, H_ * 2048 / 8);
    k_cvt_t<<<dim3(H_ / 32, 2048 / 32, E_), 256, 0, stream>>>(gup, gupt, H_, 2048);
    k_cvt_t<<<dim3(ED_ / 32, H_ / 32, E_), 256, 0, stream>>>(dwp, dwnt, ED_, H_);

    k_rmsnorm<<<T_, 256, 0, stream>>>(hidden, ln1, xnorm, xh, xl);
    // QKV: init C with bias, split-K=4 GEMMs atomically accumulate
    k_initc<<<4096, 256, 0, stream>>>(qb, nullptr, qbuf, 2048, T_ * 2048 / 4);
    k_initc<<<1024, 256, 0, stream>>>(kbia, nullptr, kbuf, 512, T_ * 512 / 4);
    k_initc<<<1024, 256, 0, stream>>>(vbia, nullptr, vbuf, 512, T_ * 512 / 4);
    k_gemm_spk<<<1024, 256, 0, stream>>>(xh, xl, qwh, qwl, qbuf, 2048, H_);
    k_gemm_spk<<<256, 256, 0, stream>>>(xh, xl, kwh, kwl, kbuf, 512, H_);
    k_gemm_spk<<<256, 256, 0, stream>>>(xh, xl, vwh, vwl, vbuf, 512, H_);
    k_rope_sp<<<T_, 256, 0, stream>>>(qbuf, kbuf, cosp, sinp, qhb, qlb, khb, klb);
    k_cvt_vt<<<dim3(32, 2, 16), 256, 0, stream>>>(vbuf, vthb, vtlb);
    k_attn_m<<<256, 256, 0, stream>>>(qhb, qlb, khb, klb, vthb, vtlb, sinks, ath, atl);
    // O-proj: out = hidden + ob + attn @ ow^T (init + split-K atomic)
    k_initc<<<4096, 256, 0, stream>>>(ob, hidden, out, 2048, T_ * 2048 / 4);
    k_gemm_spk<<<1024, 256, 0, stream>>>(ath, atl, owh, owl, out, 2048, H_);
    k_rmsnorm<<<T_, 256, 0, stream>>>(out, ln2, xnorm, xh, xl);
    k_router<<<T_, 256, 0, stream>>>(xnorm, rw, rb, topi, topw);
    k_zero<<<1, 64, 0, stream>>>(counts);
    k_hist<<<(T_ * TOPK_ + 255) / 256, 256, 0, stream>>>(topi, counts);
    k_scan<<<1, 1, 0, stream>>>(counts, offs, cursor, te, tm, ntt);
    k_scatter<<<(T_ * TOPK_ + 255) / 256, 256, 0, stream>>>(topi, topw, cursor, perm, pwb);
    k_moe1<<<MAXT_ * 16, 256, 0, stream>>>(xh, gupt, gub, perm, counts, offs, te, tm, ntt, gatedh);
    k_moe2<<<MAXT_ * 16, 256, 0, stream>>>(gatedh, dwnt, dwb, perm, pwb, counts, offs, te, tm, ntt, out);
}